// Round 1
// baseline (476.809 us; speedup 1.0000x reference)
//
#include <hip/hip_runtime.h>
#include <stdint.h>

// Reformer layer: B=4 T=4096 D=512 H=8 DH=64 N_HASH=4 N_BUCKET=64 BUCKET=64 FFN=2048
typedef unsigned short u16;
typedef __attribute__((ext_vector_type(4))) int   i32x4;
typedef __attribute__((ext_vector_type(4))) float f32x4;

__device__ __forceinline__ u16 f2bf(float x){
  unsigned int u = __float_as_uint(x);
  u += 0x7FFFu + ((u >> 16) & 1u);
  return (u16)(u >> 16);
}
__device__ __forceinline__ float bf2f(u16 h){
  return __uint_as_float(((unsigned int)h) << 16);
}
__device__ __forceinline__ f32x4 mfma16(i32x4 a, i32x4 b, f32x4 c){
  asm("v_mfma_f32_16x16x32_bf16 %0, %1, %2, %0" : "+v"(c) : "v"(a), "v"(b));
  return c;
}
// hazard fence: guarantee wait-states between MFMA writes and VALU reads of acc
__device__ __forceinline__ f32x4 acc_fence(f32x4 c){
  asm volatile("s_nop 7\ns_nop 7" : "+v"(c));
  return c;
}
__device__ __forceinline__ void gl_lds16(const void* g, void* l){
  unsigned long long ga = (unsigned long long)g;
  unsigned int la = (unsigned int)(unsigned long long)l;
  __builtin_amdgcn_global_load_lds((const __attribute__((address_space(1))) void*)ga,
                                   (__attribute__((address_space(3))) void*)la, 16, 0, 0);
}

// ---------------- converts ----------------
__global__ __launch_bounds__(256) void k_cvt(const float* __restrict__ in, u16* __restrict__ out, int n4){
  int i = blockIdx.x*256 + threadIdx.x;
  if (i >= n4) return;
  float4 v = ((const float4*)in)[i];
  ushort4 o; o.x=f2bf(v.x); o.y=f2bf(v.y); o.z=f2bf(v.z); o.w=f2bf(v.w);
  ((ushort4*)out)[i] = o;
}
__global__ __launch_bounds__(256) void k_split(const float* __restrict__ in, u16* __restrict__ hi, u16* __restrict__ lo, int n4){
  int i = blockIdx.x*256 + threadIdx.x;
  if (i >= n4) return;
  float4 v = ((const float4*)in)[i];
  ushort4 h, l;
  h.x=f2bf(v.x); l.x=f2bf(v.x - bf2f(h.x));
  h.y=f2bf(v.y); l.y=f2bf(v.y - bf2f(h.y));
  h.z=f2bf(v.z); l.z=f2bf(v.z - bf2f(h.z));
  h.w=f2bf(v.w); l.w=f2bf(v.w - bf2f(h.w));
  ((ushort4*)hi)[i]=h; ((ushort4*)lo)[i]=l;
}

// ---------------- generic bf16 MFMA GEMM: C = sum_t A_t * B_t^T ----------------
// A row-major MxK (ld=K), B row-major NxK (ld=K).
// MODE 0: fp32 rowmajor (+bias)   MODE 1: bf16 rowmajor, bias+relu
// MODE 2: fp32 head-layout (qk)   MODE 3: bf16 head-layout (v)
template<int MODE>
__global__ __launch_bounds__(256) void k_gemm(
    const u16* __restrict__ A0, const u16* __restrict__ A1,
    const u16* __restrict__ B0, const u16* __restrict__ B1,
    const float* __restrict__ bias,
    float* __restrict__ Cf, u16* __restrict__ Cb,
    int M, int N, int K, int nterms)
{
  const int tid = threadIdx.x;
  const int l = tid & 63, w = tid >> 6;
  const int lr = l & 15, lg = l >> 4;
  const int m0 = blockIdx.y * 128, n0 = blockIdx.x * 128;
  const int mbase = (w >> 1) * 64, nbase = (w & 1) * 64;

  __shared__ __align__(16) u16 As[128*64];
  __shared__ __align__(16) u16 Bs[128*64];

  f32x4 zero = {0.f,0.f,0.f,0.f};
  f32x4 acc[4][4];
  #pragma unroll
  for (int i=0;i<4;i++)
    #pragma unroll
    for (int j=0;j<4;j++) acc[i][j] = zero;

  const int row_s = tid >> 3;   // 0..31
  const int c16   = tid & 7;

  for (int term = 0; term < nterms; ++term){
    const u16* Ap = (term==2) ? A1 : A0;
    const u16* Bp = (term==1) ? B1 : B0;
    for (int k0 = 0; k0 < K; k0 += 64){
      #pragma unroll
      for (int q=0;q<4;q++){
        int ra = q*32 + row_s;
        int cs = c16 ^ (ra & 7);   // pre-swizzled global source, linear LDS dest
        gl_lds16(Ap + (size_t)(m0 + ra)*K + k0 + cs*8, (char*)As + q*4096 + tid*16);
        gl_lds16(Bp + (size_t)(n0 + ra)*K + k0 + cs*8, (char*)Bs + q*4096 + tid*16);
      }
      __syncthreads();
      #pragma unroll
      for (int kk=0; kk<64; kk+=32){
        i32x4 af[4], bfr[4];
        #pragma unroll
        for (int mf=0;mf<4;mf++){
          int row = mbase + mf*16 + lr;
          af[mf] = *(const i32x4*)((const char*)As + row*128 + (((kk*2) + (lg*16)) ^ ((row&7)<<4)));
        }
        #pragma unroll
        for (int nf=0;nf<4;nf++){
          int row = nbase + nf*16 + lr;
          bfr[nf] = *(const i32x4*)((const char*)Bs + row*128 + (((kk*2) + (lg*16)) ^ ((row&7)<<4)));
        }
        #pragma unroll
        for (int mf=0;mf<4;mf++)
          #pragma unroll
          for (int nf=0;nf<4;nf++)
            acc[mf][nf] = mfma16(af[mf], bfr[nf], acc[mf][nf]);
      }
      __syncthreads();
    }
  }

  #pragma unroll
  for (int mf=0;mf<4;mf++){
    #pragma unroll
    for (int nf=0;nf<4;nf++){
      f32x4 v = acc_fence(acc[mf][nf]);
      #pragma unroll
      for (int r=0;r<4;r++){
        int m = m0 + mbase + mf*16 + lg*4 + r;
        int n = n0 + nbase + nf*16 + lr;
        float val = v[r];
        if (MODE == 0){
          if (bias) val += bias[n];
          Cf[(size_t)m*N + n] = val;
        } else if (MODE == 1){
          val += bias[n];
          val = fmaxf(val, 0.f);
          Cb[(size_t)m*N + n] = f2bf(val);
        } else {
          int b = m >> 12, t = m & 4095, h = n >> 6, d = n & 63;
          size_t idx = ((((size_t)(b*8 + h)) << 12) + t)*64 + d;
          if (MODE == 2) Cf[idx] = val;
          else           Cb[idx] = f2bf(val);
        }
      }
    }
  }
}

// ---------------- LSH hashing: buckets = argmax([rot,-rot]) (fp32) ----------------
__global__ __launch_bounds__(256) void k_hash(const float* __restrict__ qk, const float* __restrict__ rot,
                                              int* __restrict__ buckets){
  const int bh = blockIdx.x, tb = blockIdx.y;
  const int tid = threadIdx.x;
  __shared__ float rotT[128][64];   // [hash*32+i][d]
  for (int idx = tid; idx < 8192; idx += 256)
    rotT[idx & 127][idx >> 7] = rot[idx];
  __syncthreads();
  const int tok = tb*256 + tid;
  const float4* qp = (const float4*)(qk + (((size_t)bh << 12) + tok) * 64);
  float4 q[16];
  #pragma unroll
  for (int i=0;i<16;i++) q[i] = qp[i];
  #pragma unroll
  for (int hh=0; hh<4; hh++){
    float maxv = -1e30f, minv = 1e30f; int maxi=0, mini=0;
    for (int i=0;i<32;i++){
      const float4* rp = (const float4*)(&rotT[hh*32+i][0]);
      float acc = 0.f;
      #pragma unroll
      for (int dd=0; dd<16; dd++){
        float4 r4 = rp[dd];
        acc += q[dd].x*r4.x + q[dd].y*r4.y + q[dd].z*r4.z + q[dd].w*r4.w;
      }
      if (acc > maxv){ maxv = acc; maxi = i; }
      if (acc < minv){ minv = acc; mini = i; }
    }
    int bkt = (maxv >= -minv) ? maxi : (32 + mini);
    buckets[(((size_t)(bh*4 + hh)) << 12) + tok] = bkt;
  }
}

// ---------------- stable counting sort per (bh, round): 4096 elems, 64 bins ----------------
__global__ __launch_bounds__(64) void k_sort(const int* __restrict__ buckets, int* __restrict__ st){
  const int grp = blockIdx.x;          // bh*4 + r
  const int t = threadIdx.x;           // 0..63
  __shared__ int hist[64][65];
  __shared__ int tot[64];
  const size_t gbase = ((size_t)grp) << 12;
  #pragma unroll
  for (int b=0;b<64;b++) hist[t][b] = 0;
  __syncthreads();
  for (int i=0;i<64;i++){
    int b = buckets[gbase + t*64 + i];
    hist[t][b]++;
  }
  __syncthreads();
  { int run = 0;
    for (int tt=0; tt<64; tt++){ int v = hist[tt][t]; hist[tt][t] = run; run += v; }
    tot[t] = run; }
  __syncthreads();
  { int v = tot[t]; int incl = v;
    #pragma unroll
    for (int d=1; d<64; d<<=1){ int n = __shfl_up(incl, d, 64); if (t >= d) incl += n; }
    tot[t] = incl - v; }
  __syncthreads();
  const size_t obase = (((size_t)(grp>>2)) << 14) + ((size_t)(grp&3) << 12);
  for (int i=0;i<64;i++){
    int e = t*64 + i;
    int b = buckets[gbase + e];
    int dest = tot[b] + hist[t][b];
    hist[t][b]++;
    st[obase + dest] = e;
  }
}

// ---------------- chunked LSH attention ----------------
__global__ __launch_bounds__(256) void k_attn(
    const float* __restrict__ qk, const u16* __restrict__ vB,
    const int* __restrict__ st, float* __restrict__ lgt_out, u16* __restrict__ bo)
{
  const int c = blockIdx.x, bh = blockIdx.y;
  const int rnd = c >> 6;
  const int tid = threadIdx.x;
  const int l = tid & 63, w = tid >> 6, lr = l & 15, lg = l >> 4;

  __shared__ __align__(16) u16 Qs[64][72];
  __shared__ __align__(16) u16 Ks[128][72];
  __shared__ __align__(16) u16 Vt[64][136];   // [d][key]
  __shared__ __align__(16) u16 Ps[64][136];   // [q][key]
  __shared__ int posk[128];

  if (tid < 128){
    int cc = (tid < 64) ? c : ((c + 255) & 255);
    posk[tid] = st[(((size_t)bh) << 14) + (cc << 6) + (tid & 63)];
  }
  __syncthreads();

  if (tid < 128){
    int j = tid;
    const float4* rp = (const float4*)(qk + (((size_t)bh << 12) + posk[j]) * 64);
    float4 rv[16]; float ss = 0.f;
    #pragma unroll
    for (int i=0;i<16;i++){ rv[i] = rp[i];
      ss += rv[i].x*rv[i].x + rv[i].y*rv[i].y + rv[i].z*rv[i].z + rv[i].w*rv[i].w; }
    float scale = 1.f / fmaxf(sqrtf(ss), 1e-6f);
    #pragma unroll
    for (int i=0;i<16;i++){
      Ks[j][i*4+0] = f2bf(rv[i].x*scale);
      Ks[j][i*4+1] = f2bf(rv[i].y*scale);
      Ks[j][i*4+2] = f2bf(rv[i].z*scale);
      Ks[j][i*4+3] = f2bf(rv[i].w*scale);
    }
    if (j < 64){
      #pragma unroll
      for (int i=0;i<16;i++){
        Qs[j][i*4+0] = f2bf(rv[i].x);
        Qs[j][i*4+1] = f2bf(rv[i].y);
        Qs[j][i*4+2] = f2bf(rv[i].z);
        Qs[j][i*4+3] = f2bf(rv[i].w);
      }
    }
  } else {
    int j = tid - 128;
    const uint4* vp = (const uint4*)(vB + (((size_t)bh << 12) + posk[j]) * 64);
    #pragma unroll
    for (int i=0;i<8;i++){
      uint4 vv = vp[i];
      Vt[i*8+0][j] = (u16)(vv.x & 0xFFFF);  Vt[i*8+1][j] = (u16)(vv.x >> 16);
      Vt[i*8+2][j] = (u16)(vv.y & 0xFFFF);  Vt[i*8+3][j] = (u16)(vv.y >> 16);
      Vt[i*8+4][j] = (u16)(vv.z & 0xFFFF);  Vt[i*8+5][j] = (u16)(vv.z >> 16);
      Vt[i*8+6][j] = (u16)(vv.w & 0xFFFF);  Vt[i*8+7][j] = (u16)(vv.w >> 16);
    }
  }
  __syncthreads();

  const int qr = w * 16;
  f32x4 zero = {0.f,0.f,0.f,0.f};
  f32x4 s[8];
  #pragma unroll
  for (int i=0;i<8;i++) s[i] = zero;
  #pragma unroll
  for (int kk=0; kk<64; kk+=32){
    i32x4 aq = *(const i32x4*)((const char*)&Qs[qr + lr][0] + kk*2 + lg*16);
    #pragma unroll
    for (int nf=0; nf<8; nf++){
      i32x4 kb = *(const i32x4*)((const char*)&Ks[nf*16 + lr][0] + kk*2 + lg*16);
      s[nf] = mfma16(aq, kb, s[nf]);
    }
  }

  float pv[8][4];
  int myq[4];
  #pragma unroll
  for (int r=0;r<4;r++) myq[r] = posk[qr + lg*4 + r];
  #pragma unroll
  for (int nf=0; nf<8; nf++){
    f32x4 sv = acc_fence(s[nf]);
    int pk = posk[nf*16 + lr];
    #pragma unroll
    for (int r=0;r<4;r++){
      float vv = sv[r] * 0.125f;
      if (myq[r] == pk) vv = -5e4f;
      pv[nf][r] = vv;
    }
  }
  #pragma unroll
  for (int r=0;r<4;r++){
    float m = pv[0][r];
    #pragma unroll
    for (int nf=1;nf<8;nf++) m = fmaxf(m, pv[nf][r]);
    m = fmaxf(m, __shfl_xor(m, 1));
    m = fmaxf(m, __shfl_xor(m, 2));
    m = fmaxf(m, __shfl_xor(m, 4));
    m = fmaxf(m, __shfl_xor(m, 8));
    float sum = 0.f;
    #pragma unroll
    for (int nf=0;nf<8;nf++) sum += __expf(pv[nf][r] - m);
    sum += __shfl_xor(sum, 1);
    sum += __shfl_xor(sum, 2);
    sum += __shfl_xor(sum, 4);
    sum += __shfl_xor(sum, 8);
    float lgt = m + logf(sum);
    #pragma unroll
    for (int nf=0;nf<8;nf++) pv[nf][r] = __expf(pv[nf][r] - lgt);
    if (lr == 0){
      int qrow = qr + lg*4 + r;
      lgt_out[(((size_t)(bh*4 + rnd)) << 12) + posk[qrow]] = lgt;
    }
  }
  #pragma unroll
  for (int nf=0;nf<8;nf++)
    #pragma unroll
    for (int r=0;r<4;r++)
      Ps[qr + lg*4 + r][nf*16 + lr] = f2bf(pv[nf][r]);
  __syncthreads();

  f32x4 o[4];
  #pragma unroll
  for (int i=0;i<4;i++) o[i] = zero;
  #pragma unroll
  for (int ks=0; ks<4; ks++){
    const int kk = ks*32;
    i32x4 pa = *(const i32x4*)((const char*)&Ps[qr + lr][0] + kk*2 + lg*16);
    #pragma unroll
    for (int nf=0;nf<4;nf++){
      i32x4 vb = *(const i32x4*)((const char*)&Vt[nf*16 + lr][0] + kk*2 + lg*16);
      o[nf] = mfma16(pa, vb, o[nf]);
    }
  }
  #pragma unroll
  for (int nf=0;nf<4;nf++){
    f32x4 ov = acc_fence(o[nf]);
    #pragma unroll
    for (int r=0;r<4;r++){
      int qrow = qr + lg*4 + r;
      size_t base = ((((size_t)(bh*4 + rnd)) << 12) + posk[qrow]) * 64;
      bo[base + nf*16 + lr] = f2bf(ov[r]);
    }
  }
}

// ---------------- combine hash rounds ----------------
__global__ __launch_bounds__(256) void k_combine(const u16* __restrict__ bo, const float* __restrict__ lgt,
                                                 u16* __restrict__ attn){
  const int wid = blockIdx.x * 4 + (threadIdx.x >> 6);
  const int l = threadIdx.x & 63;
  const int bh = wid >> 12, t = wid & 4095;
  const size_t lbase = (((size_t)bh) << 14) + t;
  float l0 = lgt[lbase], l1 = lgt[lbase + 4096], l2 = lgt[lbase + 8192], l3 = lgt[lbase + 12288];
  float m = fmaxf(fmaxf(l0,l1), fmaxf(l2,l3));
  float w0 = __expf(l0-m), w1 = __expf(l1-m), w2 = __expf(l2-m), w3 = __expf(l3-m);
  float inv = 1.f / (w0+w1+w2+w3);
  const size_t bbase = ((((size_t)bh) << 14) + t) * 64 + l;
  float o = w0 * bf2f(bo[bbase])
          + w1 * bf2f(bo[bbase + (size_t)4096*64])
          + w2 * bf2f(bo[bbase + (size_t)8192*64])
          + w3 * bf2f(bo[bbase + (size_t)12288*64]);
  o *= inv;
  int b = bh >> 3, h = bh & 7;
  attn[((((size_t)b) << 12) + t) * 512 + h*64 + l] = f2bf(o);
}

// ---------------- residual + LayerNorm ----------------
template<int WB16>
__global__ __launch_bounds__(256) void k_ln(const float* __restrict__ a, const float* __restrict__ res,
                                            const float* __restrict__ g, const float* __restrict__ bb,
                                            float* __restrict__ of, u16* __restrict__ ob){
  const int row = blockIdx.x*4 + (threadIdx.x >> 6);
  const int l = threadIdx.x & 63;
  const size_t base = (size_t)row*512 + l*8;
  float4 a0 = *(const float4*)(a + base);
  float4 a1 = *(const float4*)(a + base + 4);
  float4 r0 = *(const float4*)(res + base);
  float4 r1 = *(const float4*)(res + base + 4);
  float v[8] = {a0.x+r0.x, a0.y+r0.y, a0.z+r0.z, a0.w+r0.w,
                a1.x+r1.x, a1.y+r1.y, a1.z+r1.z, a1.w+r1.w};
  float sum = 0.f;
  #pragma unroll
  for (int j=0;j<8;j++) sum += v[j];
  #pragma unroll
  for (int msk=1; msk<64; msk<<=1) sum += __shfl_xor(sum, msk);
  float mean = sum * (1.f/512.f);
  float ss = 0.f;
  #pragma unroll
  for (int j=0;j<8;j++){ float d = v[j]-mean; ss += d*d; }
  #pragma unroll
  for (int msk=1; msk<64; msk<<=1) ss += __shfl_xor(ss, msk);
  float rstd = rsqrtf(ss * (1.f/512.f) + 1e-6f);
  float4 g0 = *(const float4*)(g + l*8),  g1 = *(const float4*)(g + l*8 + 4);
  float4 b0 = *(const float4*)(bb + l*8), b1 = *(const float4*)(bb + l*8 + 4);
  float gv[8] = {g0.x,g0.y,g0.z,g0.w,g1.x,g1.y,g1.z,g1.w};
  float bv[8] = {b0.x,b0.y,b0.z,b0.w,b1.x,b1.y,b1.z,b1.w};
  float y[8];
  #pragma unroll
  for (int j=0;j<8;j++) y[j] = (v[j]-mean)*rstd*gv[j] + bv[j];
  #pragma unroll
  for (int j=0;j<8;j++) of[base+j] = y[j];
  if (WB16){
    #pragma unroll
    for (int j=0;j<8;j++) ob[base+j] = f2bf(y[j]);
  }
}

extern "C" void kernel_launch(void* const* d_in, const int* in_sizes, int n_in,
                              void* d_out, int out_size, void* d_ws, size_t ws_size,
                              hipStream_t stream) {
  const float* x     = (const float*)d_in[0];
  const float* rot   = (const float*)d_in[1];
  const float* w_qk  = (const float*)d_in[2];
  const float* w_v   = (const float*)d_in[3];
  const float* w_out = (const float*)d_in[4];
  const float* b_out = (const float*)d_in[5];
  const float* ln1_g = (const float*)d_in[6];
  const float* ln1_b = (const float*)d_in[7];
  const float* w1    = (const float*)d_in[8];
  const float* b1    = (const float*)d_in[9];
  const float* w2    = (const float*)d_in[10];
  const float* b2    = (const float*)d_in[11];
  const float* ln2_g = (const float*)d_in[12];
  const float* ln2_b = (const float*)d_in[13];
  float* out = (float*)d_out;

  char* p = (char*)d_ws;
  u16*   xh   = (u16*)(p);                    // 16,777,216 B  (later: h bf16)
  u16*   xl   = (u16*)(p + 16777216);         // 16,777,216 B  (later: attn_c)
  u16*   wqkh = (u16*)(p + 33554432);
  u16*   wqkl = (u16*)(p + 34078720);
  u16*   wvb  = (u16*)(p + 34603008);
  u16*   wob  = (u16*)(p + 35127296);
  u16*   w1b  = (u16*)(p + 35651584);
  u16*   w2b  = (u16*)(p + 37748736);
  float* qkf  = (float*)(p + 39845888);       // 33,554,432 B  (later: h fp32)
  u16*   vb   = (u16*)(p + 73400320);
  int*   bkt  = (int*)(p + 90177536);
  int*   stb  = (int*)(p + 92274688);
  float* lgt  = (float*)(p + 94371840);
  u16*   bo   = (u16*)(p + 96468992);         // 67,108,864 B  (later: ffn hidden)
  // aliases (non-overlapping lifetimes)
  u16*   attnc = xl;
  float* hf    = qkf;
  u16*   hb    = xh;
  u16*   hid   = bo;

  // 1) dtype converts / splits
  k_split<<<8192, 256, 0, stream>>>(x, xh, xl, 16384*512/4);
  k_split<<<256,  256, 0, stream>>>(w_qk, wqkh, wqkl, 512*512/4);
  k_cvt  <<<256,  256, 0, stream>>>(w_v,   wvb, 512*512/4);
  k_cvt  <<<256,  256, 0, stream>>>(w_out, wob, 512*512/4);
  k_cvt  <<<1024, 256, 0, stream>>>(w1, w1b, 2048*512/4);
  k_cvt  <<<1024, 256, 0, stream>>>(w2, w2b, 2048*512/4);

  // 2) qk = x @ w_qk^T at ~fp32 (3-term split bf16), head layout fp32
  k_gemm<2><<<dim3(4,128), 256, 0, stream>>>(xh, xl, wqkh, wqkl, nullptr, qkf, nullptr, 16384, 512, 512, 3);
  // 3) v = x @ w_v^T, head layout bf16
  k_gemm<3><<<dim3(4,128), 256, 0, stream>>>(xh, nullptr, wvb, nullptr, nullptr, nullptr, vb, 16384, 512, 512, 1);
  // 4) LSH hash buckets (fp32)
  k_hash<<<dim3(32,16), 256, 0, stream>>>(qkf, rot, bkt);
  // 5) stable counting sort per (bh, round)
  k_sort<<<128, 64, 0, stream>>>(bkt, stb);
  // 6) chunked attention
  k_attn<<<dim3(256,32), 256, 0, stream>>>(qkf, vb, stb, lgt, bo);
  // 7) combine rounds -> (b,t,512) bf16
  k_combine<<<32768, 256, 0, stream>>>(bo, lgt, attnc);
  // 8) out projection (+bias) -> d_out (scratch)
  k_gemm<0><<<dim3(4,128), 256, 0, stream>>>(attnc, nullptr, wob, nullptr, b_out, out, nullptr, 16384, 512, 512, 1);
  // 9) h = LN(attn + x)
  k_ln<1><<<4096, 256, 0, stream>>>(out, x, ln1_g, ln1_b, hf, hb);
  // 10) hidden = relu(h @ w1^T + b1) bf16
  k_gemm<1><<<dim3(16,128), 256, 0, stream>>>(hb, nullptr, w1b, nullptr, b1, nullptr, hid, 16384, 2048, 512, 1);
  // 11) f = hidden @ w2^T + b2 -> d_out
  k_gemm<0><<<dim3(4,128), 256, 0, stream>>>(hid, nullptr, w2b, nullptr, b2, out, nullptr, 16384, 512, 2048, 1);
  // 12) out = LN(f + h)  (in place on d_out)
  k_ln<0><<<4096, 256, 0, stream>>>(out, hf, ln2_g, ln2_b, out, nullptr);
}

// Round 2
// 412.412 us; speedup vs baseline: 1.1561x; 1.1561x over previous
//
#include <hip/hip_runtime.h>
#include <stdint.h>

// Reformer layer: B=4 T=4096 D=512 H=8 DH=64 N_HASH=4 N_BUCKET=64 BUCKET=64 FFN=2048
typedef unsigned short u16;
typedef __attribute__((ext_vector_type(4))) int   i32x4;
typedef __attribute__((ext_vector_type(4))) float f32x4;

__device__ __forceinline__ u16 f2bf(float x){
  unsigned int u = __float_as_uint(x);
  u += 0x7FFFu + ((u >> 16) & 1u);
  return (u16)(u >> 16);
}
__device__ __forceinline__ float bf2f(u16 h){
  return __uint_as_float(((unsigned int)h) << 16);
}
__device__ __forceinline__ f32x4 mfma16(i32x4 a, i32x4 b, f32x4 c){
  asm("v_mfma_f32_16x16x32_bf16 %0, %1, %2, %0" : "+v"(c) : "v"(a), "v"(b));
  return c;
}
__device__ __forceinline__ f32x4 acc_fence(f32x4 c){
  asm volatile("s_nop 7\ns_nop 7" : "+v"(c));
  return c;
}
__device__ __forceinline__ void gl_lds16(const void* g, void* l){
  unsigned long long ga = (unsigned long long)g;
  unsigned int la = (unsigned int)(unsigned long long)l;
  __builtin_amdgcn_global_load_lds((const __attribute__((address_space(1))) void*)ga,
                                   (__attribute__((address_space(3))) void*)la, 16, 0, 0);
}

// ---------------- converts ----------------
__global__ __launch_bounds__(256) void k_cvt(const float* __restrict__ in, u16* __restrict__ out, int n4){
  int i = blockIdx.x*256 + threadIdx.x;
  if (i >= n4) return;
  float4 v = ((const float4*)in)[i];
  ushort4 o; o.x=f2bf(v.x); o.y=f2bf(v.y); o.z=f2bf(v.z); o.w=f2bf(v.w);
  ((ushort4*)out)[i] = o;
}
__global__ __launch_bounds__(256) void k_split(const float* __restrict__ in, u16* __restrict__ hi, u16* __restrict__ lo, int n4){
  int i = blockIdx.x*256 + threadIdx.x;
  if (i >= n4) return;
  float4 v = ((const float4*)in)[i];
  ushort4 h, l;
  h.x=f2bf(v.x); l.x=f2bf(v.x - bf2f(h.x));
  h.y=f2bf(v.y); l.y=f2bf(v.y - bf2f(h.y));
  h.z=f2bf(v.z); l.z=f2bf(v.z - bf2f(h.z));
  h.w=f2bf(v.w); l.w=f2bf(v.w - bf2f(h.w));
  ((ushort4*)hi)[i]=h; ((ushort4*)lo)[i]=l;
}

// ---------------- generic bf16 MFMA GEMM: C = sum_t A_t * B_t^T ----------------
template<int MODE>
__global__ __launch_bounds__(256) void k_gemm(
    const u16* __restrict__ A0, const u16* __restrict__ A1,
    const u16* __restrict__ B0, const u16* __restrict__ B1,
    const float* __restrict__ bias,
    float* __restrict__ Cf, u16* __restrict__ Cb,
    int M, int N, int K, int nterms)
{
  const int tid = threadIdx.x;
  const int l = tid & 63, w = tid >> 6;
  const int lr = l & 15, lg = l >> 4;
  const int m0 = blockIdx.y * 128, n0 = blockIdx.x * 128;
  const int mbase = (w >> 1) * 64, nbase = (w & 1) * 64;

  __shared__ __align__(16) u16 As[128*64];
  __shared__ __align__(16) u16 Bs[128*64];

  f32x4 zero = {0.f,0.f,0.f,0.f};
  f32x4 acc[4][4];
  #pragma unroll
  for (int i=0;i<4;i++)
    #pragma unroll
    for (int j=0;j<4;j++) acc[i][j] = zero;

  const int row_s = tid >> 3;
  const int c16   = tid & 7;

  for (int term = 0; term < nterms; ++term){
    const u16* Ap = (term==2) ? A1 : A0;
    const u16* Bp = (term==1) ? B1 : B0;
    for (int k0 = 0; k0 < K; k0 += 64){
      #pragma unroll
      for (int q=0;q<4;q++){
        int ra = q*32 + row_s;
        int cs = c16 ^ (ra & 7);
        gl_lds16(Ap + (size_t)(m0 + ra)*K + k0 + cs*8, (char*)As + q*4096 + tid*16);
        gl_lds16(Bp + (size_t)(n0 + ra)*K + k0 + cs*8, (char*)Bs + q*4096 + tid*16);
      }
      __syncthreads();
      #pragma unroll
      for (int kk=0; kk<64; kk+=32){
        i32x4 af[4], bfr[4];
        #pragma unroll
        for (int mf=0;mf<4;mf++){
          int row = mbase + mf*16 + lr;
          af[mf] = *(const i32x4*)((const char*)As + row*128 + (((kk*2) + (lg*16)) ^ ((row&7)<<4)));
        }
        #pragma unroll
        for (int nf=0;nf<4;nf++){
          int row = nbase + nf*16 + lr;
          bfr[nf] = *(const i32x4*)((const char*)Bs + row*128 + (((kk*2) + (lg*16)) ^ ((row&7)<<4)));
        }
        #pragma unroll
        for (int mf=0;mf<4;mf++)
          #pragma unroll
          for (int nf=0;nf<4;nf++)
            acc[mf][nf] = mfma16(af[mf], bfr[nf], acc[mf][nf]);
      }
      __syncthreads();
    }
  }

  #pragma unroll
  for (int mf=0;mf<4;mf++){
    #pragma unroll
    for (int nf=0;nf<4;nf++){
      f32x4 v = acc_fence(acc[mf][nf]);
      #pragma unroll
      for (int r=0;r<4;r++){
        int m = m0 + mbase + mf*16 + lg*4 + r;
        int n = n0 + nbase + nf*16 + lr;
        float val = v[r];
        if (MODE == 0){
          if (bias) val += bias[n];
          Cf[(size_t)m*N + n] = val;
        } else if (MODE == 1){
          val += bias[n];
          val = fmaxf(val, 0.f);
          Cb[(size_t)m*N + n] = f2bf(val);
        } else {
          int b = m >> 12, t = m & 4095, h = n >> 6, d = n & 63;
          size_t idx = ((((size_t)(b*8 + h)) << 12) + t)*64 + d;
          if (MODE == 2) Cf[idx] = val;
          else           Cb[idx] = f2bf(val);
        }
      }
    }
  }
}

// ---------------- prep: qb = bf16(qk), kn = bf16(normalize(qk)) ----------------
__global__ __launch_bounds__(256) void k_prep(const float* __restrict__ qkf,
                                              u16* __restrict__ qb, u16* __restrict__ kn){
  const int row = blockIdx.x*16 + (threadIdx.x >> 4);
  const int l16 = threadIdx.x & 15;
  float4 v = *(const float4*)(qkf + (size_t)row*64 + l16*4);
  float ss = v.x*v.x + v.y*v.y + v.z*v.z + v.w*v.w;
  ss += __shfl_xor(ss, 1); ss += __shfl_xor(ss, 2);
  ss += __shfl_xor(ss, 4); ss += __shfl_xor(ss, 8);
  float scale = 1.f / fmaxf(sqrtf(ss), 1e-6f);
  uint q0 = (uint)f2bf(v.x) | ((uint)f2bf(v.y)<<16);
  uint q1 = (uint)f2bf(v.z) | ((uint)f2bf(v.w)<<16);
  uint k0 = (uint)f2bf(v.x*scale) | ((uint)f2bf(v.y*scale)<<16);
  uint k1 = (uint)f2bf(v.z*scale) | ((uint)f2bf(v.w*scale)<<16);
  uint2 qo = {q0,q1}, ko = {k0,k1};
  ((uint2*)(qb + (size_t)row*64))[l16] = qo;
  ((uint2*)(kn + (size_t)row*64))[l16] = ko;
}

// ---------------- LSH hashing (fp32, precision-critical) ----------------
__global__ __launch_bounds__(256) void k_hash(const float* __restrict__ qk, const float* __restrict__ rot,
                                              int* __restrict__ buckets){
  const int bh = blockIdx.x, tb = blockIdx.y;
  const int tid = threadIdx.x;
  __shared__ float rotT[128][64];
  for (int idx = tid; idx < 8192; idx += 256)
    rotT[idx & 127][idx >> 7] = rot[idx];
  __syncthreads();
  const int tok = tb*256 + tid;
  const float4* qp = (const float4*)(qk + (((size_t)bh << 12) + tok) * 64);
  float4 q[16];
  #pragma unroll
  for (int i=0;i<16;i++) q[i] = qp[i];
  #pragma unroll
  for (int hh=0; hh<4; hh++){
    float maxv = -1e30f, minv = 1e30f; int maxi=0, mini=0;
    for (int i=0;i<32;i++){
      const float4* rp = (const float4*)(&rotT[hh*32+i][0]);
      float acc = 0.f;
      #pragma unroll
      for (int dd=0; dd<16; dd++){
        float4 r4 = rp[dd];
        acc += q[dd].x*r4.x + q[dd].y*r4.y + q[dd].z*r4.z + q[dd].w*r4.w;
      }
      if (acc > maxv){ maxv = acc; maxi = i; }
      if (acc < minv){ minv = acc; mini = i; }
    }
    int bkt = (maxv >= -minv) ? maxi : (32 + mini);
    buckets[(((size_t)(bh*4 + hh)) << 12) + tok] = bkt;
  }
}

// ---------------- stable counting sort per (bh, round) ----------------
__global__ __launch_bounds__(64) void k_sort(const int* __restrict__ buckets, int* __restrict__ st){
  const int grp = blockIdx.x;
  const int t = threadIdx.x;
  __shared__ int hist[64][65];
  __shared__ int tot[64];
  const size_t gbase = ((size_t)grp) << 12;
  #pragma unroll
  for (int b=0;b<64;b++) hist[t][b] = 0;
  __syncthreads();
  for (int i=0;i<64;i++){
    int b = buckets[gbase + t*64 + i];
    hist[t][b]++;
  }
  __syncthreads();
  { int run = 0;
    for (int tt=0; tt<64; tt++){ int v = hist[tt][t]; hist[tt][t] = run; run += v; }
    tot[t] = run; }
  __syncthreads();
  { int v = tot[t]; int incl = v;
    #pragma unroll
    for (int d=1; d<64; d<<=1){ int n = __shfl_up(incl, d, 64); if (t >= d) incl += n; }
    tot[t] = incl - v; }
  __syncthreads();
  const size_t obase = (((size_t)(grp>>2)) << 14) + ((size_t)(grp&3) << 12);
  for (int i=0;i<64;i++){
    int e = t*64 + i;
    int b = buckets[gbase + e];
    int dest = tot[b] + hist[t][b];
    hist[t][b]++;
    st[obase + dest] = e;
  }
}

// ---------------- chunked LSH attention v2: swapped QK^T, in-reg softmax ----------------
__global__ __launch_bounds__(256, 4) void k_attn(
    const u16* __restrict__ qb, const u16* __restrict__ kn, const u16* __restrict__ vB,
    const int* __restrict__ st, float* __restrict__ lgt_out, u16* __restrict__ bo)
{
  const int c = blockIdx.x, bh = blockIdx.y;
  const int rnd = c >> 6;
  const int tid = threadIdx.x;
  const int l = tid & 63, w = tid >> 6, lr = l & 15, lg = l >> 4;

  __shared__ __align__(16) u16 Ks[128*64];     // linear rows of 128B, XOR-swizzled content
  __shared__ __align__(16) u16 Vt[64][136];    // [d][k] blocked-k order, 272B stride
  __shared__ int posk[128];

  if (tid < 128){
    int cc = (tid < 64) ? c : ((c + 255) & 255);
    posk[tid] = st[(((size_t)bh) << 14) + (cc << 6) + (tid & 63)];
  }
  __syncthreads();

  const size_t kvbase = ((size_t)bh) << 12;

  // --- stage normalized K via global_load_lds (pre-swizzled source, linear dest) ---
  {
    const int rsub = l >> 3, c8 = l & 7;
    #pragma unroll
    for (int q2 = 0; q2 < 4; q2++){
      int row = w*32 + q2*8 + rsub;
      int cs = c8 ^ (row & 7);
      gl_lds16(kn + (kvbase + posk[row])*64 + cs*8,
               (char*)Ks + (w*4 + q2)*1024 + l*16);
    }
  }

  // --- Q fragments straight to registers (each wave owns 16 q-rows) ---
  const int pos_q16 = posk[w*16 + lr];
  i32x4 qf[2];
  #pragma unroll
  for (int ks = 0; ks < 2; ks++)
    qf[ks] = *(const i32x4*)(qb + (kvbase + pos_q16)*64 + ks*32 + lg*8);

  // --- V gather + register transpose into blocked-k Vt (conflict-free b32 writes) ---
  {
    const int pp = tid & 63, db = tid >> 6;
    const int q5 = pp & 15;
    const int K0 = (pp >> 4)*32 + 16*((q5 >> 1) & 1) + 4*(q5 >> 2) + 2*(q5 & 1);
    const u16* r0 = vB + (kvbase + posk[K0])*64 + db*16;
    const u16* r1 = vB + (kvbase + posk[K0+1])*64 + db*16;
    uint4 a0 = *(const uint4*)r0, a1 = *(const uint4*)(r0 + 8);
    uint4 b0 = *(const uint4*)r1, b1 = *(const uint4*)(r1 + 8);
    uint av[8] = {a0.x,a0.y,a0.z,a0.w,a1.x,a1.y,a1.z,a1.w};
    uint bv[8] = {b0.x,b0.y,b0.z,b0.w,b1.x,b1.y,b1.z,b1.w};
    #pragma unroll
    for (int dd = 0; dd < 16; dd++){
      uint lo = (av[dd>>1] >> ((dd&1)*16)) & 0xFFFFu;
      uint hi = (bv[dd>>1] >> ((dd&1)*16)) & 0xFFFFu;
      *(uint*)((char*)&Vt[db*16 + dd][0] + pp*4) = lo | (hi << 16);
    }
  }
  __syncthreads();

  // --- S = K · Q^T (swapped): lane holds S[k=nf*16+lg*4+r][q=w*16+lr] ---
  f32x4 zero = {0.f,0.f,0.f,0.f};
  f32x4 s[8];
  #pragma unroll
  for (int i=0;i<8;i++) s[i] = zero;
  #pragma unroll
  for (int ks = 0; ks < 2; ks++){
    #pragma unroll
    for (int nf = 0; nf < 8; nf++){
      int row = nf*16 + lr;
      i32x4 kf = *(const i32x4*)((const char*)Ks + row*128 + ((ks*64 + lg*16) ^ ((row&7)<<4)));
      s[nf] = mfma16(kf, qf[ks], s[nf]);
    }
  }

  // --- mask + in-register softmax (reduce over 32 local + 2 shfl) ---
  float sv[8][4];
  const int q_loc = w*16 + lr;
  #pragma unroll
  for (int nf=0;nf<8;nf++){
    f32x4 t = acc_fence(s[nf]);
    #pragma unroll
    for (int r=0;r<4;r++){
      int k = nf*16 + lg*4 + r;
      sv[nf][r] = (k == q_loc) ? -5e4f : t[r]*0.125f;
    }
  }
  float m = -1e30f;
  #pragma unroll
  for (int nf=0;nf<8;nf++)
    #pragma unroll
    for (int r=0;r<4;r++) m = fmaxf(m, sv[nf][r]);
  m = fmaxf(m, __shfl_xor(m, 16));
  m = fmaxf(m, __shfl_xor(m, 32));
  float sum = 0.f;
  #pragma unroll
  for (int nf=0;nf<8;nf++)
    #pragma unroll
    for (int r=0;r<4;r++) sum += __expf(sv[nf][r] - m);
  sum += __shfl_xor(sum, 16);
  sum += __shfl_xor(sum, 32);
  float lv = m + logf(sum);
  if (l < 16)
    lgt_out[(((size_t)(bh*4 + rnd)) << 12) + pos_q16] = lv;

  // --- P -> bf16, lane-local A fragments ---
  i32x4 pa[4];
  #pragma unroll
  for (int ks=0;ks<4;ks++){
    uint wd[4];
    #pragma unroll
    for (int h2=0; h2<2; h2++){
      int nf = 2*ks + h2;
      float p0 = __expf(sv[nf][0]-lv), p1 = __expf(sv[nf][1]-lv);
      float p2 = __expf(sv[nf][2]-lv), p3 = __expf(sv[nf][3]-lv);
      wd[h2*2]   = (uint)f2bf(p0) | ((uint)f2bf(p1)<<16);
      wd[h2*2+1] = (uint)f2bf(p2) | ((uint)f2bf(p3)<<16);
    }
    i32x4 t = {(int)wd[0],(int)wd[1],(int)wd[2],(int)wd[3]};
    pa[ks] = t;
  }

  // --- O = P · V ---
  f32x4 o[4];
  #pragma unroll
  for (int i=0;i<4;i++) o[i] = zero;
  #pragma unroll
  for (int ks=0;ks<4;ks++){
    #pragma unroll
    for (int nf=0;nf<4;nf++){
      i32x4 vf = *(const i32x4*)((const char*)&Vt[nf*16 + lr][0] + ks*64 + lg*16);
      o[nf] = mfma16(pa[ks], vf, o[nf]);
    }
  }
  #pragma unroll
  for (int nf=0;nf<4;nf++){
    f32x4 ov = acc_fence(o[nf]);
    #pragma unroll
    for (int r=0;r<4;r++){
      int q = w*16 + lg*4 + r;
      bo[((((size_t)(bh*4 + rnd)) << 12) + posk[q])*64 + nf*16 + lr] = f2bf(ov[r]);
    }
  }
}

// ---------------- combine hash rounds ----------------
__global__ __launch_bounds__(256) void k_combine(const u16* __restrict__ bo, const float* __restrict__ lgt,
                                                 u16* __restrict__ attn){
  const int wid = blockIdx.x * 4 + (threadIdx.x >> 6);
  const int l = threadIdx.x & 63;
  const int bh = wid >> 12, t = wid & 4095;
  const size_t lbase = (((size_t)bh) << 14) + t;
  float l0 = lgt[lbase], l1 = lgt[lbase + 4096], l2 = lgt[lbase + 8192], l3 = lgt[lbase + 12288];
  float m = fmaxf(fmaxf(l0,l1), fmaxf(l2,l3));
  float w0 = __expf(l0-m), w1 = __expf(l1-m), w2 = __expf(l2-m), w3 = __expf(l3-m);
  float inv = 1.f / (w0+w1+w2+w3);
  const size_t bbase = ((((size_t)bh) << 14) + t) * 64 + l;
  float o = w0 * bf2f(bo[bbase])
          + w1 * bf2f(bo[bbase + (size_t)4096*64])
          + w2 * bf2f(bo[bbase + (size_t)8192*64])
          + w3 * bf2f(bo[bbase + (size_t)12288*64]);
  o *= inv;
  int b = bh >> 3, h = bh & 7;
  attn[((((size_t)b) << 12) + t) * 512 + h*64 + l] = f2bf(o);
}

// ---------------- residual + LayerNorm ----------------
template<int WB16>
__global__ __launch_bounds__(256) void k_ln(const float* __restrict__ a, const float* __restrict__ res,
                                            const float* __restrict__ g, const float* __restrict__ bb,
                                            float* __restrict__ of, u16* __restrict__ ob){
  const int row = blockIdx.x*4 + (threadIdx.x >> 6);
  const int l = threadIdx.x & 63;
  const size_t base = (size_t)row*512 + l*8;
  float4 a0 = *(const float4*)(a + base);
  float4 a1 = *(const float4*)(a + base + 4);
  float4 r0 = *(const float4*)(res + base);
  float4 r1 = *(const float4*)(res + base + 4);
  float v[8] = {a0.x+r0.x, a0.y+r0.y, a0.z+r0.z, a0.w+r0.w,
                a1.x+r1.x, a1.y+r1.y, a1.z+r1.z, a1.w+r1.w};
  float sum = 0.f;
  #pragma unroll
  for (int j=0;j<8;j++) sum += v[j];
  #pragma unroll
  for (int msk=1; msk<64; msk<<=1) sum += __shfl_xor(sum, msk);
  float mean = sum * (1.f/512.f);
  float ss = 0.f;
  #pragma unroll
  for (int j=0;j<8;j++){ float d = v[j]-mean; ss += d*d; }
  #pragma unroll
  for (int msk=1; msk<64; msk<<=1) ss += __shfl_xor(ss, msk);
  float rstd = rsqrtf(ss * (1.f/512.f) + 1e-6f);
  float4 g0 = *(const float4*)(g + l*8),  g1 = *(const float4*)(g + l*8 + 4);
  float4 b0 = *(const float4*)(bb + l*8), b1 = *(const float4*)(bb + l*8 + 4);
  float gv[8] = {g0.x,g0.y,g0.z,g0.w,g1.x,g1.y,g1.z,g1.w};
  float bv[8] = {b0.x,b0.y,b0.z,b0.w,b1.x,b1.y,b1.z,b1.w};
  float y[8];
  #pragma unroll
  for (int j=0;j<8;j++) y[j] = (v[j]-mean)*rstd*gv[j] + bv[j];
  #pragma unroll
  for (int j=0;j<8;j++) of[base+j] = y[j];
  if (WB16){
    #pragma unroll
    for (int j=0;j<8;j++) ob[base+j] = f2bf(y[j]);
  }
}

extern "C" void kernel_launch(void* const* d_in, const int* in_sizes, int n_in,
                              void* d_out, int out_size, void* d_ws, size_t ws_size,
                              hipStream_t stream) {
  const float* x     = (const float*)d_in[0];
  const float* rot   = (const float*)d_in[1];
  const float* w_qk  = (const float*)d_in[2];
  const float* w_v   = (const float*)d_in[3];
  const float* w_out = (const float*)d_in[4];
  const float* b_out = (const float*)d_in[5];
  const float* ln1_g = (const float*)d_in[6];
  const float* ln1_b = (const float*)d_in[7];
  const float* w1    = (const float*)d_in[8];
  const float* b1    = (const float*)d_in[9];
  const float* w2    = (const float*)d_in[10];
  const float* b2    = (const float*)d_in[11];
  const float* ln2_g = (const float*)d_in[12];
  const float* ln2_b = (const float*)d_in[13];
  float* out = (float*)d_out;

  char* p = (char*)d_ws;
  u16*   xh   = (u16*)(p);                    // x-hi   | later: qb, then hb
  u16*   xl   = (u16*)(p + 16777216);         // x-lo   | later: kn, then attnc
  u16*   wqkh = (u16*)(p + 33554432);
  u16*   wqkl = (u16*)(p + 34078720);
  u16*   wvb  = (u16*)(p + 34603008);
  u16*   wob  = (u16*)(p + 35127296);
  u16*   w1b  = (u16*)(p + 35651584);
  u16*   w2b  = (u16*)(p + 37748736);
  float* qkf  = (float*)(p + 39845888);       // fp32 qk | later: hf
  u16*   vb   = (u16*)(p + 73400320);
  int*   bkt  = (int*)(p + 90177536);
  int*   stb  = (int*)(p + 92274688);
  float* lgt  = (float*)(p + 94371840);
  u16*   bo   = (u16*)(p + 96468992);         // 67 MB  | later: ffn hidden
  // aliases (non-overlapping lifetimes)
  u16*   qbuf  = xh;    // after v-gemm consumed xh
  u16*   knb   = xl;    // after qk-gemm consumed xl
  u16*   attnc = xl;
  float* hf    = qkf;
  u16*   hb    = xh;
  u16*   hid   = bo;

  // 1) dtype converts / splits
  k_split<<<8192, 256, 0, stream>>>(x, xh, xl, 16384*512/4);
  k_split<<<256,  256, 0, stream>>>(w_qk, wqkh, wqkl, 512*512/4);
  k_cvt  <<<256,  256, 0, stream>>>(w_v,   wvb, 512*512/4);
  k_cvt  <<<256,  256, 0, stream>>>(w_out, wob, 512*512/4);
  k_cvt  <<<1024, 256, 0, stream>>>(w1, w1b, 2048*512/4);
  k_cvt  <<<1024, 256, 0, stream>>>(w2, w2b, 2048*512/4);

  // 2) qk = x @ w_qk^T at ~fp32 (3-term split bf16), head layout fp32
  k_gemm<2><<<dim3(4,128), 256, 0, stream>>>(xh, xl, wqkh, wqkl, nullptr, qkf, nullptr, 16384, 512, 512, 3);
  // 3) v = x @ w_v^T, head layout bf16
  k_gemm<3><<<dim3(4,128), 256, 0, stream>>>(xh, nullptr, wvb, nullptr, nullptr, nullptr, vb, 16384, 512, 512, 1);
  // 4) prep: qb (bf16) + kn (bf16 normalized) — xh/xl now free
  k_prep<<<8192, 256, 0, stream>>>(qkf, qbuf, knb);
  // 5) LSH hash buckets (fp32)
  k_hash<<<dim3(32,16), 256, 0, stream>>>(qkf, rot, bkt);
  // 6) stable counting sort per (bh, round)
  k_sort<<<128, 64, 0, stream>>>(bkt, stb);
  // 7) chunked attention
  k_attn<<<dim3(256,32), 256, 0, stream>>>(qbuf, knb, vb, stb, lgt, bo);
  // 8) combine rounds -> (b,t,512) bf16
  k_combine<<<32768, 256, 0, stream>>>(bo, lgt, attnc);
  // 9) out projection (+bias) -> d_out (scratch)
  k_gemm<0><<<dim3(4,128), 256, 0, stream>>>(attnc, nullptr, wob, nullptr, b_out, out, nullptr, 16384, 512, 512, 1);
  // 10) h = LN(attn + x)
  k_ln<1><<<4096, 256, 0, stream>>>(out, x, ln1_g, ln1_b, hf, hb);
  // 11) hidden = relu(h @ w1^T + b1) bf16
  k_gemm<1><<<dim3(16,128), 256, 0, stream>>>(hb, nullptr, w1b, nullptr, b1, nullptr, hid, 16384, 2048, 512, 1);
  // 12) f = hidden @ w2^T + b2 -> d_out
  k_gemm<0><<<dim3(4,128), 256, 0, stream>>>(hid, nullptr, w2b, nullptr, b2, out, nullptr, 16384, 512, 2048, 1);
  // 13) out = LN(f + h)  (in place on d_out)
  k_ln<0><<<4096, 256, 0, stream>>>(out, hf, ln2_g, ln2_b, out, nullptr);
}

// Round 3
// 373.716 us; speedup vs baseline: 1.2759x; 1.1035x over previous
//
#include <hip/hip_runtime.h>
#include <stdint.h>

// Reformer layer: B=4 T=4096 D=512 H=8 DH=64 N_HASH=4 N_BUCKET=64 BUCKET=64 FFN=2048
typedef unsigned short u16;
typedef __attribute__((ext_vector_type(4))) int   i32x4;
typedef __attribute__((ext_vector_type(4))) float f32x4;

__device__ __forceinline__ u16 f2bf(float x){
  unsigned int u = __float_as_uint(x);
  u += 0x7FFFu + ((u >> 16) & 1u);
  return (u16)(u >> 16);
}
__device__ __forceinline__ float bf2f(u16 h){
  return __uint_as_float(((unsigned int)h) << 16);
}
__device__ __forceinline__ f32x4 mfma16(i32x4 a, i32x4 b, f32x4 c){
  asm("v_mfma_f32_16x16x32_bf16 %0, %1, %2, %0" : "+v"(c) : "v"(a), "v"(b));
  return c;
}
__device__ __forceinline__ f32x4 acc_fence(f32x4 c){
  asm volatile("s_nop 7\ns_nop 7" : "+v"(c));
  return c;
}
__device__ __forceinline__ void gl_lds16(const void* g, void* l){
  unsigned long long ga = (unsigned long long)g;
  unsigned int la = (unsigned int)(unsigned long long)l;
  __builtin_amdgcn_global_load_lds((const __attribute__((address_space(1))) void*)ga,
                                   (__attribute__((address_space(3))) void*)la, 16, 0, 0);
}
// monotonic-uint transform: order-preserving for fp32 compares
__device__ __forceinline__ unsigned int f2mono(float v){
  unsigned int u = __float_as_uint(v);
  return u ^ ((unsigned int)((int)u >> 31) | 0x80000000u);
}
__device__ __forceinline__ float mono2f(unsigned int mu){
  unsigned int u = (mu & 0x80000000u) ? (mu ^ 0x80000000u) : ~mu;
  return __uint_as_float(u);
}
__device__ __forceinline__ unsigned long long shfl_xor_u64(unsigned long long x, int m){
  int lo = __shfl_xor((int)(unsigned int)(x & 0xFFFFFFFFull), m);
  int hi = __shfl_xor((int)(unsigned int)(x >> 32), m);
  return ((unsigned long long)(unsigned int)hi << 32) | (unsigned int)lo;
}

// ---------------- converts ----------------
__global__ __launch_bounds__(256) void k_cvt(const float* __restrict__ in, u16* __restrict__ out, int n4){
  int i = blockIdx.x*256 + threadIdx.x;
  if (i >= n4) return;
  float4 v = ((const float4*)in)[i];
  ushort4 o; o.x=f2bf(v.x); o.y=f2bf(v.y); o.z=f2bf(v.z); o.w=f2bf(v.w);
  ((ushort4*)out)[i] = o;
}
__global__ __launch_bounds__(256) void k_split(const float* __restrict__ in, u16* __restrict__ hi, u16* __restrict__ lo, int n4){
  int i = blockIdx.x*256 + threadIdx.x;
  if (i >= n4) return;
  float4 v = ((const float4*)in)[i];
  ushort4 h, l;
  h.x=f2bf(v.x); l.x=f2bf(v.x - bf2f(h.x));
  h.y=f2bf(v.y); l.y=f2bf(v.y - bf2f(h.y));
  h.z=f2bf(v.z); l.z=f2bf(v.z - bf2f(h.z));
  h.w=f2bf(v.w); l.w=f2bf(v.w - bf2f(h.w));
  ((ushort4*)hi)[i]=h; ((ushort4*)lo)[i]=l;
}
// rot (64 x 4 x 32) -> rotT[n=h*32+i][d] bf16 hi/lo
__global__ __launch_bounds__(256) void k_rotT(const float* __restrict__ rot, u16* __restrict__ hi, u16* __restrict__ lo){
  int i = blockIdx.x*256 + threadIdx.x;
  if (i >= 8192) return;
  int d = i & 63, n = i >> 6;
  float v = rot[d*128 + n];
  u16 h = f2bf(v);
  hi[i] = h; lo[i] = f2bf(v - bf2f(h));
}

// ---------------- generic bf16 MFMA GEMM: C = sum_t A_t * B_t^T ----------------
// MODE 0: fp32 rowmajor (+bias)   MODE 1: bf16 rowmajor, bias+relu
// MODE 2: fp32 head-layout (qk)   MODE 3: bf16 head-layout (v)
// MODE 4: LSH bucket epilogue (argmax over [S,-S] per 32-col hash group)
template<int MODE>
__global__ __launch_bounds__(256) void k_gemm(
    const u16* __restrict__ A0, const u16* __restrict__ A1,
    const u16* __restrict__ B0, const u16* __restrict__ B1,
    const float* __restrict__ bias,
    float* __restrict__ Cf, u16* __restrict__ Cb, int* __restrict__ Bkt,
    int M, int N, int K, int nterms)
{
  const int tid = threadIdx.x;
  const int l = tid & 63, w = tid >> 6;
  const int lr = l & 15, lg = l >> 4;
  const int m0 = blockIdx.y * 128, n0 = blockIdx.x * 128;
  const int mbase = (w >> 1) * 64, nbase = (w & 1) * 64;

  __shared__ __align__(16) u16 As[128*64];
  __shared__ __align__(16) u16 Bs[128*64];

  f32x4 zero = {0.f,0.f,0.f,0.f};
  f32x4 acc[4][4];
  #pragma unroll
  for (int i=0;i<4;i++)
    #pragma unroll
    for (int j=0;j<4;j++) acc[i][j] = zero;

  const int row_s = tid >> 3;
  const int c16   = tid & 7;

  for (int term = 0; term < nterms; ++term){
    const u16* Ap = (term==2) ? A1 : A0;
    const u16* Bp = (term==1) ? B1 : B0;
    for (int k0 = 0; k0 < K; k0 += 64){
      #pragma unroll
      for (int q=0;q<4;q++){
        int ra = q*32 + row_s;
        int cs = c16 ^ (ra & 7);
        gl_lds16(Ap + (size_t)(m0 + ra)*K + k0 + cs*8, (char*)As + q*4096 + tid*16);
        gl_lds16(Bp + (size_t)(n0 + ra)*K + k0 + cs*8, (char*)Bs + q*4096 + tid*16);
      }
      __syncthreads();
      #pragma unroll
      for (int kk=0; kk<64; kk+=32){
        i32x4 af[4], bfr[4];
        #pragma unroll
        for (int mf=0;mf<4;mf++){
          int row = mbase + mf*16 + lr;
          af[mf] = *(const i32x4*)((const char*)As + row*128 + (((kk*2) + (lg*16)) ^ ((row&7)<<4)));
        }
        #pragma unroll
        for (int nf=0;nf<4;nf++){
          int row = nbase + nf*16 + lr;
          bfr[nf] = *(const i32x4*)((const char*)Bs + row*128 + (((kk*2) + (lg*16)) ^ ((row&7)<<4)));
        }
        #pragma unroll
        for (int mf=0;mf<4;mf++)
          #pragma unroll
          for (int nf=0;nf<4;nf++)
            acc[mf][nf] = mfma16(af[mf], bfr[nf], acc[mf][nf]);
      }
      __syncthreads();
    }
  }

  if (MODE == 4){
    // each lg group holds rows m = m0+mbase+mf*16+lg*4+r across lr lanes;
    // columns n = nbase+nf*16+lr; hash group hh = n>>5, j = n&31.
    #pragma unroll
    for (int mf=0;mf<4;mf++){
      f32x4 v[4];
      #pragma unroll
      for (int nf=0;nf<4;nf++) v[nf] = acc_fence(acc[mf][nf]);
      #pragma unroll
      for (int r=0;r<4;r++){
        #pragma unroll
        for (int hp=0;hp<2;hp++){
          float va = v[2*hp][r], vb2 = v[2*hp+1][r];
          unsigned int ma = f2mono(va), mb = f2mono(vb2);
          // key = mono<<32 | (31-j): max picks larger val, ties -> smaller j (numpy-first)
          unsigned long long kmax = ((unsigned long long)ma<<32) | (unsigned int)(31-lr);
          unsigned long long t2   = ((unsigned long long)mb<<32) | (unsigned int)(15-lr);
          if (t2 > kmax) kmax = t2;
          unsigned long long kmin = ((unsigned long long)(~ma)<<32) | (unsigned int)(31-lr);
          unsigned long long t3   = ((unsigned long long)(~mb)<<32) | (unsigned int)(15-lr);
          if (t3 > kmin) kmin = t3;
          #pragma unroll
          for (int d2=1; d2<16; d2<<=1){
            unsigned long long o1 = shfl_xor_u64(kmax, d2);
            if (o1 > kmax) kmax = o1;
            unsigned long long o2 = shfl_xor_u64(kmin, d2);
            if (o2 > kmin) kmin = o2;
          }
          if (lr == 0){
            unsigned int mumax = (unsigned int)(kmax>>32);
            int jmax = 31 - (int)(kmax & 0xFFFFFFFFull);
            float vmax = mono2f(mumax);
            unsigned int mumin = ~(unsigned int)(kmin>>32);
            int jmin = 31 - (int)(kmin & 0xFFFFFFFFull);
            float vmin = mono2f(mumin);
            int bucket = (vmax >= -vmin) ? jmax : 32 + jmin;
            int m = m0 + mbase + mf*16 + lg*4 + r;
            int hh2 = (nbase>>5) + hp;
            Bkt[((size_t)((m>>12)*4 + hh2) << 12) + (m & 4095)] = bucket;
          }
        }
      }
    }
    return;
  }

  #pragma unroll
  for (int mf=0;mf<4;mf++){
    #pragma unroll
    for (int nf=0;nf<4;nf++){
      f32x4 v = acc_fence(acc[mf][nf]);
      #pragma unroll
      for (int r=0;r<4;r++){
        int m = m0 + mbase + mf*16 + lg*4 + r;
        int n = n0 + nbase + nf*16 + lr;
        float val = v[r];
        if (MODE == 0){
          if (bias) val += bias[n];
          Cf[(size_t)m*N + n] = val;
        } else if (MODE == 1){
          val += bias[n];
          val = fmaxf(val, 0.f);
          Cb[(size_t)m*N + n] = f2bf(val);
        } else {
          int b = m >> 12, t = m & 4095, h = n >> 6, d = n & 63;
          size_t idx = ((((size_t)(b*8 + h)) << 12) + t)*64 + d;
          if (MODE == 2) Cf[idx] = val;
          else           Cb[idx] = f2bf(val);
        }
      }
    }
  }
}

// ---------------- prep: qb/qlo = bf16 hi/lo of qk, kn = bf16(normalize(qk)) ----------------
__global__ __launch_bounds__(256) void k_prep(const float* __restrict__ qkf,
                                              u16* __restrict__ qb, u16* __restrict__ qlo,
                                              u16* __restrict__ kn){
  const int row = blockIdx.x*16 + (threadIdx.x >> 4);
  const int l16 = threadIdx.x & 15;
  float4 v = *(const float4*)(qkf + (size_t)row*64 + l16*4);
  float ss = v.x*v.x + v.y*v.y + v.z*v.z + v.w*v.w;
  ss += __shfl_xor(ss, 1); ss += __shfl_xor(ss, 2);
  ss += __shfl_xor(ss, 4); ss += __shfl_xor(ss, 8);
  float scale = 1.f / fmaxf(sqrtf(ss), 1e-6f);
  u16 h0=f2bf(v.x), h1=f2bf(v.y), h2=f2bf(v.z), h3=f2bf(v.w);
  uint q0 = (uint)h0 | ((uint)h1<<16);
  uint q1 = (uint)h2 | ((uint)h3<<16);
  uint e0 = (uint)f2bf(v.x-bf2f(h0)) | ((uint)f2bf(v.y-bf2f(h1))<<16);
  uint e1 = (uint)f2bf(v.z-bf2f(h2)) | ((uint)f2bf(v.w-bf2f(h3))<<16);
  uint k0 = (uint)f2bf(v.x*scale) | ((uint)f2bf(v.y*scale)<<16);
  uint k1 = (uint)f2bf(v.z*scale) | ((uint)f2bf(v.w*scale)<<16);
  uint2 qo = {q0,q1}, eo = {e0,e1}, ko = {k0,k1};
  ((uint2*)(qb  + (size_t)row*64))[l16] = qo;
  ((uint2*)(qlo + (size_t)row*64))[l16] = eo;
  ((uint2*)(kn  + (size_t)row*64))[l16] = ko;
}

// ---------------- stable counting sort per (bh, round) ----------------
__global__ __launch_bounds__(64) void k_sort(const int* __restrict__ buckets, int* __restrict__ st){
  const int grp = blockIdx.x;
  const int t = threadIdx.x;
  __shared__ int hist[64][65];
  __shared__ int tot[64];
  const size_t gbase = ((size_t)grp) << 12;
  #pragma unroll
  for (int b=0;b<64;b++) hist[t][b] = 0;
  __syncthreads();
  for (int i=0;i<64;i++){
    int b = buckets[gbase + t*64 + i];
    hist[t][b]++;
  }
  __syncthreads();
  { int run = 0;
    for (int tt=0; tt<64; tt++){ int v = hist[tt][t]; hist[tt][t] = run; run += v; }
    tot[t] = run; }
  __syncthreads();
  { int v = tot[t]; int incl = v;
    #pragma unroll
    for (int d=1; d<64; d<<=1){ int n = __shfl_up(incl, d, 64); if (t >= d) incl += n; }
    tot[t] = incl - v; }
  __syncthreads();
  const size_t obase = (((size_t)(grp>>2)) << 14) + ((size_t)(grp&3) << 12);
  for (int i=0;i<64;i++){
    int e = t*64 + i;
    int b = buckets[gbase + e];
    int dest = tot[b] + hist[t][b];
    hist[t][b]++;
    st[obase + dest] = e;
  }
}

// ---------------- chunked LSH attention: swapped QK^T, in-reg softmax ----------------
__global__ __launch_bounds__(256, 4) void k_attn(
    const u16* __restrict__ qb, const u16* __restrict__ kn, const u16* __restrict__ vB,
    const int* __restrict__ st, float* __restrict__ lgt_out, u16* __restrict__ bo)
{
  const int c = blockIdx.x, bh = blockIdx.y;
  const int rnd = c >> 6;
  const int tid = threadIdx.x;
  const int l = tid & 63, w = tid >> 6, lr = l & 15, lg = l >> 4;

  __shared__ __align__(16) u16 Ks[128*64];
  __shared__ __align__(16) u16 Vt[64][136];
  __shared__ int posk[128];

  if (tid < 128){
    int cc = (tid < 64) ? c : ((c + 255) & 255);
    posk[tid] = st[(((size_t)bh) << 14) + (cc << 6) + (tid & 63)];
  }
  __syncthreads();

  const size_t kvbase = ((size_t)bh) << 12;

  {
    const int rsub = l >> 3, c8 = l & 7;
    #pragma unroll
    for (int q2 = 0; q2 < 4; q2++){
      int row = w*32 + q2*8 + rsub;
      int cs = c8 ^ (row & 7);
      gl_lds16(kn + (kvbase + posk[row])*64 + cs*8,
               (char*)Ks + (w*4 + q2)*1024 + l*16);
    }
  }

  const int pos_q16 = posk[w*16 + lr];
  i32x4 qf[2];
  #pragma unroll
  for (int ks = 0; ks < 2; ks++)
    qf[ks] = *(const i32x4*)(qb + (kvbase + pos_q16)*64 + ks*32 + lg*8);

  {
    const int pp = tid & 63, db = tid >> 6;
    const int q5 = pp & 15;
    const int K0 = (pp >> 4)*32 + 16*((q5 >> 1) & 1) + 4*(q5 >> 2) + 2*(q5 & 1);
    const u16* r0 = vB + (kvbase + posk[K0])*64 + db*16;
    const u16* r1 = vB + (kvbase + posk[K0+1])*64 + db*16;
    uint4 a0 = *(const uint4*)r0, a1 = *(const uint4*)(r0 + 8);
    uint4 b0 = *(const uint4*)r1, b1 = *(const uint4*)(r1 + 8);
    uint av[8] = {a0.x,a0.y,a0.z,a0.w,a1.x,a1.y,a1.z,a1.w};
    uint bv[8] = {b0.x,b0.y,b0.z,b0.w,b1.x,b1.y,b1.z,b1.w};
    #pragma unroll
    for (int dd = 0; dd < 16; dd++){
      uint lo = (av[dd>>1] >> ((dd&1)*16)) & 0xFFFFu;
      uint hi = (bv[dd>>1] >> ((dd&1)*16)) & 0xFFFFu;
      *(uint*)((char*)&Vt[db*16 + dd][0] + pp*4) = lo | (hi << 16);
    }
  }
  __syncthreads();

  f32x4 zero = {0.f,0.f,0.f,0.f};
  f32x4 s[8];
  #pragma unroll
  for (int i=0;i<8;i++) s[i] = zero;
  #pragma unroll
  for (int ks = 0; ks < 2; ks++){
    #pragma unroll
    for (int nf = 0; nf < 8; nf++){
      int row = nf*16 + lr;
      i32x4 kf = *(const i32x4*)((const char*)Ks + row*128 + ((ks*64 + lg*16) ^ ((row&7)<<4)));
      s[nf] = mfma16(kf, qf[ks], s[nf]);
    }
  }

  float sv[8][4];
  const int q_loc = w*16 + lr;
  #pragma unroll
  for (int nf=0;nf<8;nf++){
    f32x4 t = acc_fence(s[nf]);
    #pragma unroll
    for (int r=0;r<4;r++){
      int k = nf*16 + lg*4 + r;
      sv[nf][r] = (k == q_loc) ? -5e4f : t[r]*0.125f;
    }
  }
  float m = -1e30f;
  #pragma unroll
  for (int nf=0;nf<8;nf++)
    #pragma unroll
    for (int r=0;r<4;r++) m = fmaxf(m, sv[nf][r]);
  m = fmaxf(m, __shfl_xor(m, 16));
  m = fmaxf(m, __shfl_xor(m, 32));
  float sum = 0.f;
  #pragma unroll
  for (int nf=0;nf<8;nf++)
    #pragma unroll
    for (int r=0;r<4;r++) sum += __expf(sv[nf][r] - m);
  sum += __shfl_xor(sum, 16);
  sum += __shfl_xor(sum, 32);
  float lv = m + logf(sum);
  if (l < 16)
    lgt_out[(((size_t)(bh*4 + rnd)) << 12) + pos_q16] = lv;

  i32x4 pa[4];
  #pragma unroll
  for (int ks=0;ks<4;ks++){
    uint wd[4];
    #pragma unroll
    for (int h2=0; h2<2; h2++){
      int nf = 2*ks + h2;
      float p0 = __expf(sv[nf][0]-lv), p1 = __expf(sv[nf][1]-lv);
      float p2 = __expf(sv[nf][2]-lv), p3 = __expf(sv[nf][3]-lv);
      wd[h2*2]   = (uint)f2bf(p0) | ((uint)f2bf(p1)<<16);
      wd[h2*2+1] = (uint)f2bf(p2) | ((uint)f2bf(p3)<<16);
    }
    i32x4 t = {(int)wd[0],(int)wd[1],(int)wd[2],(int)wd[3]};
    pa[ks] = t;
  }

  f32x4 o[4];
  #pragma unroll
  for (int i=0;i<4;i++) o[i] = zero;
  #pragma unroll
  for (int ks=0;ks<4;ks++){
    #pragma unroll
    for (int nf=0;nf<4;nf++){
      i32x4 vf = *(const i32x4*)((const char*)&Vt[nf*16 + lr][0] + ks*64 + lg*16);
      o[nf] = mfma16(pa[ks], vf, o[nf]);
    }
  }
  #pragma unroll
  for (int nf=0;nf<4;nf++){
    f32x4 ov = acc_fence(o[nf]);
    #pragma unroll
    for (int r=0;r<4;r++){
      int q = w*16 + lg*4 + r;
      bo[((((size_t)(bh*4 + rnd)) << 12) + posk[q])*64 + nf*16 + lr] = f2bf(ov[r]);
    }
  }
}

// ---------------- combine hash rounds ----------------
__global__ __launch_bounds__(256) void k_combine(const u16* __restrict__ bo, const float* __restrict__ lgt,
                                                 u16* __restrict__ attn){
  const int wid = blockIdx.x * 4 + (threadIdx.x >> 6);
  const int l = threadIdx.x & 63;
  const int bh = wid >> 12, t = wid & 4095;
  const size_t lbase = (((size_t)bh) << 14) + t;
  float l0 = lgt[lbase], l1 = lgt[lbase + 4096], l2 = lgt[lbase + 8192], l3 = lgt[lbase + 12288];
  float m = fmaxf(fmaxf(l0,l1), fmaxf(l2,l3));
  float w0 = __expf(l0-m), w1 = __expf(l1-m), w2 = __expf(l2-m), w3 = __expf(l3-m);
  float inv = 1.f / (w0+w1+w2+w3);
  const size_t bbase = ((((size_t)bh) << 14) + t) * 64 + l;
  float o = w0 * bf2f(bo[bbase])
          + w1 * bf2f(bo[bbase + (size_t)4096*64])
          + w2 * bf2f(bo[bbase + (size_t)8192*64])
          + w3 * bf2f(bo[bbase + (size_t)12288*64]);
  o *= inv;
  int b = bh >> 3, h = bh & 7;
  attn[((((size_t)b) << 12) + t) * 512 + h*64 + l] = f2bf(o);
}

// ---------------- residual + LayerNorm ----------------
template<int WB16>
__global__ __launch_bounds__(256) void k_ln(const float* __restrict__ a, const float* __restrict__ res,
                                            const float* __restrict__ g, const float* __restrict__ bb,
                                            float* __restrict__ of, u16* __restrict__ ob){
  const int row = blockIdx.x*4 + (threadIdx.x >> 6);
  const int l = threadIdx.x & 63;
  const size_t base = (size_t)row*512 + l*8;
  float4 a0 = *(const float4*)(a + base);
  float4 a1 = *(const float4*)(a + base + 4);
  float4 r0 = *(const float4*)(res + base);
  float4 r1 = *(const float4*)(res + base + 4);
  float v[8] = {a0.x+r0.x, a0.y+r0.y, a0.z+r0.z, a0.w+r0.w,
                a1.x+r1.x, a1.y+r1.y, a1.z+r1.z, a1.w+r1.w};
  float sum = 0.f;
  #pragma unroll
  for (int j=0;j<8;j++) sum += v[j];
  #pragma unroll
  for (int msk=1; msk<64; msk<<=1) sum += __shfl_xor(sum, msk);
  float mean = sum * (1.f/512.f);
  float ss = 0.f;
  #pragma unroll
  for (int j=0;j<8;j++){ float d = v[j]-mean; ss += d*d; }
  #pragma unroll
  for (int msk=1; msk<64; msk<<=1) ss += __shfl_xor(ss, msk);
  float rstd = rsqrtf(ss * (1.f/512.f) + 1e-6f);
  float4 g0 = *(const float4*)(g + l*8),  g1 = *(const float4*)(g + l*8 + 4);
  float4 b0 = *(const float4*)(bb + l*8), b1 = *(const float4*)(bb + l*8 + 4);
  float gv[8] = {g0.x,g0.y,g0.z,g0.w,g1.x,g1.y,g1.z,g1.w};
  float bv[8] = {b0.x,b0.y,b0.z,b0.w,b1.x,b1.y,b1.z,b1.w};
  float y[8];
  #pragma unroll
  for (int j=0;j<8;j++) y[j] = (v[j]-mean)*rstd*gv[j] + bv[j];
  #pragma unroll
  for (int j=0;j<8;j++) of[base+j] = y[j];
  if (WB16){
    #pragma unroll
    for (int j=0;j<8;j++) ob[base+j] = f2bf(y[j]);
  }
}

extern "C" void kernel_launch(void* const* d_in, const int* in_sizes, int n_in,
                              void* d_out, int out_size, void* d_ws, size_t ws_size,
                              hipStream_t stream) {
  const float* x     = (const float*)d_in[0];
  const float* rot   = (const float*)d_in[1];
  const float* w_qk  = (const float*)d_in[2];
  const float* w_v   = (const float*)d_in[3];
  const float* w_out = (const float*)d_in[4];
  const float* b_out = (const float*)d_in[5];
  const float* ln1_g = (const float*)d_in[6];
  const float* ln1_b = (const float*)d_in[7];
  const float* w1    = (const float*)d_in[8];
  const float* b1    = (const float*)d_in[9];
  const float* w2    = (const float*)d_in[10];
  const float* b2    = (const float*)d_in[11];
  const float* ln2_g = (const float*)d_in[12];
  const float* ln2_b = (const float*)d_in[13];
  float* out = (float*)d_out;

  char* p = (char*)d_ws;
  u16*   xh   = (u16*)(p);                    // x-hi   | later: qb, then hb
  u16*   xl   = (u16*)(p + 16777216);         // x-lo   | later: kn, then attnc
  u16*   wqkh = (u16*)(p + 33554432);         //        | later: rotT hi
  u16*   wqkl = (u16*)(p + 34078720);         //        | later: rotT lo
  u16*   wvb  = (u16*)(p + 34603008);
  u16*   wob  = (u16*)(p + 35127296);
  u16*   w1b  = (u16*)(p + 35651584);
  u16*   w2b  = (u16*)(p + 37748736);
  float* qkf  = (float*)(p + 39845888);       // fp32 qk | later: hf
  u16*   vb   = (u16*)(p + 73400320);
  int*   bkt  = (int*)(p + 90177536);
  int*   stb  = (int*)(p + 92274688);
  float* lgt  = (float*)(p + 94371840);
  u16*   bo   = (u16*)(p + 96468992);         // 67 MB  | early: qlo, later: ffn hidden
  // aliases (non-overlapping lifetimes)
  u16*   qbuf  = xh;
  u16*   knb   = xl;
  u16*   qlo   = bo;     // dead before k_attn writes bo
  u16*   rothi = wqkh;   // dead after qk-gemm
  u16*   rotlo = wqkl;
  u16*   attnc = xl;
  float* hf    = qkf;
  u16*   hb    = xh;
  u16*   hid   = bo;

  // 1) dtype converts / splits
  k_split<<<8192, 256, 0, stream>>>(x, xh, xl, 16384*512/4);
  k_split<<<256,  256, 0, stream>>>(w_qk, wqkh, wqkl, 512*512/4);
  k_cvt  <<<256,  256, 0, stream>>>(w_v,   wvb, 512*512/4);
  k_cvt  <<<256,  256, 0, stream>>>(w_out, wob, 512*512/4);
  k_cvt  <<<1024, 256, 0, stream>>>(w1, w1b, 2048*512/4);
  k_cvt  <<<1024, 256, 0, stream>>>(w2, w2b, 2048*512/4);

  // 2) qk = x @ w_qk^T at ~fp32 (3-term split bf16), head layout fp32
  k_gemm<2><<<dim3(4,128), 256, 0, stream>>>(xh, xl, wqkh, wqkl, nullptr, qkf, nullptr, nullptr, 16384, 512, 512, 3);
  // 3) v = x @ w_v^T, head layout bf16
  k_gemm<3><<<dim3(4,128), 256, 0, stream>>>(xh, nullptr, wvb, nullptr, nullptr, nullptr, vb, nullptr, 16384, 512, 512, 1);
  // 4) rot transpose+split (wqkh/wqkl now dead)
  k_rotT<<<32, 256, 0, stream>>>(rot, rothi, rotlo);
  // 5) prep: qb/qlo (bf16 hi/lo) + kn (bf16 normalized) — xh/xl now free
  k_prep<<<8192, 256, 0, stream>>>(qkf, qbuf, qlo, knb);
  // 6) LSH hash: S = qk @ rotT^T (3-term split) with fused argmax -> buckets
  k_gemm<4><<<dim3(1,1024), 256, 0, stream>>>(qbuf, qlo, rothi, rotlo, nullptr, nullptr, nullptr, bkt, 131072, 128, 64, 3);
  // 7) stable counting sort per (bh, round)
  k_sort<<<128, 64, 0, stream>>>(bkt, stb);
  // 8) chunked attention
  k_attn<<<dim3(256,32), 256, 0, stream>>>(qbuf, knb, vb, stb, lgt, bo);
  // 9) combine rounds -> (b,t,512) bf16
  k_combine<<<32768, 256, 0, stream>>>(bo, lgt, attnc);
  // 10) out projection (+bias) -> d_out (scratch)
  k_gemm<0><<<dim3(4,128), 256, 0, stream>>>(attnc, nullptr, wob, nullptr, b_out, out, nullptr, nullptr, 16384, 512, 512, 1);
  // 11) h = LN(attn + x)
  k_ln<1><<<4096, 256, 0, stream>>>(out, x, ln1_g, ln1_b, hf, hb);
  // 12) hidden = relu(h @ w1^T + b1) bf16
  k_gemm<1><<<dim3(16,128), 256, 0, stream>>>(hb, nullptr, w1b, nullptr, b1, nullptr, hid, nullptr, 16384, 2048, 512, 1);
  // 13) f = hidden @ w2^T + b2 -> d_out
  k_gemm<0><<<dim3(4,128), 256, 0, stream>>>(hid, nullptr, w2b, nullptr, b2, out, nullptr, nullptr, 16384, 512, 2048, 1);
  // 14) out = LN(f + h)  (in place on d_out)
  k_ln<0><<<4096, 256, 0, stream>>>(out, hf, ln2_g, ln2_b, out, nullptr);
}

// Round 4
// 352.208 us; speedup vs baseline: 1.3538x; 1.0611x over previous
//
#include <hip/hip_runtime.h>
#include <stdint.h>

// Reformer layer: B=4 T=4096 D=512 H=8 DH=64 N_HASH=4 N_BUCKET=64 BUCKET=64 FFN=2048
typedef unsigned short u16;
typedef __attribute__((ext_vector_type(4))) int   i32x4;
typedef __attribute__((ext_vector_type(4))) float f32x4;

__device__ __forceinline__ u16 f2bf(float x){
  unsigned int u = __float_as_uint(x);
  u += 0x7FFFu + ((u >> 16) & 1u);
  return (u16)(u >> 16);
}
__device__ __forceinline__ float bf2f(u16 h){
  return __uint_as_float(((unsigned int)h) << 16);
}
__device__ __forceinline__ f32x4 mfma16(i32x4 a, i32x4 b, f32x4 c){
  asm("v_mfma_f32_16x16x32_bf16 %0, %1, %2, %0" : "+v"(c) : "v"(a), "v"(b));
  return c;
}
__device__ __forceinline__ f32x4 acc_fence(f32x4 c){
  asm volatile("s_nop 7\ns_nop 7" : "+v"(c));
  return c;
}
__device__ __forceinline__ void gl_lds16(const void* g, void* l){
  unsigned long long ga = (unsigned long long)g;
  unsigned int la = (unsigned int)(unsigned long long)l;
  __builtin_amdgcn_global_load_lds((const __attribute__((address_space(1))) void*)ga,
                                   (__attribute__((address_space(3))) void*)la, 16, 0, 0);
}
// monotonic-uint transform: order-preserving for fp32 compares
__device__ __forceinline__ unsigned int f2mono(float v){
  unsigned int u = __float_as_uint(v);
  return u ^ ((unsigned int)((int)u >> 31) | 0x80000000u);
}
__device__ __forceinline__ float mono2f(unsigned int mu){
  unsigned int u = (mu & 0x80000000u) ? (mu ^ 0x80000000u) : ~mu;
  return __uint_as_float(u);
}
__device__ __forceinline__ unsigned long long shfl_xor_u64(unsigned long long x, int m){
  int lo = __shfl_xor((int)(unsigned int)(x & 0xFFFFFFFFull), m);
  int hi = __shfl_xor((int)(unsigned int)(x >> 32), m);
  return ((unsigned long long)(unsigned int)hi << 32) | (unsigned int)lo;
}

// ---------------- converts ----------------
__global__ __launch_bounds__(256) void k_cvt(const float* __restrict__ in, u16* __restrict__ out, int n4){
  int i = blockIdx.x*256 + threadIdx.x;
  if (i >= n4) return;
  float4 v = ((const float4*)in)[i];
  ushort4 o; o.x=f2bf(v.x); o.y=f2bf(v.y); o.z=f2bf(v.z); o.w=f2bf(v.w);
  ((ushort4*)out)[i] = o;
}
__global__ __launch_bounds__(256) void k_split(const float* __restrict__ in, u16* __restrict__ hi, u16* __restrict__ lo, int n4){
  int i = blockIdx.x*256 + threadIdx.x;
  if (i >= n4) return;
  float4 v = ((const float4*)in)[i];
  ushort4 h, l;
  h.x=f2bf(v.x); l.x=f2bf(v.x - bf2f(h.x));
  h.y=f2bf(v.y); l.y=f2bf(v.y - bf2f(h.y));
  h.z=f2bf(v.z); l.z=f2bf(v.z - bf2f(h.z));
  h.w=f2bf(v.w); l.w=f2bf(v.w - bf2f(h.w));
  ((ushort4*)hi)[i]=h; ((ushort4*)lo)[i]=l;
}
// rot (64 x 4 x 32) -> rotT[n=h*32+i][d] bf16 hi/lo
__global__ __launch_bounds__(256) void k_rotT(const float* __restrict__ rot, u16* __restrict__ hi, u16* __restrict__ lo){
  int i = blockIdx.x*256 + threadIdx.x;
  if (i >= 8192) return;
  int d = i & 63, n = i >> 6;
  float v = rot[d*128 + n];
  u16 h = f2bf(v);
  hi[i] = h; lo[i] = f2bf(v - bf2f(h));
}

// ---------------- generic bf16 MFMA GEMM: C = sum_t A_t * B_t^T ----------------
// MODE 0: fp32 rowmajor (+bias)   MODE 1: bf16 rowmajor, bias+relu
// MODE 2: fp32 head-layout (qk)   MODE 3: bf16 head-layout (v)
template<int MODE>
__global__ __launch_bounds__(256) void k_gemm(
    const u16* __restrict__ A0, const u16* __restrict__ A1,
    const u16* __restrict__ B0, const u16* __restrict__ B1,
    const float* __restrict__ bias,
    float* __restrict__ Cf, u16* __restrict__ Cb,
    int M, int N, int K, int nterms)
{
  const int tid = threadIdx.x;
  const int l = tid & 63, w = tid >> 6;
  const int lr = l & 15, lg = l >> 4;
  const int m0 = blockIdx.y * 128, n0 = blockIdx.x * 128;
  const int mbase = (w >> 1) * 64, nbase = (w & 1) * 64;

  __shared__ __align__(16) u16 As[128*64];
  __shared__ __align__(16) u16 Bs[128*64];

  f32x4 zero = {0.f,0.f,0.f,0.f};
  f32x4 acc[4][4];
  #pragma unroll
  for (int i=0;i<4;i++)
    #pragma unroll
    for (int j=0;j<4;j++) acc[i][j] = zero;

  const int row_s = tid >> 3;
  const int c16   = tid & 7;

  for (int term = 0; term < nterms; ++term){
    const u16* Ap = (term==2) ? A1 : A0;
    const u16* Bp = (term==1) ? B1 : B0;
    for (int k0 = 0; k0 < K; k0 += 64){
      #pragma unroll
      for (int q=0;q<4;q++){
        int ra = q*32 + row_s;
        int cs = c16 ^ (ra & 7);
        gl_lds16(Ap + (size_t)(m0 + ra)*K + k0 + cs*8, (char*)As + q*4096 + tid*16);
        gl_lds16(Bp + (size_t)(n0 + ra)*K + k0 + cs*8, (char*)Bs + q*4096 + tid*16);
      }
      __syncthreads();
      #pragma unroll
      for (int kk=0; kk<64; kk+=32){
        i32x4 af[4], bfr[4];
        #pragma unroll
        for (int mf=0;mf<4;mf++){
          int row = mbase + mf*16 + lr;
          af[mf] = *(const i32x4*)((const char*)As + row*128 + (((kk*2) + (lg*16)) ^ ((row&7)<<4)));
        }
        #pragma unroll
        for (int nf=0;nf<4;nf++){
          int row = nbase + nf*16 + lr;
          bfr[nf] = *(const i32x4*)((const char*)Bs + row*128 + (((kk*2) + (lg*16)) ^ ((row&7)<<4)));
        }
        #pragma unroll
        for (int mf=0;mf<4;mf++)
          #pragma unroll
          for (int nf=0;nf<4;nf++)
            acc[mf][nf] = mfma16(af[mf], bfr[nf], acc[mf][nf]);
      }
      __syncthreads();
    }
  }

  #pragma unroll
  for (int mf=0;mf<4;mf++){
    #pragma unroll
    for (int nf=0;nf<4;nf++){
      f32x4 v = acc_fence(acc[mf][nf]);
      #pragma unroll
      for (int r=0;r<4;r++){
        int m = m0 + mbase + mf*16 + lg*4 + r;
        int n = n0 + nbase + nf*16 + lr;
        float val = v[r];
        if (MODE == 0){
          if (bias) val += bias[n];
          Cf[(size_t)m*N + n] = val;
        } else if (MODE == 1){
          val += bias[n];
          val = fmaxf(val, 0.f);
          Cb[(size_t)m*N + n] = f2bf(val);
        } else {
          int b = m >> 12, t = m & 4095, h = n >> 6, d = n & 63;
          size_t idx = ((((size_t)(b*8 + h)) << 12) + t)*64 + d;
          if (MODE == 2) Cf[idx] = val;
          else           Cb[idx] = f2bf(val);
        }
      }
    }
  }
}

// ---------------- LSH hash v2: swapped-operand MFMA, lane-local argmax ----------------
// S^T = rot(128 n-rows) x q(16 q-rows): acc[nf] holds n = nf*16+lg*4+r, q-row = lr.
__global__ __launch_bounds__(256) void k_hash2(
    const u16* __restrict__ qh, const u16* __restrict__ ql,
    const u16* __restrict__ rh, const u16* __restrict__ rl,
    int* __restrict__ bkt)
{
  const int tid = threadIdx.x;
  const int l = tid & 63, w = tid >> 6, lr = l & 15, lg = l >> 4;
  __shared__ __align__(16) u16 Rh[128*64];
  __shared__ __align__(16) u16 Rl[128*64];
  {
    const int row_s = tid >> 3, c8 = tid & 7;
    #pragma unroll
    for (int q = 0; q < 4; q++){
      int ra = q*32 + row_s;
      int cs = c8 ^ (ra & 7);
      gl_lds16(rh + ra*64 + cs*8, (char*)Rh + q*4096 + tid*16);
      gl_lds16(rl + ra*64 + cs*8, (char*)Rl + q*4096 + tid*16);
    }
  }
  const int qrow = blockIdx.x*64 + w*16 + lr;
  const size_t qoff = (size_t)qrow*64;
  i32x4 qhf[2], qlf[2];
  qhf[0] = *(const i32x4*)(qh + qoff + lg*8);
  qhf[1] = *(const i32x4*)(qh + qoff + 32 + lg*8);
  qlf[0] = *(const i32x4*)(ql + qoff + lg*8);
  qlf[1] = *(const i32x4*)(ql + qoff + 32 + lg*8);
  __syncthreads();

  f32x4 zero = {0.f,0.f,0.f,0.f};
  f32x4 acc[8];
  #pragma unroll
  for (int i=0;i<8;i++) acc[i] = zero;
  #pragma unroll
  for (int ks = 0; ks < 2; ks++){
    #pragma unroll
    for (int nf = 0; nf < 8; nf++){
      int row = nf*16 + lr;
      int off = (ks*64 + lg*16) ^ ((row & 7) << 4);
      i32x4 rhf = *(const i32x4*)((const char*)Rh + row*128 + off);
      i32x4 rlf = *(const i32x4*)((const char*)Rl + row*128 + off);
      acc[nf] = mfma16(rhf, qhf[ks], acc[nf]);
      acc[nf] = mfma16(rlf, qhf[ks], acc[nf]);
      acc[nf] = mfma16(rhf, qlf[ks], acc[nf]);
    }
  }

  const int bh = qrow >> 12, t = qrow & 4095;
  #pragma unroll
  for (int hh = 0; hh < 4; hh++){
    f32x4 v0 = acc_fence(acc[2*hh]);
    f32x4 v1 = acc_fence(acc[2*hh+1]);
    unsigned long long kmax = 0, kmin = 0;
    #pragma unroll
    for (int r = 0; r < 4; r++){
      int j0 = lg*4 + r, j1 = 16 + lg*4 + r;
      unsigned int mu0 = f2mono(v0[r]), mu1 = f2mono(v1[r]);
      unsigned long long a = ((unsigned long long)mu0 << 32) | (unsigned int)(31 - j0);
      unsigned long long b = ((unsigned long long)mu1 << 32) | (unsigned int)(31 - j1);
      if (a > kmax) kmax = a;
      if (b > kmax) kmax = b;
      unsigned long long c = ((unsigned long long)(~mu0) << 32) | (unsigned int)(31 - j0);
      unsigned long long d = ((unsigned long long)(~mu1) << 32) | (unsigned int)(31 - j1);
      if (c > kmin) kmin = c;
      if (d > kmin) kmin = d;
    }
    #pragma unroll
    for (int msk = 16; msk < 64; msk <<= 1){
      unsigned long long o1 = shfl_xor_u64(kmax, msk); if (o1 > kmax) kmax = o1;
      unsigned long long o2 = shfl_xor_u64(kmin, msk); if (o2 > kmin) kmin = o2;
    }
    if (lg == 0){
      float vmax = mono2f((unsigned int)(kmax >> 32));
      int jmax = 31 - (int)(kmax & 0xFFFFFFFFull);
      float vmin = mono2f(~(unsigned int)(kmin >> 32));
      int jmin = 31 - (int)(kmin & 0xFFFFFFFFull);
      int bucket = (vmax >= -vmin) ? jmax : 32 + jmin;
      bkt[((size_t)(bh*4 + hh) << 12) + t] = bucket;
    }
  }
}

// ---------------- prep: qb/qlo = bf16 hi/lo of qk, kn = bf16(normalize(qk)) ----------------
__global__ __launch_bounds__(256) void k_prep(const float* __restrict__ qkf,
                                              u16* __restrict__ qb, u16* __restrict__ qlo,
                                              u16* __restrict__ kn){
  const int row = blockIdx.x*16 + (threadIdx.x >> 4);
  const int l16 = threadIdx.x & 15;
  float4 v = *(const float4*)(qkf + (size_t)row*64 + l16*4);
  float ss = v.x*v.x + v.y*v.y + v.z*v.z + v.w*v.w;
  ss += __shfl_xor(ss, 1); ss += __shfl_xor(ss, 2);
  ss += __shfl_xor(ss, 4); ss += __shfl_xor(ss, 8);
  float scale = 1.f / fmaxf(sqrtf(ss), 1e-6f);
  u16 h0=f2bf(v.x), h1=f2bf(v.y), h2=f2bf(v.z), h3=f2bf(v.w);
  uint q0 = (uint)h0 | ((uint)h1<<16);
  uint q1 = (uint)h2 | ((uint)h3<<16);
  uint e0 = (uint)f2bf(v.x-bf2f(h0)) | ((uint)f2bf(v.y-bf2f(h1))<<16);
  uint e1 = (uint)f2bf(v.z-bf2f(h2)) | ((uint)f2bf(v.w-bf2f(h3))<<16);
  uint k0 = (uint)f2bf(v.x*scale) | ((uint)f2bf(v.y*scale)<<16);
  uint k1 = (uint)f2bf(v.z*scale) | ((uint)f2bf(v.w*scale)<<16);
  uint2 qo = {q0,q1}, eo = {e0,e1}, ko = {k0,k1};
  ((uint2*)(qb  + (size_t)row*64))[l16] = qo;
  ((uint2*)(qlo + (size_t)row*64))[l16] = eo;
  ((uint2*)(kn  + (size_t)row*64))[l16] = ko;
}

// ---------------- stable counting sort per (bh, round) ----------------
__global__ __launch_bounds__(64) void k_sort(const int* __restrict__ buckets, int* __restrict__ st){
  const int grp = blockIdx.x;
  const int t = threadIdx.x;
  __shared__ int hist[64][65];
  __shared__ int tot[64];
  const size_t gbase = ((size_t)grp) << 12;
  #pragma unroll
  for (int b=0;b<64;b++) hist[t][b] = 0;
  __syncthreads();
  for (int i=0;i<64;i++){
    int b = buckets[gbase + t*64 + i];
    hist[t][b]++;
  }
  __syncthreads();
  { int run = 0;
    for (int tt=0; tt<64; tt++){ int v = hist[tt][t]; hist[tt][t] = run; run += v; }
    tot[t] = run; }
  __syncthreads();
  { int v = tot[t]; int incl = v;
    #pragma unroll
    for (int d=1; d<64; d<<=1){ int n = __shfl_up(incl, d, 64); if (t >= d) incl += n; }
    tot[t] = incl - v; }
  __syncthreads();
  const size_t obase = (((size_t)(grp>>2)) << 14) + ((size_t)(grp&3) << 12);
  for (int i=0;i<64;i++){
    int e = t*64 + i;
    int b = buckets[gbase + e];
    int dest = tot[b] + hist[t][b];
    hist[t][b]++;
    st[obase + dest] = e;
  }
}

// ---------------- chunked LSH attention: swapped QK^T, in-reg softmax ----------------
__global__ __launch_bounds__(256, 4) void k_attn(
    const u16* __restrict__ qb, const u16* __restrict__ kn, const u16* __restrict__ vB,
    const int* __restrict__ st, float* __restrict__ lgt_out, u16* __restrict__ bo)
{
  const int c = blockIdx.x, bh = blockIdx.y;
  const int rnd = c >> 6;
  const int tid = threadIdx.x;
  const int l = tid & 63, w = tid >> 6, lr = l & 15, lg = l >> 4;

  __shared__ __align__(16) u16 Ks[128*64];
  __shared__ __align__(16) u16 Vt[64][136];
  __shared__ int posk[128];

  if (tid < 128){
    int cc = (tid < 64) ? c : ((c + 255) & 255);
    posk[tid] = st[(((size_t)bh) << 14) + (cc << 6) + (tid & 63)];
  }
  __syncthreads();

  const size_t kvbase = ((size_t)bh) << 12;

  {
    const int rsub = l >> 3, c8 = l & 7;
    #pragma unroll
    for (int q2 = 0; q2 < 4; q2++){
      int row = w*32 + q2*8 + rsub;
      int cs = c8 ^ (row & 7);
      gl_lds16(kn + (kvbase + posk[row])*64 + cs*8,
               (char*)Ks + (w*4 + q2)*1024 + l*16);
    }
  }

  const int pos_q16 = posk[w*16 + lr];
  i32x4 qf[2];
  #pragma unroll
  for (int ks = 0; ks < 2; ks++)
    qf[ks] = *(const i32x4*)(qb + (kvbase + pos_q16)*64 + ks*32 + lg*8);

  {
    const int pp = tid & 63, db = tid >> 6;
    const int q5 = pp & 15;
    const int K0 = (pp >> 4)*32 + 16*((q5 >> 1) & 1) + 4*(q5 >> 2) + 2*(q5 & 1);
    const u16* r0 = vB + (kvbase + posk[K0])*64 + db*16;
    const u16* r1 = vB + (kvbase + posk[K0+1])*64 + db*16;
    uint4 a0 = *(const uint4*)r0, a1 = *(const uint4*)(r0 + 8);
    uint4 b0 = *(const uint4*)r1, b1 = *(const uint4*)(r1 + 8);
    uint av[8] = {a0.x,a0.y,a0.z,a0.w,a1.x,a1.y,a1.z,a1.w};
    uint bv[8] = {b0.x,b0.y,b0.z,b0.w,b1.x,b1.y,b1.z,b1.w};
    #pragma unroll
    for (int dd = 0; dd < 16; dd++){
      uint lo = (av[dd>>1] >> ((dd&1)*16)) & 0xFFFFu;
      uint hi = (bv[dd>>1] >> ((dd&1)*16)) & 0xFFFFu;
      *(uint*)((char*)&Vt[db*16 + dd][0] + pp*4) = lo | (hi << 16);
    }
  }
  __syncthreads();

  f32x4 zero = {0.f,0.f,0.f,0.f};
  f32x4 s[8];
  #pragma unroll
  for (int i=0;i<8;i++) s[i] = zero;
  #pragma unroll
  for (int ks = 0; ks < 2; ks++){
    #pragma unroll
    for (int nf = 0; nf < 8; nf++){
      int row = nf*16 + lr;
      i32x4 kf = *(const i32x4*)((const char*)Ks + row*128 + ((ks*64 + lg*16) ^ ((row&7)<<4)));
      s[nf] = mfma16(kf, qf[ks], s[nf]);
    }
  }

  float sv[8][4];
  const int q_loc = w*16 + lr;
  #pragma unroll
  for (int nf=0;nf<8;nf++){
    f32x4 t = acc_fence(s[nf]);
    #pragma unroll
    for (int r=0;r<4;r++){
      int k = nf*16 + lg*4 + r;
      sv[nf][r] = (k == q_loc) ? -5e4f : t[r]*0.125f;
    }
  }
  float m = -1e30f;
  #pragma unroll
  for (int nf=0;nf<8;nf++)
    #pragma unroll
    for (int r=0;r<4;r++) m = fmaxf(m, sv[nf][r]);
  m = fmaxf(m, __shfl_xor(m, 16));
  m = fmaxf(m, __shfl_xor(m, 32));
  float sum = 0.f;
  #pragma unroll
  for (int nf=0;nf<8;nf++)
    #pragma unroll
    for (int r=0;r<4;r++) sum += __expf(sv[nf][r] - m);
  sum += __shfl_xor(sum, 16);
  sum += __shfl_xor(sum, 32);
  float lv = m + logf(sum);
  if (l < 16)
    lgt_out[(((size_t)(bh*4 + rnd)) << 12) + pos_q16] = lv;

  i32x4 pa[4];
  #pragma unroll
  for (int ks=0;ks<4;ks++){
    uint wd[4];
    #pragma unroll
    for (int h2=0; h2<2; h2++){
      int nf = 2*ks + h2;
      float p0 = __expf(sv[nf][0]-lv), p1 = __expf(sv[nf][1]-lv);
      float p2 = __expf(sv[nf][2]-lv), p3 = __expf(sv[nf][3]-lv);
      wd[h2*2]   = (uint)f2bf(p0) | ((uint)f2bf(p1)<<16);
      wd[h2*2+1] = (uint)f2bf(p2) | ((uint)f2bf(p3)<<16);
    }
    i32x4 t = {(int)wd[0],(int)wd[1],(int)wd[2],(int)wd[3]};
    pa[ks] = t;
  }

  f32x4 o[4];
  #pragma unroll
  for (int i=0;i<4;i++) o[i] = zero;
  #pragma unroll
  for (int ks=0;ks<4;ks++){
    #pragma unroll
    for (int nf=0;nf<4;nf++){
      i32x4 vf = *(const i32x4*)((const char*)&Vt[nf*16 + lr][0] + ks*64 + lg*16);
      o[nf] = mfma16(pa[ks], vf, o[nf]);
    }
  }
  #pragma unroll
  for (int nf=0;nf<4;nf++){
    f32x4 ov = acc_fence(o[nf]);
    #pragma unroll
    for (int r=0;r<4;r++){
      int q = w*16 + lg*4 + r;
      bo[((((size_t)(bh*4 + rnd)) << 12) + posk[q])*64 + nf*16 + lr] = f2bf(ov[r]);
    }
  }
}

// ---------------- combine hash rounds ----------------
__global__ __launch_bounds__(256) void k_combine(const u16* __restrict__ bo, const float* __restrict__ lgt,
                                                 u16* __restrict__ attn){
  const int wid = blockIdx.x * 4 + (threadIdx.x >> 6);
  const int l = threadIdx.x & 63;
  const int bh = wid >> 12, t = wid & 4095;
  const size_t lbase = (((size_t)bh) << 14) + t;
  float l0 = lgt[lbase], l1 = lgt[lbase + 4096], l2 = lgt[lbase + 8192], l3 = lgt[lbase + 12288];
  float m = fmaxf(fmaxf(l0,l1), fmaxf(l2,l3));
  float w0 = __expf(l0-m), w1 = __expf(l1-m), w2 = __expf(l2-m), w3 = __expf(l3-m);
  float inv = 1.f / (w0+w1+w2+w3);
  const size_t bbase = ((((size_t)bh) << 14) + t) * 64 + l;
  float o = w0 * bf2f(bo[bbase])
          + w1 * bf2f(bo[bbase + (size_t)4096*64])
          + w2 * bf2f(bo[bbase + (size_t)8192*64])
          + w3 * bf2f(bo[bbase + (size_t)12288*64]);
  o *= inv;
  int b = bh >> 3, h = bh & 7;
  attn[((((size_t)b) << 12) + t) * 512 + h*64 + l] = f2bf(o);
}

// ---------------- residual + LayerNorm ----------------
template<int WB16>
__global__ __launch_bounds__(256) void k_ln(const float* __restrict__ a, const float* __restrict__ res,
                                            const float* __restrict__ g, const float* __restrict__ bb,
                                            float* __restrict__ of, u16* __restrict__ ob){
  const int row = blockIdx.x*4 + (threadIdx.x >> 6);
  const int l = threadIdx.x & 63;
  const size_t base = (size_t)row*512 + l*8;
  float4 a0 = *(const float4*)(a + base);
  float4 a1 = *(const float4*)(a + base + 4);
  float4 r0 = *(const float4*)(res + base);
  float4 r1 = *(const float4*)(res + base + 4);
  float v[8] = {a0.x+r0.x, a0.y+r0.y, a0.z+r0.z, a0.w+r0.w,
                a1.x+r1.x, a1.y+r1.y, a1.z+r1.z, a1.w+r1.w};
  float sum = 0.f;
  #pragma unroll
  for (int j=0;j<8;j++) sum += v[j];
  #pragma unroll
  for (int msk=1; msk<64; msk<<=1) sum += __shfl_xor(sum, msk);
  float mean = sum * (1.f/512.f);
  float ss = 0.f;
  #pragma unroll
  for (int j=0;j<8;j++){ float d = v[j]-mean; ss += d*d; }
  #pragma unroll
  for (int msk=1; msk<64; msk<<=1) ss += __shfl_xor(ss, msk);
  float rstd = rsqrtf(ss * (1.f/512.f) + 1e-6f);
  float4 g0 = *(const float4*)(g + l*8),  g1 = *(const float4*)(g + l*8 + 4);
  float4 b0 = *(const float4*)(bb + l*8), b1 = *(const float4*)(bb + l*8 + 4);
  float gv[8] = {g0.x,g0.y,g0.z,g0.w,g1.x,g1.y,g1.z,g1.w};
  float bv[8] = {b0.x,b0.y,b0.z,b0.w,b1.x,b1.y,b1.z,b1.w};
  float y[8];
  #pragma unroll
  for (int j=0;j<8;j++) y[j] = (v[j]-mean)*rstd*gv[j] + bv[j];
  #pragma unroll
  for (int j=0;j<8;j++) of[base+j] = y[j];
  if (WB16){
    #pragma unroll
    for (int j=0;j<8;j++) ob[base+j] = f2bf(y[j]);
  }
}

extern "C" void kernel_launch(void* const* d_in, const int* in_sizes, int n_in,
                              void* d_out, int out_size, void* d_ws, size_t ws_size,
                              hipStream_t stream) {
  const float* x     = (const float*)d_in[0];
  const float* rot   = (const float*)d_in[1];
  const float* w_qk  = (const float*)d_in[2];
  const float* w_v   = (const float*)d_in[3];
  const float* w_out = (const float*)d_in[4];
  const float* b_out = (const float*)d_in[5];
  const float* ln1_g = (const float*)d_in[6];
  const float* ln1_b = (const float*)d_in[7];
  const float* w1    = (const float*)d_in[8];
  const float* b1    = (const float*)d_in[9];
  const float* w2    = (const float*)d_in[10];
  const float* b2    = (const float*)d_in[11];
  const float* ln2_g = (const float*)d_in[12];
  const float* ln2_b = (const float*)d_in[13];
  float* out = (float*)d_out;

  char* p = (char*)d_ws;
  u16*   xh   = (u16*)(p);                    // x-hi   | later: qb, then hb
  u16*   xl   = (u16*)(p + 16777216);         // x-lo   | later: kn, then attnc
  u16*   wqkh = (u16*)(p + 33554432);         //        | later: rotT hi
  u16*   wqkl = (u16*)(p + 34078720);         //        | later: rotT lo
  u16*   wvb  = (u16*)(p + 34603008);
  u16*   wob  = (u16*)(p + 35127296);
  u16*   w1b  = (u16*)(p + 35651584);
  u16*   w2b  = (u16*)(p + 37748736);
  float* qkf  = (float*)(p + 39845888);       // fp32 qk | later: hf
  u16*   vb   = (u16*)(p + 73400320);
  int*   bkt  = (int*)(p + 90177536);
  int*   stb  = (int*)(p + 92274688);
  float* lgt  = (float*)(p + 94371840);
  u16*   bo   = (u16*)(p + 96468992);         // 67 MB  | early: qlo, later: ffn hidden
  // aliases (non-overlapping lifetimes)
  u16*   qbuf  = xh;
  u16*   knb   = xl;
  u16*   qlo   = bo;     // dead before k_attn writes bo
  u16*   rothi = wqkh;   // dead after qk-gemm
  u16*   rotlo = wqkl;
  u16*   attnc = xl;
  float* hf    = qkf;
  u16*   hb    = xh;
  u16*   hid   = bo;

  // 1) dtype converts / splits
  k_split<<<8192, 256, 0, stream>>>(x, xh, xl, 16384*512/4);
  k_split<<<256,  256, 0, stream>>>(w_qk, wqkh, wqkl, 512*512/4);
  k_cvt  <<<256,  256, 0, stream>>>(w_v,   wvb, 512*512/4);
  k_cvt  <<<256,  256, 0, stream>>>(w_out, wob, 512*512/4);
  k_cvt  <<<1024, 256, 0, stream>>>(w1, w1b, 2048*512/4);
  k_cvt  <<<1024, 256, 0, stream>>>(w2, w2b, 2048*512/4);

  // 2) qk = x @ w_qk^T at ~fp32 (3-term split bf16), head layout fp32
  k_gemm<2><<<dim3(4,128), 256, 0, stream>>>(xh, xl, wqkh, wqkl, nullptr, qkf, nullptr, 16384, 512, 512, 3);
  // 3) v = x @ w_v^T, head layout bf16
  k_gemm<3><<<dim3(4,128), 256, 0, stream>>>(xh, nullptr, wvb, nullptr, nullptr, nullptr, vb, 16384, 512, 512, 1);
  // 4) rot transpose+split (wqkh/wqkl now dead)
  k_rotT<<<32, 256, 0, stream>>>(rot, rothi, rotlo);
  // 5) prep: qb/qlo (bf16 hi/lo) + kn (bf16 normalized) — xh/xl now free
  k_prep<<<8192, 256, 0, stream>>>(qkf, qbuf, qlo, knb);
  // 6) LSH hash: S^T = rot x qk (3-term split), lane-local argmax -> buckets
  k_hash2<<<2048, 256, 0, stream>>>(qbuf, qlo, rothi, rotlo, bkt);
  // 7) stable counting sort per (bh, round)
  k_sort<<<128, 64, 0, stream>>>(bkt, stb);
  // 8) chunked attention
  k_attn<<<dim3(256,32), 256, 0, stream>>>(qbuf, knb, vb, stb, lgt, bo);
  // 9) combine rounds -> (b,t,512) bf16
  k_combine<<<32768, 256, 0, stream>>>(bo, lgt, attnc);
  // 10) out projection (+bias) -> d_out (scratch)
  k_gemm<0><<<dim3(4,128), 256, 0, stream>>>(attnc, nullptr, wob, nullptr, b_out, out, nullptr, 16384, 512, 512, 1);
  // 11) h = LN(attn + x)
  k_ln<1><<<4096, 256, 0, stream>>>(out, x, ln1_g, ln1_b, hf, hb);
  // 12) hidden = relu(h @ w1^T + b1) bf16
  k_gemm<1><<<dim3(16,128), 256, 0, stream>>>(hb, nullptr, w1b, nullptr, b1, nullptr, hid, 16384, 2048, 512, 1);
  // 13) f = hidden @ w2^T + b2 -> d_out
  k_gemm<0><<<dim3(4,128), 256, 0, stream>>>(hid, nullptr, w2b, nullptr, b2, out, nullptr, 16384, 512, 2048, 1);
  // 14) out = LN(f + h)  (in place on d_out)
  k_ln<0><<<4096, 256, 0, stream>>>(out, hf, ln2_g, ln2_b, out, nullptr);
}

// Round 5
// 333.922 us; speedup vs baseline: 1.4279x; 1.0548x over previous
//
#include <hip/hip_runtime.h>
#include <stdint.h>

// Reformer layer: B=4 T=4096 D=512 H=8 DH=64 N_HASH=4 N_BUCKET=64 BUCKET=64 FFN=2048
typedef unsigned short u16;
typedef __attribute__((ext_vector_type(4))) int   i32x4;
typedef __attribute__((ext_vector_type(4))) float f32x4;

__device__ __forceinline__ u16 f2bf(float x){
  unsigned int u = __float_as_uint(x);
  u += 0x7FFFu + ((u >> 16) & 1u);
  return (u16)(u >> 16);
}
__device__ __forceinline__ float bf2f(u16 h){
  return __uint_as_float(((unsigned int)h) << 16);
}
__device__ __forceinline__ f32x4 mfma16(i32x4 a, i32x4 b, f32x4 c){
  asm("v_mfma_f32_16x16x32_bf16 %0, %1, %2, %0" : "+v"(c) : "v"(a), "v"(b));
  return c;
}
__device__ __forceinline__ f32x4 acc_fence(f32x4 c){
  asm volatile("s_nop 7\ns_nop 7" : "+v"(c));
  return c;
}
__device__ __forceinline__ void gl_lds16(const void* g, void* l){
  unsigned long long ga = (unsigned long long)g;
  unsigned int la = (unsigned int)(unsigned long long)l;
  __builtin_amdgcn_global_load_lds((const __attribute__((address_space(1))) void*)ga,
                                   (__attribute__((address_space(3))) void*)la, 16, 0, 0);
}
// XCD-chunked bijective swizzle (requires n % 8 == 0)
__device__ __forceinline__ int xcd_swz(int f, int n){
  int chunk = n >> 3;
  return (f & 7) * chunk + (f >> 3);
}
// monotonic-uint transform: order-preserving for fp32 compares
__device__ __forceinline__ unsigned int f2mono(float v){
  unsigned int u = __float_as_uint(v);
  return u ^ ((unsigned int)((int)u >> 31) | 0x80000000u);
}
__device__ __forceinline__ float mono2f(unsigned int mu){
  unsigned int u = (mu & 0x80000000u) ? (mu ^ 0x80000000u) : ~mu;
  return __uint_as_float(u);
}
__device__ __forceinline__ unsigned long long shfl_xor_u64(unsigned long long x, int m){
  int lo = __shfl_xor((int)(unsigned int)(x & 0xFFFFFFFFull), m);
  int hi = __shfl_xor((int)(unsigned int)(x >> 32), m);
  return ((unsigned long long)(unsigned int)hi << 32) | (unsigned int)lo;
}

// ---------------- converts ----------------
__global__ __launch_bounds__(256) void k_cvt(const float* __restrict__ in, u16* __restrict__ out, int n4){
  int i = blockIdx.x*256 + threadIdx.x;
  if (i >= n4) return;
  float4 v = ((const float4*)in)[i];
  ushort4 o; o.x=f2bf(v.x); o.y=f2bf(v.y); o.z=f2bf(v.z); o.w=f2bf(v.w);
  ((ushort4*)out)[i] = o;
}
__global__ __launch_bounds__(256) void k_split(const float* __restrict__ in, u16* __restrict__ hi, u16* __restrict__ lo, int n4){
  int i = blockIdx.x*256 + threadIdx.x;
  if (i >= n4) return;
  float4 v = ((const float4*)in)[i];
  ushort4 h, l;
  h.x=f2bf(v.x); l.x=f2bf(v.x - bf2f(h.x));
  h.y=f2bf(v.y); l.y=f2bf(v.y - bf2f(h.y));
  h.z=f2bf(v.z); l.z=f2bf(v.z - bf2f(h.z));
  h.w=f2bf(v.w); l.w=f2bf(v.w - bf2f(h.w));
  ((ushort4*)hi)[i]=h; ((ushort4*)lo)[i]=l;
}
// rot (64 x 4 x 32) -> rotT[n=h*32+i][d] bf16 hi/lo
__global__ __launch_bounds__(256) void k_rotT(const float* __restrict__ rot, u16* __restrict__ hi, u16* __restrict__ lo){
  int i = blockIdx.x*256 + threadIdx.x;
  if (i >= 8192) return;
  int d = i & 63, n = i >> 6;
  float v = rot[d*128 + n];
  u16 h = f2bf(v);
  hi[i] = h; lo[i] = f2bf(v - bf2f(h));
}

// ---------------- generic bf16 MFMA GEMM: C = sum_t A_t * B_t^T ----------------
// MODE 0: fp32 rowmajor (+bias)   MODE 1: bf16 rowmajor, bias+relu
// MODE 2: fused qk epilogue -> qb/qlo/kn head-layout bf16
// MODE 3: bf16 head-layout (v)
template<int MODE>
__global__ __launch_bounds__(256) void k_gemm(
    const u16* __restrict__ A0, const u16* __restrict__ A1,
    const u16* __restrict__ B0, const u16* __restrict__ B1,
    const float* __restrict__ bias,
    float* __restrict__ Cf, u16* __restrict__ Cb,
    u16* __restrict__ Cb2, u16* __restrict__ Cb3,
    int M, int N, int K, int nterms)
{
  const int tid = threadIdx.x;
  const int l = tid & 63, w = tid >> 6;
  const int lr = l & 15, lg = l >> 4;
  int flat = blockIdx.y * gridDim.x + blockIdx.x;
  flat = xcd_swz(flat, gridDim.x * gridDim.y);
  const int m0 = (flat / gridDim.x) * 128, n0 = (flat % gridDim.x) * 128;
  const int mbase = (w >> 1) * 64, nbase = (w & 1) * 64;

  __shared__ __align__(16) u16 As[128*64];
  __shared__ __align__(16) u16 Bs[128*64];

  f32x4 zero = {0.f,0.f,0.f,0.f};
  f32x4 acc[4][4];
  #pragma unroll
  for (int i=0;i<4;i++)
    #pragma unroll
    for (int j=0;j<4;j++) acc[i][j] = zero;

  const int row_s = tid >> 3;
  const int c16   = tid & 7;

  for (int term = 0; term < nterms; ++term){
    const u16* Ap = (term==2) ? A1 : A0;
    const u16* Bp = (term==1) ? B1 : B0;
    for (int k0 = 0; k0 < K; k0 += 64){
      #pragma unroll
      for (int q=0;q<4;q++){
        int ra = q*32 + row_s;
        int cs = c16 ^ (ra & 7);
        gl_lds16(Ap + (size_t)(m0 + ra)*K + k0 + cs*8, (char*)As + q*4096 + tid*16);
        gl_lds16(Bp + (size_t)(n0 + ra)*K + k0 + cs*8, (char*)Bs + q*4096 + tid*16);
      }
      __syncthreads();
      #pragma unroll
      for (int kk=0; kk<64; kk+=32){
        i32x4 af[4], bfr[4];
        #pragma unroll
        for (int mf=0;mf<4;mf++){
          int row = mbase + mf*16 + lr;
          af[mf] = *(const i32x4*)((const char*)As + row*128 + (((kk*2) + (lg*16)) ^ ((row&7)<<4)));
        }
        #pragma unroll
        for (int nf=0;nf<4;nf++){
          int row = nbase + nf*16 + lr;
          bfr[nf] = *(const i32x4*)((const char*)Bs + row*128 + (((kk*2) + (lg*16)) ^ ((row&7)<<4)));
        }
        #pragma unroll
        for (int mf=0;mf<4;mf++)
          #pragma unroll
          for (int nf=0;nf<4;nf++)
            acc[mf][nf] = mfma16(af[mf], bfr[nf], acc[mf][nf]);
      }
      __syncthreads();
    }
  }

  if (MODE == 2){
    // fused prep: this wave's 64 columns are exactly one head (N=512, nbase 64-aligned)
    const int hh = (n0 + nbase) >> 6;
    #pragma unroll
    for (int mf=0;mf<4;mf++){
      f32x4 v[4];
      #pragma unroll
      for (int nf=0;nf<4;nf++) v[nf] = acc_fence(acc[mf][nf]);
      #pragma unroll
      for (int r=0;r<4;r++){
        float ss = 0.f;
        #pragma unroll
        for (int nf=0;nf<4;nf++) ss += v[nf][r]*v[nf][r];
        ss += __shfl_xor(ss, 1); ss += __shfl_xor(ss, 2);
        ss += __shfl_xor(ss, 4); ss += __shfl_xor(ss, 8);
        float scale = 1.f / fmaxf(sqrtf(ss), 1e-6f);
        int m = m0 + mbase + mf*16 + lg*4 + r;
        int b = m >> 12, t = m & 4095;
        size_t rowb = ((((size_t)(b*8 + hh)) << 12) + t) * 64;
        #pragma unroll
        for (int nf=0;nf<4;nf++){
          float val = v[nf][r];
          u16 hbf = f2bf(val);
          size_t idx = rowb + nf*16 + lr;
          Cb [idx] = hbf;
          Cb2[idx] = f2bf(val - bf2f(hbf));
          Cb3[idx] = f2bf(val * scale);
        }
      }
    }
    return;
  }

  #pragma unroll
  for (int mf=0;mf<4;mf++){
    #pragma unroll
    for (int nf=0;nf<4;nf++){
      f32x4 v = acc_fence(acc[mf][nf]);
      #pragma unroll
      for (int r=0;r<4;r++){
        int m = m0 + mbase + mf*16 + lg*4 + r;
        int n = n0 + nbase + nf*16 + lr;
        float val = v[r];
        if (MODE == 0){
          if (bias) val += bias[n];
          Cf[(size_t)m*N + n] = val;
        } else if (MODE == 1){
          val += bias[n];
          val = fmaxf(val, 0.f);
          Cb[(size_t)m*N + n] = f2bf(val);
        } else {
          int b = m >> 12, t = m & 4095, h = n >> 6, d = n & 63;
          size_t idx = ((((size_t)(b*8 + h)) << 12) + t)*64 + d;
          Cb[idx] = f2bf(val);
        }
      }
    }
  }
}

// ---------------- LSH hash: swapped-operand MFMA, lane-local argmax ----------------
__global__ __launch_bounds__(256) void k_hash2(
    const u16* __restrict__ qh, const u16* __restrict__ ql,
    const u16* __restrict__ rh, const u16* __restrict__ rl,
    int* __restrict__ bkt)
{
  const int tid = threadIdx.x;
  const int l = tid & 63, w = tid >> 6, lr = l & 15, lg = l >> 4;
  __shared__ __align__(16) u16 Rh[128*64];
  __shared__ __align__(16) u16 Rl[128*64];
  {
    const int row_s = tid >> 3, c8 = tid & 7;
    #pragma unroll
    for (int q = 0; q < 4; q++){
      int ra = q*32 + row_s;
      int cs = c8 ^ (ra & 7);
      gl_lds16(rh + ra*64 + cs*8, (char*)Rh + q*4096 + tid*16);
      gl_lds16(rl + ra*64 + cs*8, (char*)Rl + q*4096 + tid*16);
    }
  }
  const int blk = xcd_swz(blockIdx.x, gridDim.x);
  const int qrow = blk*64 + w*16 + lr;
  const size_t qoff = (size_t)qrow*64;
  i32x4 qhf[2], qlf[2];
  qhf[0] = *(const i32x4*)(qh + qoff + lg*8);
  qhf[1] = *(const i32x4*)(qh + qoff + 32 + lg*8);
  qlf[0] = *(const i32x4*)(ql + qoff + lg*8);
  qlf[1] = *(const i32x4*)(ql + qoff + 32 + lg*8);
  __syncthreads();

  f32x4 zero = {0.f,0.f,0.f,0.f};
  f32x4 acc[8];
  #pragma unroll
  for (int i=0;i<8;i++) acc[i] = zero;
  #pragma unroll
  for (int ks = 0; ks < 2; ks++){
    #pragma unroll
    for (int nf = 0; nf < 8; nf++){
      int row = nf*16 + lr;
      int off = (ks*64 + lg*16) ^ ((row & 7) << 4);
      i32x4 rhf = *(const i32x4*)((const char*)Rh + row*128 + off);
      i32x4 rlf = *(const i32x4*)((const char*)Rl + row*128 + off);
      acc[nf] = mfma16(rhf, qhf[ks], acc[nf]);
      acc[nf] = mfma16(rlf, qhf[ks], acc[nf]);
      acc[nf] = mfma16(rhf, qlf[ks], acc[nf]);
    }
  }

  const int bh = qrow >> 12, t = qrow & 4095;
  #pragma unroll
  for (int hh = 0; hh < 4; hh++){
    f32x4 v0 = acc_fence(acc[2*hh]);
    f32x4 v1 = acc_fence(acc[2*hh+1]);
    unsigned long long kmax = 0, kmin = 0;
    #pragma unroll
    for (int r = 0; r < 4; r++){
      int j0 = lg*4 + r, j1 = 16 + lg*4 + r;
      unsigned int mu0 = f2mono(v0[r]), mu1 = f2mono(v1[r]);
      unsigned long long a = ((unsigned long long)mu0 << 32) | (unsigned int)(31 - j0);
      unsigned long long b = ((unsigned long long)mu1 << 32) | (unsigned int)(31 - j1);
      if (a > kmax) kmax = a;
      if (b > kmax) kmax = b;
      unsigned long long c = ((unsigned long long)(~mu0) << 32) | (unsigned int)(31 - j0);
      unsigned long long d = ((unsigned long long)(~mu1) << 32) | (unsigned int)(31 - j1);
      if (c > kmin) kmin = c;
      if (d > kmin) kmin = d;
    }
    #pragma unroll
    for (int msk = 16; msk < 64; msk <<= 1){
      unsigned long long o1 = shfl_xor_u64(kmax, msk); if (o1 > kmax) kmax = o1;
      unsigned long long o2 = shfl_xor_u64(kmin, msk); if (o2 > kmin) kmin = o2;
    }
    if (lg == 0){
      float vmax = mono2f((unsigned int)(kmax >> 32));
      int jmax = 31 - (int)(kmax & 0xFFFFFFFFull);
      float vmin = mono2f(~(unsigned int)(kmin >> 32));
      int jmin = 31 - (int)(kmin & 0xFFFFFFFFull);
      int bucket = (vmax >= -vmin) ? jmax : 32 + jmin;
      bkt[((size_t)(bh*4 + hh) << 12) + t] = bucket;
    }
  }
}

// ---------------- stable counting sort per (bh, round) ----------------
__global__ __launch_bounds__(64) void k_sort(const int* __restrict__ buckets, int* __restrict__ st){
  const int grp = blockIdx.x;
  const int t = threadIdx.x;
  __shared__ int hist[64][65];
  __shared__ int tot[64];
  const size_t gbase = ((size_t)grp) << 12;
  #pragma unroll
  for (int b=0;b<64;b++) hist[t][b] = 0;
  __syncthreads();
  for (int i=0;i<64;i++){
    int b = buckets[gbase + t*64 + i];
    hist[t][b]++;
  }
  __syncthreads();
  { int run = 0;
    for (int tt=0; tt<64; tt++){ int v = hist[tt][t]; hist[tt][t] = run; run += v; }
    tot[t] = run; }
  __syncthreads();
  { int v = tot[t]; int incl = v;
    #pragma unroll
    for (int d=1; d<64; d<<=1){ int n = __shfl_up(incl, d, 64); if (t >= d) incl += n; }
    tot[t] = incl - v; }
  __syncthreads();
  const size_t obase = (((size_t)(grp>>2)) << 14) + ((size_t)(grp&3) << 12);
  for (int i=0;i<64;i++){
    int e = t*64 + i;
    int b = buckets[gbase + e];
    int dest = tot[b] + hist[t][b];
    hist[t][b]++;
    st[obase + dest] = e;
  }
}

// ---------------- chunked LSH attention: swapped QK^T, in-reg softmax ----------------
__global__ __launch_bounds__(256, 4) void k_attn(
    const u16* __restrict__ qb, const u16* __restrict__ kn, const u16* __restrict__ vB,
    const int* __restrict__ st, float* __restrict__ lgt_out, u16* __restrict__ bo)
{
  int flat = blockIdx.y * gridDim.x + blockIdx.x;
  flat = xcd_swz(flat, gridDim.x * gridDim.y);
  const int c = flat & 255, bh = flat >> 8;
  const int rnd = c >> 6;
  const int tid = threadIdx.x;
  const int l = tid & 63, w = tid >> 6, lr = l & 15, lg = l >> 4;

  __shared__ __align__(16) u16 Ks[128*64];
  __shared__ __align__(16) u16 Vt[64][136];
  __shared__ int posk[128];

  if (tid < 128){
    int cc = (tid < 64) ? c : ((c + 255) & 255);
    posk[tid] = st[(((size_t)bh) << 14) + (cc << 6) + (tid & 63)];
  }
  __syncthreads();

  const size_t kvbase = ((size_t)bh) << 12;

  {
    const int rsub = l >> 3, c8 = l & 7;
    #pragma unroll
    for (int q2 = 0; q2 < 4; q2++){
      int row = w*32 + q2*8 + rsub;
      int cs = c8 ^ (row & 7);
      gl_lds16(kn + (kvbase + posk[row])*64 + cs*8,
               (char*)Ks + (w*4 + q2)*1024 + l*16);
    }
  }

  const int pos_q16 = posk[w*16 + lr];
  i32x4 qf[2];
  #pragma unroll
  for (int ks = 0; ks < 2; ks++)
    qf[ks] = *(const i32x4*)(qb + (kvbase + pos_q16)*64 + ks*32 + lg*8);

  {
    const int pp = tid & 63, db = tid >> 6;
    const int q5 = pp & 15;
    const int K0 = (pp >> 4)*32 + 16*((q5 >> 1) & 1) + 4*(q5 >> 2) + 2*(q5 & 1);
    const u16* r0 = vB + (kvbase + posk[K0])*64 + db*16;
    const u16* r1 = vB + (kvbase + posk[K0+1])*64 + db*16;
    uint4 a0 = *(const uint4*)r0, a1 = *(const uint4*)(r0 + 8);
    uint4 b0 = *(const uint4*)r1, b1 = *(const uint4*)(r1 + 8);
    uint av[8] = {a0.x,a0.y,a0.z,a0.w,a1.x,a1.y,a1.z,a1.w};
    uint bv[8] = {b0.x,b0.y,b0.z,b0.w,b1.x,b1.y,b1.z,b1.w};
    #pragma unroll
    for (int dd = 0; dd < 16; dd++){
      uint lo = (av[dd>>1] >> ((dd&1)*16)) & 0xFFFFu;
      uint hi = (bv[dd>>1] >> ((dd&1)*16)) & 0xFFFFu;
      *(uint*)((char*)&Vt[db*16 + dd][0] + pp*4) = lo | (hi << 16);
    }
  }
  __syncthreads();

  f32x4 zero = {0.f,0.f,0.f,0.f};
  f32x4 s[8];
  #pragma unroll
  for (int i=0;i<8;i++) s[i] = zero;
  #pragma unroll
  for (int ks = 0; ks < 2; ks++){
    #pragma unroll
    for (int nf = 0; nf < 8; nf++){
      int row = nf*16 + lr;
      i32x4 kf = *(const i32x4*)((const char*)Ks + row*128 + ((ks*64 + lg*16) ^ ((row&7)<<4)));
      s[nf] = mfma16(kf, qf[ks], s[nf]);
    }
  }

  float sv[8][4];
  const int q_loc = w*16 + lr;
  #pragma unroll
  for (int nf=0;nf<8;nf++){
    f32x4 t = acc_fence(s[nf]);
    #pragma unroll
    for (int r=0;r<4;r++){
      int k = nf*16 + lg*4 + r;
      sv[nf][r] = (k == q_loc) ? -5e4f : t[r]*0.125f;
    }
  }
  float m = -1e30f;
  #pragma unroll
  for (int nf=0;nf<8;nf++)
    #pragma unroll
    for (int r=0;r<4;r++) m = fmaxf(m, sv[nf][r]);
  m = fmaxf(m, __shfl_xor(m, 16));
  m = fmaxf(m, __shfl_xor(m, 32));
  // single-exp: p = exp(s-m) in place, then scale by 1/sum
  float sum = 0.f;
  #pragma unroll
  for (int nf=0;nf<8;nf++)
    #pragma unroll
    for (int r=0;r<4;r++){ sv[nf][r] = __expf(sv[nf][r] - m); sum += sv[nf][r]; }
  sum += __shfl_xor(sum, 16);
  sum += __shfl_xor(sum, 32);
  float lv = m + logf(sum);
  float inv = 1.f / sum;
  if (l < 16)
    lgt_out[(((size_t)(bh*4 + rnd)) << 12) + pos_q16] = lv;

  i32x4 pa[4];
  #pragma unroll
  for (int ks=0;ks<4;ks++){
    uint wd[4];
    #pragma unroll
    for (int h2=0; h2<2; h2++){
      int nf = 2*ks + h2;
      float p0 = sv[nf][0]*inv, p1 = sv[nf][1]*inv;
      float p2 = sv[nf][2]*inv, p3 = sv[nf][3]*inv;
      wd[h2*2]   = (uint)f2bf(p0) | ((uint)f2bf(p1)<<16);
      wd[h2*2+1] = (uint)f2bf(p2) | ((uint)f2bf(p3)<<16);
    }
    i32x4 t = {(int)wd[0],(int)wd[1],(int)wd[2],(int)wd[3]};
    pa[ks] = t;
  }

  f32x4 o[4];
  #pragma unroll
  for (int i=0;i<4;i++) o[i] = zero;
  #pragma unroll
  for (int ks=0;ks<4;ks++){
    #pragma unroll
    for (int nf=0;nf<4;nf++){
      i32x4 vf = *(const i32x4*)((const char*)&Vt[nf*16 + lr][0] + ks*64 + lg*16);
      o[nf] = mfma16(pa[ks], vf, o[nf]);
    }
  }
  #pragma unroll
  for (int nf=0;nf<4;nf++){
    f32x4 ov = acc_fence(o[nf]);
    #pragma unroll
    for (int r=0;r<4;r++){
      int q = w*16 + lg*4 + r;
      bo[((((size_t)(bh*4 + rnd)) << 12) + posk[q])*64 + nf*16 + lr] = f2bf(ov[r]);
    }
  }
}

// ---------------- combine hash rounds ----------------
__global__ __launch_bounds__(256) void k_combine(const u16* __restrict__ bo, const float* __restrict__ lgt,
                                                 u16* __restrict__ attn){
  const int wid = blockIdx.x * 4 + (threadIdx.x >> 6);
  const int l = threadIdx.x & 63;
  const int bh = wid >> 12, t = wid & 4095;
  const size_t lbase = (((size_t)bh) << 14) + t;
  float l0 = lgt[lbase], l1 = lgt[lbase + 4096], l2 = lgt[lbase + 8192], l3 = lgt[lbase + 12288];
  float m = fmaxf(fmaxf(l0,l1), fmaxf(l2,l3));
  float w0 = __expf(l0-m), w1 = __expf(l1-m), w2 = __expf(l2-m), w3 = __expf(l3-m);
  float inv = 1.f / (w0+w1+w2+w3);
  const size_t bbase = ((((size_t)bh) << 14) + t) * 64 + l;
  float o = w0 * bf2f(bo[bbase])
          + w1 * bf2f(bo[bbase + (size_t)4096*64])
          + w2 * bf2f(bo[bbase + (size_t)8192*64])
          + w3 * bf2f(bo[bbase + (size_t)12288*64]);
  o *= inv;
  int b = bh >> 3, h = bh & 7;
  attn[((((size_t)b) << 12) + t) * 512 + h*64 + l] = f2bf(o);
}

// ---------------- residual + LayerNorm ----------------
template<int WB16>
__global__ __launch_bounds__(256) void k_ln(const float* __restrict__ a, const float* __restrict__ res,
                                            const float* __restrict__ g, const float* __restrict__ bb,
                                            float* __restrict__ of, u16* __restrict__ ob){
  const int row = blockIdx.x*4 + (threadIdx.x >> 6);
  const int l = threadIdx.x & 63;
  const size_t base = (size_t)row*512 + l*8;
  float4 a0 = *(const float4*)(a + base);
  float4 a1 = *(const float4*)(a + base + 4);
  float4 r0 = *(const float4*)(res + base);
  float4 r1 = *(const float4*)(res + base + 4);
  float v[8] = {a0.x+r0.x, a0.y+r0.y, a0.z+r0.z, a0.w+r0.w,
                a1.x+r1.x, a1.y+r1.y, a1.z+r1.z, a1.w+r1.w};
  float sum = 0.f;
  #pragma unroll
  for (int j=0;j<8;j++) sum += v[j];
  #pragma unroll
  for (int msk=1; msk<64; msk<<=1) sum += __shfl_xor(sum, msk);
  float mean = sum * (1.f/512.f);
  float ss = 0.f;
  #pragma unroll
  for (int j=0;j<8;j++){ float d = v[j]-mean; ss += d*d; }
  #pragma unroll
  for (int msk=1; msk<64; msk<<=1) ss += __shfl_xor(ss, msk);
  float rstd = rsqrtf(ss * (1.f/512.f) + 1e-6f);
  float4 g0 = *(const float4*)(g + l*8),  g1 = *(const float4*)(g + l*8 + 4);
  float4 b0 = *(const float4*)(bb + l*8), b1 = *(const float4*)(bb + l*8 + 4);
  float gv[8] = {g0.x,g0.y,g0.z,g0.w,g1.x,g1.y,g1.z,g1.w};
  float bv[8] = {b0.x,b0.y,b0.z,b0.w,b1.x,b1.y,b1.z,b1.w};
  float y[8];
  #pragma unroll
  for (int j=0;j<8;j++) y[j] = (v[j]-mean)*rstd*gv[j] + bv[j];
  #pragma unroll
  for (int j=0;j<8;j++) of[base+j] = y[j];
  if (WB16){
    #pragma unroll
    for (int j=0;j<8;j++) ob[base+j] = f2bf(y[j]);
  }
}

extern "C" void kernel_launch(void* const* d_in, const int* in_sizes, int n_in,
                              void* d_out, int out_size, void* d_ws, size_t ws_size,
                              hipStream_t stream) {
  const float* x     = (const float*)d_in[0];
  const float* rot   = (const float*)d_in[1];
  const float* w_qk  = (const float*)d_in[2];
  const float* w_v   = (const float*)d_in[3];
  const float* w_out = (const float*)d_in[4];
  const float* b_out = (const float*)d_in[5];
  const float* ln1_g = (const float*)d_in[6];
  const float* ln1_b = (const float*)d_in[7];
  const float* w1    = (const float*)d_in[8];
  const float* b1    = (const float*)d_in[9];
  const float* w2    = (const float*)d_in[10];
  const float* b2    = (const float*)d_in[11];
  const float* ln2_g = (const float*)d_in[12];
  const float* ln2_b = (const float*)d_in[13];
  float* out = (float*)d_out;

  char* p = (char*)d_ws;
  u16*   xh   = (u16*)(p);                    // x-hi   | later: hb
  u16*   xl   = (u16*)(p + 16777216);         // x-lo   | later: attnc
  u16*   wqkh = (u16*)(p + 33554432);         //        | later: rotT hi
  u16*   wqkl = (u16*)(p + 34078720);         //        | later: rotT lo
  u16*   wvb  = (u16*)(p + 34603008);
  u16*   wob  = (u16*)(p + 35127296);
  u16*   w1b  = (u16*)(p + 35651584);
  u16*   w2b  = (u16*)(p + 37748736);
  u16*   qbuf = (u16*)(p + 39845888);         // qk bf16 hi (head layout) | later region: hf
  u16*   knb  = (u16*)(p + 56623104);         // kn bf16 (head layout)
  u16*   vb   = (u16*)(p + 73400320);
  int*   bkt  = (int*)(p + 90177536);
  int*   stb  = (int*)(p + 92274688);
  float* lgt  = (float*)(p + 94371840);
  u16*   bo   = (u16*)(p + 96468992);         // 67 MB  | early: qlo, later: ffn hidden
  // aliases (non-overlapping lifetimes)
  u16*   qlo   = bo;                 // dead before k_attn writes bo
  u16*   rothi = wqkh;               // dead after qk-gemm
  u16*   rotlo = wqkl;
  u16*   attnc = xl;
  float* hf    = (float*)(p + 39845888);   // overwrites qbuf/knb after attn done
  u16*   hb    = xh;
  u16*   hid   = bo;

  // 1) dtype converts / splits
  k_split<<<8192, 256, 0, stream>>>(x, xh, xl, 16384*512/4);
  k_split<<<256,  256, 0, stream>>>(w_qk, wqkh, wqkl, 512*512/4);
  k_cvt  <<<256,  256, 0, stream>>>(w_v,   wvb, 512*512/4);
  k_cvt  <<<256,  256, 0, stream>>>(w_out, wob, 512*512/4);
  k_cvt  <<<1024, 256, 0, stream>>>(w1, w1b, 2048*512/4);
  k_cvt  <<<1024, 256, 0, stream>>>(w2, w2b, 2048*512/4);

  // 2) qk = x @ w_qk^T (3-term split bf16) with fused prep epilogue -> qb/qlo/kn
  k_gemm<2><<<dim3(4,128), 256, 0, stream>>>(xh, xl, wqkh, wqkl, nullptr, nullptr, qbuf, qlo, knb, 16384, 512, 512, 3);
  // 3) v = x @ w_v^T, head layout bf16
  k_gemm<3><<<dim3(4,128), 256, 0, stream>>>(xh, nullptr, wvb, nullptr, nullptr, nullptr, vb, nullptr, nullptr, 16384, 512, 512, 1);
  // 4) rot transpose+split (wqkh/wqkl now dead)
  k_rotT<<<32, 256, 0, stream>>>(rot, rothi, rotlo);
  // 5) LSH hash: S^T = rot x qk (3-term split), lane-local argmax -> buckets
  k_hash2<<<2048, 256, 0, stream>>>(qbuf, qlo, rothi, rotlo, bkt);
  // 6) stable counting sort per (bh, round)
  k_sort<<<128, 64, 0, stream>>>(bkt, stb);
  // 7) chunked attention
  k_attn<<<dim3(256,32), 256, 0, stream>>>(qbuf, knb, vb, stb, lgt, bo);
  // 8) combine rounds -> (b,t,512) bf16
  k_combine<<<32768, 256, 0, stream>>>(bo, lgt, attnc);
  // 9) out projection (+bias) -> d_out (scratch)
  k_gemm<0><<<dim3(4,128), 256, 0, stream>>>(attnc, nullptr, wob, nullptr, b_out, out, nullptr, nullptr, nullptr, 16384, 512, 512, 1);
  // 10) h = LN(attn + x)
  k_ln<1><<<4096, 256, 0, stream>>>(out, x, ln1_g, ln1_b, hf, hb);
  // 11) hidden = relu(h @ w1^T + b1) bf16
  k_gemm<1><<<dim3(16,128), 256, 0, stream>>>(hb, nullptr, w1b, nullptr, b1, nullptr, hid, nullptr, nullptr, 16384, 2048, 512, 1);
  // 12) f = hidden @ w2^T + b2 -> d_out
  k_gemm<0><<<dim3(4,128), 256, 0, stream>>>(hid, nullptr, w2b, nullptr, b2, out, nullptr, nullptr, nullptr, 16384, 512, 2048, 1);
  // 13) out = LN(f + h)  (in place on d_out)
  k_ln<0><<<4096, 256, 0, stream>>>(out, hf, ln2_g, ln2_b, out, nullptr);
}

// Round 6
// 314.998 us; speedup vs baseline: 1.5137x; 1.0601x over previous
//
#include <hip/hip_runtime.h>
#include <stdint.h>

// Reformer layer: B=4 T=4096 D=512 H=8 DH=64 N_HASH=4 N_BUCKET=64 BUCKET=64 FFN=2048
typedef unsigned short u16;
typedef __attribute__((ext_vector_type(4))) int   i32x4;
typedef __attribute__((ext_vector_type(4))) float f32x4;

__device__ __forceinline__ u16 f2bf(float x){
  unsigned int u = __float_as_uint(x);
  u += 0x7FFFu + ((u >> 16) & 1u);
  return (u16)(u >> 16);
}
__device__ __forceinline__ float bf2f(u16 h){
  return __uint_as_float(((unsigned int)h) << 16);
}
__device__ __forceinline__ unsigned int cvtpk_bf16(float lo, float hi){
  unsigned int r;
  asm("v_cvt_pk_bf16_f32 %0, %1, %2" : "=v"(r) : "v"(lo), "v"(hi));
  return r;
}
__device__ __forceinline__ f32x4 mfma16(i32x4 a, i32x4 b, f32x4 c){
  asm("v_mfma_f32_16x16x32_bf16 %0, %1, %2, %0" : "+v"(c) : "v"(a), "v"(b));
  return c;
}
__device__ __forceinline__ f32x4 acc_fence(f32x4 c){
  asm volatile("s_nop 7\ns_nop 7" : "+v"(c));
  return c;
}
__device__ __forceinline__ void gl_lds16(const void* g, void* l){
  unsigned long long ga = (unsigned long long)g;
  unsigned int la = (unsigned int)(unsigned long long)l;
  __builtin_amdgcn_global_load_lds((const __attribute__((address_space(1))) void*)ga,
                                   (__attribute__((address_space(3))) void*)la, 16, 0, 0);
}
// XCD-chunked bijective swizzle (requires n % 8 == 0)
__device__ __forceinline__ int xcd_swz(int f, int n){
  int chunk = n >> 3;
  return (f & 7) * chunk + (f >> 3);
}
// monotonic-uint transform: order-preserving for fp32 compares
__device__ __forceinline__ unsigned int f2mono(float v){
  unsigned int u = __float_as_uint(v);
  return u ^ ((unsigned int)((int)u >> 31) | 0x80000000u);
}
__device__ __forceinline__ float mono2f(unsigned int mu){
  unsigned int u = (mu & 0x80000000u) ? (mu ^ 0x80000000u) : ~mu;
  return __uint_as_float(u);
}
__device__ __forceinline__ unsigned long long shfl_xor_u64(unsigned long long x, int m){
  int lo = __shfl_xor((int)(unsigned int)(x & 0xFFFFFFFFull), m);
  int hi = __shfl_xor((int)(unsigned int)(x >> 32), m);
  return ((unsigned long long)(unsigned int)hi << 32) | (unsigned int)lo;
}

// ---------------- converts ----------------
__global__ __launch_bounds__(256) void k_cvt(const float* __restrict__ in, u16* __restrict__ out, int n4){
  int i = blockIdx.x*256 + threadIdx.x;
  if (i >= n4) return;
  float4 v = ((const float4*)in)[i];
  ushort4 o; o.x=f2bf(v.x); o.y=f2bf(v.y); o.z=f2bf(v.z); o.w=f2bf(v.w);
  ((ushort4*)out)[i] = o;
}
__global__ __launch_bounds__(256) void k_split(const float* __restrict__ in, u16* __restrict__ hi, u16* __restrict__ lo, int n4){
  int i = blockIdx.x*256 + threadIdx.x;
  if (i >= n4) return;
  float4 v = ((const float4*)in)[i];
  ushort4 h, l;
  h.x=f2bf(v.x); l.x=f2bf(v.x - bf2f(h.x));
  h.y=f2bf(v.y); l.y=f2bf(v.y - bf2f(h.y));
  h.z=f2bf(v.z); l.z=f2bf(v.z - bf2f(h.z));
  h.w=f2bf(v.w); l.w=f2bf(v.w - bf2f(h.w));
  ((ushort4*)hi)[i]=h; ((ushort4*)lo)[i]=l;
}
// rot (64 x 4 x 32) -> rotT[n=h*32+i][d] bf16 hi/lo
__global__ __launch_bounds__(256) void k_rotT(const float* __restrict__ rot, u16* __restrict__ hi, u16* __restrict__ lo){
  int i = blockIdx.x*256 + threadIdx.x;
  if (i >= 8192) return;
  int d = i & 63, n = i >> 6;
  float v = rot[d*128 + n];
  u16 h = f2bf(v);
  hi[i] = h; lo[i] = f2bf(v - bf2f(h));
}

// ---------------- generic bf16 MFMA GEMM: C = A * B^T ----------------
// MODE 0: fp32 rowmajor (+bias)   MODE 1: bf16 rowmajor, bias+relu   MODE 3: bf16 head-layout (v)
template<int MODE>
__global__ __launch_bounds__(256) void k_gemm(
    const u16* __restrict__ A0, const u16* __restrict__ B0,
    const float* __restrict__ bias,
    float* __restrict__ Cf, u16* __restrict__ Cb,
    int M, int N, int K)
{
  const int tid = threadIdx.x;
  const int l = tid & 63, w = tid >> 6;
  const int lr = l & 15, lg = l >> 4;
  int flat = blockIdx.y * gridDim.x + blockIdx.x;
  flat = xcd_swz(flat, gridDim.x * gridDim.y);
  const int m0 = (flat / gridDim.x) * 128, n0 = (flat % gridDim.x) * 128;
  const int mbase = (w >> 1) * 64, nbase = (w & 1) * 64;

  __shared__ __align__(16) u16 As[128*64];
  __shared__ __align__(16) u16 Bs[128*64];

  f32x4 zero = {0.f,0.f,0.f,0.f};
  f32x4 acc[4][4];
  #pragma unroll
  for (int i=0;i<4;i++)
    #pragma unroll
    for (int j=0;j<4;j++) acc[i][j] = zero;

  const int row_s = tid >> 3;
  const int c16   = tid & 7;

  for (int k0 = 0; k0 < K; k0 += 64){
    #pragma unroll
    for (int q=0;q<4;q++){
      int ra = q*32 + row_s;
      int cs = c16 ^ (ra & 7);
      gl_lds16(A0 + (size_t)(m0 + ra)*K + k0 + cs*8, (char*)As + q*4096 + tid*16);
      gl_lds16(B0 + (size_t)(n0 + ra)*K + k0 + cs*8, (char*)Bs + q*4096 + tid*16);
    }
    __syncthreads();
    #pragma unroll
    for (int kk=0; kk<64; kk+=32){
      i32x4 af[4], bfr[4];
      #pragma unroll
      for (int mf=0;mf<4;mf++){
        int row = mbase + mf*16 + lr;
        af[mf] = *(const i32x4*)((const char*)As + row*128 + (((kk*2) + (lg*16)) ^ ((row&7)<<4)));
      }
      #pragma unroll
      for (int nf=0;nf<4;nf++){
        int row = nbase + nf*16 + lr;
        bfr[nf] = *(const i32x4*)((const char*)Bs + row*128 + (((kk*2) + (lg*16)) ^ ((row&7)<<4)));
      }
      #pragma unroll
      for (int mf=0;mf<4;mf++)
        #pragma unroll
        for (int nf=0;nf<4;nf++)
          acc[mf][nf] = mfma16(af[mf], bfr[nf], acc[mf][nf]);
    }
    __syncthreads();
  }

  #pragma unroll
  for (int mf=0;mf<4;mf++){
    #pragma unroll
    for (int nf=0;nf<4;nf++){
      f32x4 v = acc_fence(acc[mf][nf]);
      #pragma unroll
      for (int r=0;r<4;r++){
        int m = m0 + mbase + mf*16 + lg*4 + r;
        int n = n0 + nbase + nf*16 + lr;
        float val = v[r];
        if (MODE == 0){
          if (bias) val += bias[n];
          Cf[(size_t)m*N + n] = val;
        } else if (MODE == 1){
          val += bias[n];
          val = fmaxf(val, 0.f);
          Cb[(size_t)m*N + n] = f2bf(val);
        } else {
          int b = m >> 12, t = m & 4095, h = n >> 6, d = n & 63;
          size_t idx = ((((size_t)(b*8 + h)) << 12) + t)*64 + d;
          Cb[idx] = f2bf(val);
        }
      }
    }
  }
}

// ---------------- qk GEMM: single-pass 3-term split-bf16 + fused prep epilogue ----------------
// out: qb (bf16 hi), qlo (bf16 lo), kn (normalized * 0.125, bf16), all head-layout
__global__ __launch_bounds__(256) void k_gemmqk(
    const u16* __restrict__ Ah, const u16* __restrict__ Al,
    const u16* __restrict__ Bh, const u16* __restrict__ Bl,
    u16* __restrict__ qb, u16* __restrict__ qlo, u16* __restrict__ kn)
{
  const int K = 512;
  const int tid = threadIdx.x;
  const int l = tid & 63, w = tid >> 6;
  const int lr = l & 15, lg = l >> 4;
  int flat = blockIdx.y * gridDim.x + blockIdx.x;
  flat = xcd_swz(flat, gridDim.x * gridDim.y);
  const int m0 = (flat >> 2) * 128, n0 = (flat & 3) * 128;
  const int mbase = (w >> 1) * 64, nbase = (w & 1) * 64;

  __shared__ __align__(16) u16 AsH[128*64];
  __shared__ __align__(16) u16 AsL[128*64];
  __shared__ __align__(16) u16 BsH[128*64];
  __shared__ __align__(16) u16 BsL[128*64];

  f32x4 zero = {0.f,0.f,0.f,0.f};
  f32x4 acc[4][4];
  #pragma unroll
  for (int i=0;i<4;i++)
    #pragma unroll
    for (int j=0;j<4;j++) acc[i][j] = zero;

  const int row_s = tid >> 3;
  const int c16   = tid & 7;

  for (int k0 = 0; k0 < K; k0 += 64){
    #pragma unroll
    for (int q=0;q<4;q++){
      int ra = q*32 + row_s;
      int cs = c16 ^ (ra & 7);
      size_t ao = (size_t)(m0 + ra)*K + k0 + cs*8;
      size_t bo = (size_t)(n0 + ra)*K + k0 + cs*8;
      gl_lds16(Ah + ao, (char*)AsH + q*4096 + tid*16);
      gl_lds16(Al + ao, (char*)AsL + q*4096 + tid*16);
      gl_lds16(Bh + bo, (char*)BsH + q*4096 + tid*16);
      gl_lds16(Bl + bo, (char*)BsL + q*4096 + tid*16);
    }
    __syncthreads();
    #pragma unroll
    for (int kk=0; kk<64; kk+=32){
      i32x4 ah[4], al[4], bh2[4], bl2[4];
      #pragma unroll
      for (int mf=0;mf<4;mf++){
        int row = mbase + mf*16 + lr;
        int off = (((kk*2) + (lg*16)) ^ ((row&7)<<4));
        ah[mf] = *(const i32x4*)((const char*)AsH + row*128 + off);
        al[mf] = *(const i32x4*)((const char*)AsL + row*128 + off);
      }
      #pragma unroll
      for (int nf=0;nf<4;nf++){
        int row = nbase + nf*16 + lr;
        int off = (((kk*2) + (lg*16)) ^ ((row&7)<<4));
        bh2[nf] = *(const i32x4*)((const char*)BsH + row*128 + off);
        bl2[nf] = *(const i32x4*)((const char*)BsL + row*128 + off);
      }
      #pragma unroll
      for (int mf=0;mf<4;mf++)
        #pragma unroll
        for (int nf=0;nf<4;nf++){
          acc[mf][nf] = mfma16(ah[mf], bh2[nf], acc[mf][nf]);
          acc[mf][nf] = mfma16(al[mf], bh2[nf], acc[mf][nf]);
          acc[mf][nf] = mfma16(ah[mf], bl2[nf], acc[mf][nf]);
        }
    }
    __syncthreads();
  }

  // fused prep epilogue: this wave's 64 columns are exactly one head
  const int hh = (n0 + nbase) >> 6;
  #pragma unroll
  for (int mf=0;mf<4;mf++){
    f32x4 v[4];
    #pragma unroll
    for (int nf=0;nf<4;nf++) v[nf] = acc_fence(acc[mf][nf]);
    #pragma unroll
    for (int r=0;r<4;r++){
      float ss = 0.f;
      #pragma unroll
      for (int nf=0;nf<4;nf++) ss += v[nf][r]*v[nf][r];
      ss += __shfl_xor(ss, 1); ss += __shfl_xor(ss, 2);
      ss += __shfl_xor(ss, 4); ss += __shfl_xor(ss, 8);
      float scale = 0.125f / fmaxf(sqrtf(ss), 1e-6f);   // fold dim_head^-0.5 into kn
      int m = m0 + mbase + mf*16 + lg*4 + r;
      int b = m >> 12, t = m & 4095;
      size_t rowb = ((((size_t)(b*8 + hh)) << 12) + t) * 64;
      #pragma unroll
      for (int nf=0;nf<4;nf++){
        float val = v[nf][r];
        u16 hbf = f2bf(val);
        size_t idx = rowb + nf*16 + lr;
        qb [idx] = hbf;
        qlo[idx] = f2bf(val - bf2f(hbf));
        kn [idx] = f2bf(val * scale);
      }
    }
  }
}

// ---------------- LSH hash: swapped-operand MFMA, lane-local argmax ----------------
__global__ __launch_bounds__(256) void k_hash2(
    const u16* __restrict__ qh, const u16* __restrict__ ql,
    const u16* __restrict__ rh, const u16* __restrict__ rl,
    int* __restrict__ bkt)
{
  const int tid = threadIdx.x;
  const int l = tid & 63, w = tid >> 6, lr = l & 15, lg = l >> 4;
  __shared__ __align__(16) u16 Rh[128*64];
  __shared__ __align__(16) u16 Rl[128*64];
  {
    const int row_s = tid >> 3, c8 = tid & 7;
    #pragma unroll
    for (int q = 0; q < 4; q++){
      int ra = q*32 + row_s;
      int cs = c8 ^ (ra & 7);
      gl_lds16(rh + ra*64 + cs*8, (char*)Rh + q*4096 + tid*16);
      gl_lds16(rl + ra*64 + cs*8, (char*)Rl + q*4096 + tid*16);
    }
  }
  const int blk = xcd_swz(blockIdx.x, gridDim.x);
  const int qrow = blk*64 + w*16 + lr;
  const size_t qoff = (size_t)qrow*64;
  i32x4 qhf[2], qlf[2];
  qhf[0] = *(const i32x4*)(qh + qoff + lg*8);
  qhf[1] = *(const i32x4*)(qh + qoff + 32 + lg*8);
  qlf[0] = *(const i32x4*)(ql + qoff + lg*8);
  qlf[1] = *(const i32x4*)(ql + qoff + 32 + lg*8);
  __syncthreads();

  f32x4 zero = {0.f,0.f,0.f,0.f};
  f32x4 acc[8];
  #pragma unroll
  for (int i=0;i<8;i++) acc[i] = zero;
  #pragma unroll
  for (int ks = 0; ks < 2; ks++){
    #pragma unroll
    for (int nf = 0; nf < 8; nf++){
      int row = nf*16 + lr;
      int off = (ks*64 + lg*16) ^ ((row & 7) << 4);
      i32x4 rhf = *(const i32x4*)((const char*)Rh + row*128 + off);
      i32x4 rlf = *(const i32x4*)((const char*)Rl + row*128 + off);
      acc[nf] = mfma16(rhf, qhf[ks], acc[nf]);
      acc[nf] = mfma16(rlf, qhf[ks], acc[nf]);
      acc[nf] = mfma16(rhf, qlf[ks], acc[nf]);
    }
  }

  const int bh = qrow >> 12, t = qrow & 4095;
  #pragma unroll
  for (int hh = 0; hh < 4; hh++){
    f32x4 v0 = acc_fence(acc[2*hh]);
    f32x4 v1 = acc_fence(acc[2*hh+1]);
    unsigned long long kmax = 0, kmin = 0;
    #pragma unroll
    for (int r = 0; r < 4; r++){
      int j0 = lg*4 + r, j1 = 16 + lg*4 + r;
      unsigned int mu0 = f2mono(v0[r]), mu1 = f2mono(v1[r]);
      unsigned long long a = ((unsigned long long)mu0 << 32) | (unsigned int)(31 - j0);
      unsigned long long b = ((unsigned long long)mu1 << 32) | (unsigned int)(31 - j1);
      if (a > kmax) kmax = a;
      if (b > kmax) kmax = b;
      unsigned long long c = ((unsigned long long)(~mu0) << 32) | (unsigned int)(31 - j0);
      unsigned long long d = ((unsigned long long)(~mu1) << 32) | (unsigned int)(31 - j1);
      if (c > kmin) kmin = c;
      if (d > kmin) kmin = d;
    }
    #pragma unroll
    for (int msk = 16; msk < 64; msk <<= 1){
      unsigned long long o1 = shfl_xor_u64(kmax, msk); if (o1 > kmax) kmax = o1;
      unsigned long long o2 = shfl_xor_u64(kmin, msk); if (o2 > kmin) kmin = o2;
    }
    if (lg == 0){
      float vmax = mono2f((unsigned int)(kmax >> 32));
      int jmax = 31 - (int)(kmax & 0xFFFFFFFFull);
      float vmin = mono2f(~(unsigned int)(kmin >> 32));
      int jmin = 31 - (int)(kmin & 0xFFFFFFFFull);
      int bucket = (vmax >= -vmin) ? jmax : 32 + jmin;
      bkt[((size_t)(bh*4 + hh) << 12) + t] = bucket;
    }
  }
}

// ---------------- stable counting sort per (bh, round) ----------------
__global__ __launch_bounds__(64) void k_sort(const int* __restrict__ buckets, int* __restrict__ st){
  const int grp = blockIdx.x;
  const int t = threadIdx.x;
  __shared__ int bkL[4096];
  __shared__ int hist[64][65];
  __shared__ int tot[64];
  const size_t gbase = ((size_t)grp) << 12;
  for (int i=0;i<64;i++)
    bkL[i*64 + t] = buckets[gbase + i*64 + t];   // coalesced
  #pragma unroll
  for (int b=0;b<64;b++) hist[t][b] = 0;
  __syncthreads();
  for (int i=0;i<64;i++){
    int b = bkL[t*64 + i];
    hist[t][b]++;
  }
  __syncthreads();
  { int run = 0;
    for (int tt=0; tt<64; tt++){ int v = hist[tt][t]; hist[tt][t] = run; run += v; }
    tot[t] = run; }
  __syncthreads();
  { int v = tot[t]; int incl = v;
    #pragma unroll
    for (int d=1; d<64; d<<=1){ int n = __shfl_up(incl, d, 64); if (t >= d) incl += n; }
    tot[t] = incl - v; }
  __syncthreads();
  const size_t obase = (((size_t)(grp>>2)) << 14) + ((size_t)(grp&3) << 12);
  for (int i=0;i<64;i++){
    int e = t*64 + i;
    int b = bkL[e];
    int dest = tot[b] + hist[t][b];
    hist[t][b]++;
    st[obase + dest] = e;
  }
}

// ---------------- chunked LSH attention: swapped QK^T, max-free in-reg softmax ----------------
__global__ __launch_bounds__(256, 4) void k_attn(
    const u16* __restrict__ qb, const u16* __restrict__ kn, const u16* __restrict__ vB,
    const int* __restrict__ st, float* __restrict__ lgt_out, u16* __restrict__ bo)
{
  int flat = blockIdx.y * gridDim.x + blockIdx.x;
  flat = xcd_swz(flat, gridDim.x * gridDim.y);
  const int c = flat & 255, bh = flat >> 8;
  const int rnd = c >> 6;
  const int tid = threadIdx.x;
  const int l = tid & 63, w = tid >> 6, lr = l & 15, lg = l >> 4;

  __shared__ __align__(16) u16 Ks[128*64];
  __shared__ __align__(16) u16 Vt[64][136];
  __shared__ int posk[128];

  if (tid < 128){
    int cc = (tid < 64) ? c : ((c + 255) & 255);
    posk[tid] = st[(((size_t)bh) << 14) + (cc << 6) + (tid & 63)];
  }
  __syncthreads();

  const size_t kvbase = ((size_t)bh) << 12;

  {
    const int rsub = l >> 3, c8 = l & 7;
    #pragma unroll
    for (int q2 = 0; q2 < 4; q2++){
      int row = w*32 + q2*8 + rsub;
      int cs = c8 ^ (row & 7);
      gl_lds16(kn + (kvbase + posk[row])*64 + cs*8,
               (char*)Ks + (w*4 + q2)*1024 + l*16);
    }
  }

  const int pos_q16 = posk[w*16 + lr];
  i32x4 qf[2];
  #pragma unroll
  for (int ks = 0; ks < 2; ks++)
    qf[ks] = *(const i32x4*)(qb + (kvbase + pos_q16)*64 + ks*32 + lg*8);

  {
    const int pp = tid & 63, db = tid >> 6;
    const int q5 = pp & 15;
    const int K0 = (pp >> 4)*32 + 16*((q5 >> 1) & 1) + 4*(q5 >> 2) + 2*(q5 & 1);
    const u16* r0 = vB + (kvbase + posk[K0])*64 + db*16;
    const u16* r1 = vB + (kvbase + posk[K0+1])*64 + db*16;
    uint4 a0 = *(const uint4*)r0, a1 = *(const uint4*)(r0 + 8);
    uint4 b0 = *(const uint4*)r1, b1 = *(const uint4*)(r1 + 8);
    uint av[8] = {a0.x,a0.y,a0.z,a0.w,a1.x,a1.y,a1.z,a1.w};
    uint bv[8] = {b0.x,b0.y,b0.z,b0.w,b1.x,b1.y,b1.z,b1.w};
    #pragma unroll
    for (int dd = 0; dd < 16; dd++){
      uint lo = (av[dd>>1] >> ((dd&1)*16)) & 0xFFFFu;
      uint hi = (bv[dd>>1] >> ((dd&1)*16)) & 0xFFFFu;
      *(uint*)((char*)&Vt[db*16 + dd][0] + pp*4) = lo | (hi << 16);
    }
  }
  __syncthreads();

  f32x4 zero = {0.f,0.f,0.f,0.f};
  f32x4 s[8];
  #pragma unroll
  for (int i=0;i<8;i++) s[i] = zero;
  __builtin_amdgcn_s_setprio(1);
  #pragma unroll
  for (int ks = 0; ks < 2; ks++){
    #pragma unroll
    for (int nf = 0; nf < 8; nf++){
      int row = nf*16 + lr;
      i32x4 kf = *(const i32x4*)((const char*)Ks + row*128 + ((ks*64 + lg*16) ^ ((row&7)<<4)));
      s[nf] = mfma16(kf, qf[ks], s[nf]);
    }
  }
  __builtin_amdgcn_s_setprio(0);

  // max-free softmax: |s| <= ~1 here (kn pre-scaled by 0.125, ||k||=1), exp cannot overflow
  float p[8][4];
  const int q_loc = w*16 + lr;
  float sum = 0.f;
  #pragma unroll
  for (int nf=0;nf<8;nf++){
    f32x4 t = acc_fence(s[nf]);
    #pragma unroll
    for (int r=0;r<4;r++){
      int k = nf*16 + lg*4 + r;
      float e = (k == q_loc) ? 0.f : __expf(t[r]);
      p[nf][r] = e;
      sum += e;
    }
  }
  sum += __shfl_xor(sum, 16);
  sum += __shfl_xor(sum, 32);
  float lv = logf(sum);
  float inv = 1.f / sum;
  if (l < 16)
    lgt_out[(((size_t)(bh*4 + rnd)) << 12) + pos_q16] = lv;

  // unnormalized P -> bf16 via cvt_pk; scale output by per-q inv afterwards
  i32x4 pa[4];
  #pragma unroll
  for (int ks=0;ks<4;ks++){
    uint w0 = cvtpk_bf16(p[2*ks][0],   p[2*ks][1]);
    uint w1 = cvtpk_bf16(p[2*ks][2],   p[2*ks][3]);
    uint w2 = cvtpk_bf16(p[2*ks+1][0], p[2*ks+1][1]);
    uint w3 = cvtpk_bf16(p[2*ks+1][2], p[2*ks+1][3]);
    i32x4 t = {(int)w0,(int)w1,(int)w2,(int)w3};
    pa[ks] = t;
  }

  f32x4 o[4];
  #pragma unroll
  for (int i=0;i<4;i++) o[i] = zero;
  __builtin_amdgcn_s_setprio(1);
  #pragma unroll
  for (int ks=0;ks<4;ks++){
    #pragma unroll
    for (int nf=0;nf<4;nf++){
      i32x4 vf = *(const i32x4*)((const char*)&Vt[nf*16 + lr][0] + ks*64 + lg*16);
      o[nf] = mfma16(pa[ks], vf, o[nf]);
    }
  }
  __builtin_amdgcn_s_setprio(0);
  float invq[4];
  #pragma unroll
  for (int r=0;r<4;r++) invq[r] = __shfl(inv, lg*4 + r, 64);
  #pragma unroll
  for (int nf=0;nf<4;nf++){
    f32x4 ov = acc_fence(o[nf]);
    #pragma unroll
    for (int r=0;r<4;r++){
      int q = w*16 + lg*4 + r;
      bo[((((size_t)(bh*4 + rnd)) << 12) + posk[q])*64 + nf*16 + lr] = f2bf(ov[r] * invq[r]);
    }
  }
}

// ---------------- combine hash rounds ----------------
__global__ __launch_bounds__(256) void k_combine(const u16* __restrict__ bo, const float* __restrict__ lgt,
                                                 u16* __restrict__ attn){
  const int wid = blockIdx.x * 4 + (threadIdx.x >> 6);
  const int l = threadIdx.x & 63;
  const int bh = wid >> 12, t = wid & 4095;
  const size_t lbase = (((size_t)bh) << 14) + t;
  float l0 = lgt[lbase], l1 = lgt[lbase + 4096], l2 = lgt[lbase + 8192], l3 = lgt[lbase + 12288];
  float m = fmaxf(fmaxf(l0,l1), fmaxf(l2,l3));
  float w0 = __expf(l0-m), w1 = __expf(l1-m), w2 = __expf(l2-m), w3 = __expf(l3-m);
  float inv = 1.f / (w0+w1+w2+w3);
  const size_t bbase = ((((size_t)bh) << 14) + t) * 64 + l;
  float o = w0 * bf2f(bo[bbase])
          + w1 * bf2f(bo[bbase + (size_t)4096*64])
          + w2 * bf2f(bo[bbase + (size_t)8192*64])
          + w3 * bf2f(bo[bbase + (size_t)12288*64]);
  o *= inv;
  int b = bh >> 3, h = bh & 7;
  attn[((((size_t)b) << 12) + t) * 512 + h*64 + l] = f2bf(o);
}

// ---------------- residual + LayerNorm ----------------
template<int WB16>
__global__ __launch_bounds__(256) void k_ln(const float* __restrict__ a, const float* __restrict__ res,
                                            const float* __restrict__ g, const float* __restrict__ bb,
                                            float* __restrict__ of, u16* __restrict__ ob){
  const int row = blockIdx.x*4 + (threadIdx.x >> 6);
  const int l = threadIdx.x & 63;
  const size_t base = (size_t)row*512 + l*8;
  float4 a0 = *(const float4*)(a + base);
  float4 a1 = *(const float4*)(a + base + 4);
  float4 r0 = *(const float4*)(res + base);
  float4 r1 = *(const float4*)(res + base + 4);
  float v[8] = {a0.x+r0.x, a0.y+r0.y, a0.z+r0.z, a0.w+r0.w,
                a1.x+r1.x, a1.y+r1.y, a1.z+r1.z, a1.w+r1.w};
  float sum = 0.f;
  #pragma unroll
  for (int j=0;j<8;j++) sum += v[j];
  #pragma unroll
  for (int msk=1; msk<64; msk<<=1) sum += __shfl_xor(sum, msk);
  float mean = sum * (1.f/512.f);
  float ss = 0.f;
  #pragma unroll
  for (int j=0;j<8;j++){ float d = v[j]-mean; ss += d*d; }
  #pragma unroll
  for (int msk=1; msk<64; msk<<=1) ss += __shfl_xor(ss, msk);
  float rstd = rsqrtf(ss * (1.f/512.f) + 1e-6f);
  float4 g0 = *(const float4*)(g + l*8),  g1 = *(const float4*)(g + l*8 + 4);
  float4 b0 = *(const float4*)(bb + l*8), b1 = *(const float4*)(bb + l*8 + 4);
  float gv[8] = {g0.x,g0.y,g0.z,g0.w,g1.x,g1.y,g1.z,g1.w};
  float bv[8] = {b0.x,b0.y,b0.z,b0.w,b1.x,b1.y,b1.z,b1.w};
  float y[8];
  #pragma unroll
  for (int j=0;j<8;j++) y[j] = (v[j]-mean)*rstd*gv[j] + bv[j];
  #pragma unroll
  for (int j=0;j<8;j++) of[base+j] = y[j];
  if (WB16){
    #pragma unroll
    for (int j=0;j<8;j++) ob[base+j] = f2bf(y[j]);
  }
}

extern "C" void kernel_launch(void* const* d_in, const int* in_sizes, int n_in,
                              void* d_out, int out_size, void* d_ws, size_t ws_size,
                              hipStream_t stream) {
  const float* x     = (const float*)d_in[0];
  const float* rot   = (const float*)d_in[1];
  const float* w_qk  = (const float*)d_in[2];
  const float* w_v   = (const float*)d_in[3];
  const float* w_out = (const float*)d_in[4];
  const float* b_out = (const float*)d_in[5];
  const float* ln1_g = (const float*)d_in[6];
  const float* ln1_b = (const float*)d_in[7];
  const float* w1    = (const float*)d_in[8];
  const float* b1    = (const float*)d_in[9];
  const float* w2    = (const float*)d_in[10];
  const float* b2    = (const float*)d_in[11];
  const float* ln2_g = (const float*)d_in[12];
  const float* ln2_b = (const float*)d_in[13];
  float* out = (float*)d_out;

  char* p = (char*)d_ws;
  u16*   xh   = (u16*)(p);                    // x-hi   | later: hb
  u16*   xl   = (u16*)(p + 16777216);         // x-lo   | later: attnc
  u16*   wqkh = (u16*)(p + 33554432);         //        | later: rotT hi
  u16*   wqkl = (u16*)(p + 34078720);         //        | later: rotT lo
  u16*   wvb  = (u16*)(p + 34603008);
  u16*   wob  = (u16*)(p + 35127296);
  u16*   w1b  = (u16*)(p + 35651584);
  u16*   w2b  = (u16*)(p + 37748736);
  u16*   qbuf = (u16*)(p + 39845888);         // qk bf16 hi (head layout) | later region: hf
  u16*   knb  = (u16*)(p + 56623104);         // kn bf16 (head layout, pre-scaled 1/8)
  u16*   vb   = (u16*)(p + 73400320);
  int*   bkt  = (int*)(p + 90177536);
  int*   stb  = (int*)(p + 92274688);
  float* lgt  = (float*)(p + 94371840);
  u16*   bo   = (u16*)(p + 96468992);         // 67 MB  | early: qlo, later: ffn hidden
  // aliases (non-overlapping lifetimes)
  u16*   qlo   = bo;                 // dead before k_attn writes bo
  u16*   rothi = wqkh;               // dead after qk-gemm
  u16*   rotlo = wqkl;
  u16*   attnc = xl;
  float* hf    = (float*)(p + 39845888);   // overwrites qbuf/knb after attn done
  u16*   hb    = xh;
  u16*   hid   = bo;

  // 1) dtype converts / splits
  k_split<<<8192, 256, 0, stream>>>(x, xh, xl, 16384*512/4);
  k_split<<<256,  256, 0, stream>>>(w_qk, wqkh, wqkl, 512*512/4);
  k_cvt  <<<256,  256, 0, stream>>>(w_v,   wvb, 512*512/4);
  k_cvt  <<<256,  256, 0, stream>>>(w_out, wob, 512*512/4);
  k_cvt  <<<1024, 256, 0, stream>>>(w1, w1b, 2048*512/4);
  k_cvt  <<<1024, 256, 0, stream>>>(w2, w2b, 2048*512/4);

  // 2) qk = x @ w_qk^T (single-pass 3-term split) with fused prep epilogue
  k_gemmqk<<<dim3(4,128), 256, 0, stream>>>(xh, xl, wqkh, wqkl, qbuf, qlo, knb);
  // 3) v = x @ w_v^T, head layout bf16
  k_gemm<3><<<dim3(4,128), 256, 0, stream>>>(xh, wvb, nullptr, nullptr, vb, 16384, 512, 512);
  // 4) rot transpose+split (wqkh/wqkl now dead)
  k_rotT<<<32, 256, 0, stream>>>(rot, rothi, rotlo);
  // 5) LSH hash: S^T = rot x qk (3-term split), lane-local argmax -> buckets
  k_hash2<<<2048, 256, 0, stream>>>(qbuf, qlo, rothi, rotlo, bkt);
  // 6) stable counting sort per (bh, round)
  k_sort<<<128, 64, 0, stream>>>(bkt, stb);
  // 7) chunked attention
  k_attn<<<dim3(256,32), 256, 0, stream>>>(qbuf, knb, vb, stb, lgt, bo);
  // 8) combine rounds -> (b,t,512) bf16
  k_combine<<<32768, 256, 0, stream>>>(bo, lgt, attnc);
  // 9) out projection (+bias) -> d_out (scratch)
  k_gemm<0><<<dim3(4,128), 256, 0, stream>>>(attnc, wob, b_out, out, nullptr, 16384, 512, 512);
  // 10) h = LN(attn + x)
  k_ln<1><<<4096, 256, 0, stream>>>(out, x, ln1_g, ln1_b, hf, hb);
  // 11) hidden = relu(h @ w1^T + b1) bf16
  k_gemm<1><<<dim3(16,128), 256, 0, stream>>>(hb, w1b, b1, nullptr, hid, 16384, 2048, 512);
  // 12) f = hidden @ w2^T + b2 -> d_out
  k_gemm<0><<<dim3(4,128), 256, 0, stream>>>(hid, w2b, b2, out, nullptr, 16384, 512, 2048);
  // 13) out = LN(f + h)  (in place on d_out)
  k_ln<0><<<4096, 256, 0, stream>>>(out, hf, ln2_g, ln2_b, out, nullptr);
}

// Round 7
// 300.116 us; speedup vs baseline: 1.5888x; 1.0496x over previous
//
#include <hip/hip_runtime.h>
#include <stdint.h>

// Reformer layer: B=4 T=4096 D=512 H=8 DH=64 N_HASH=4 N_BUCKET=64 BUCKET=64 FFN=2048
typedef unsigned short u16;
typedef __attribute__((ext_vector_type(4))) int   i32x4;
typedef __attribute__((ext_vector_type(4))) float f32x4;

__device__ __forceinline__ u16 f2bf(float x){
  unsigned int u = __float_as_uint(x);
  u += 0x7FFFu + ((u >> 16) & 1u);
  return (u16)(u >> 16);
}
__device__ __forceinline__ float bf2f(u16 h){
  return __uint_as_float(((unsigned int)h) << 16);
}
__device__ __forceinline__ unsigned int cvtpk_bf16(float lo, float hi){
  unsigned int r;
  asm("v_cvt_pk_bf16_f32 %0, %1, %2" : "=v"(r) : "v"(lo), "v"(hi));
  return r;
}
__device__ __forceinline__ f32x4 mfma16(i32x4 a, i32x4 b, f32x4 c){
  asm("v_mfma_f32_16x16x32_bf16 %0, %1, %2, %0" : "+v"(c) : "v"(a), "v"(b));
  return c;
}
__device__ __forceinline__ f32x4 acc_fence(f32x4 c){
  asm volatile("s_nop 7\ns_nop 7" : "+v"(c));
  return c;
}
__device__ __forceinline__ void gl_lds16(const void* g, void* l){
  unsigned long long ga = (unsigned long long)g;
  unsigned int la = (unsigned int)(unsigned long long)l;
  __builtin_amdgcn_global_load_lds((const __attribute__((address_space(1))) void*)ga,
                                   (__attribute__((address_space(3))) void*)la, 16, 0, 0);
}
// XCD-chunked bijective swizzle (requires n % 8 == 0)
__device__ __forceinline__ int xcd_swz(int f, int n){
  int chunk = n >> 3;
  return (f & 7) * chunk + (f >> 3);
}
// monotonic-uint transform: order-preserving for fp32 compares
__device__ __forceinline__ unsigned int f2mono(float v){
  unsigned int u = __float_as_uint(v);
  return u ^ ((unsigned int)((int)u >> 31) | 0x80000000u);
}
__device__ __forceinline__ float mono2f(unsigned int mu){
  unsigned int u = (mu & 0x80000000u) ? (mu ^ 0x80000000u) : ~mu;
  return __uint_as_float(u);
}
__device__ __forceinline__ unsigned long long shfl_xor_u64(unsigned long long x, int m){
  int lo = __shfl_xor((int)(unsigned int)(x & 0xFFFFFFFFull), m);
  int hi = __shfl_xor((int)(unsigned int)(x >> 32), m);
  return ((unsigned long long)(unsigned int)hi << 32) | (unsigned int)lo;
}

// ---------------- x split (big) ----------------
__global__ __launch_bounds__(256) void k_split(const float* __restrict__ in, u16* __restrict__ hi, u16* __restrict__ lo, int n4){
  int i = blockIdx.x*256 + threadIdx.x;
  if (i >= n4) return;
  float4 v = ((const float4*)in)[i];
  ushort4 h, l;
  h.x=f2bf(v.x); l.x=f2bf(v.x - bf2f(h.x));
  h.y=f2bf(v.y); l.y=f2bf(v.y - bf2f(h.y));
  h.z=f2bf(v.z); l.z=f2bf(v.z - bf2f(h.z));
  h.w=f2bf(v.w); l.w=f2bf(v.w - bf2f(h.w));
  ((ushort4*)hi)[i]=h; ((ushort4*)lo)[i]=l;
}

// ---------------- fused weight prep: w_qk split, w_v/w_out/w1/w2 cvt, rot transpose+split ----------------
__global__ __launch_bounds__(256) void k_wprep(
    const float* __restrict__ w_qk, const float* __restrict__ w_v,
    const float* __restrict__ w_out, const float* __restrict__ w1,
    const float* __restrict__ w2, const float* __restrict__ rot,
    u16* __restrict__ wqkh, u16* __restrict__ wqkl,
    u16* __restrict__ wvb, u16* __restrict__ wob,
    u16* __restrict__ w1b, u16* __restrict__ w2b,
    u16* __restrict__ rothi, u16* __restrict__ rotlo)
{
  const int bid = blockIdx.x;
  if (bid >= 2816){
    int i = (bid - 2816)*256 + threadIdx.x;   // 8192 elems
    int d = i & 63, n = i >> 6;
    float v = rot[d*128 + n];
    u16 h = f2bf(v);
    rothi[i] = h; rotlo[i] = f2bf(v - bf2f(h));
    return;
  }
  const int i = bid*256 + threadIdx.x;
  if (i < 65536){
    float4 v = ((const float4*)w_qk)[i];
    ushort4 h, l;
    h.x=f2bf(v.x); l.x=f2bf(v.x - bf2f(h.x));
    h.y=f2bf(v.y); l.y=f2bf(v.y - bf2f(h.y));
    h.z=f2bf(v.z); l.z=f2bf(v.z - bf2f(h.z));
    h.w=f2bf(v.w); l.w=f2bf(v.w - bf2f(h.w));
    ((ushort4*)wqkh)[i]=h; ((ushort4*)wqkl)[i]=l;
    return;
  }
  const float* src; u16* dst; int j;
  if (i < 131072){ src = w_v;  dst = wvb; j = i - 65536; }
  else if (i < 196608){ src = w_out; dst = wob; j = i - 131072; }
  else if (i < 458752){ src = w1;   dst = w1b; j = i - 196608; }
  else { src = w2; dst = w2b; j = i - 458752; }
  float4 v = ((const float4*)src)[j];
  ushort4 o; o.x=f2bf(v.x); o.y=f2bf(v.y); o.z=f2bf(v.z); o.w=f2bf(v.w);
  ((ushort4*)dst)[j] = o;
}

// ---------------- generic bf16 MFMA GEMM: C = A * B^T ----------------
// MODE 0: fp32 rowmajor (+bias)   MODE 1: bf16 rowmajor, bias+relu   MODE 3: bf16 head-layout (v)
template<int MODE>
__global__ __launch_bounds__(256) void k_gemm(
    const u16* __restrict__ A0, const u16* __restrict__ B0,
    const float* __restrict__ bias,
    float* __restrict__ Cf, u16* __restrict__ Cb,
    int M, int N, int K)
{
  const int tid = threadIdx.x;
  const int l = tid & 63, w = tid >> 6;
  const int lr = l & 15, lg = l >> 4;
  int flat = blockIdx.y * gridDim.x + blockIdx.x;
  flat = xcd_swz(flat, gridDim.x * gridDim.y);
  const int m0 = (flat / gridDim.x) * 128, n0 = (flat % gridDim.x) * 128;
  const int mbase = (w >> 1) * 64, nbase = (w & 1) * 64;

  __shared__ __align__(16) u16 As[128*64];
  __shared__ __align__(16) u16 Bs[128*64];

  f32x4 zero = {0.f,0.f,0.f,0.f};
  f32x4 acc[4][4];
  #pragma unroll
  for (int i=0;i<4;i++)
    #pragma unroll
    for (int j=0;j<4;j++) acc[i][j] = zero;

  const int row_s = tid >> 3;
  const int c16   = tid & 7;

  for (int k0 = 0; k0 < K; k0 += 64){
    #pragma unroll
    for (int q=0;q<4;q++){
      int ra = q*32 + row_s;
      int cs = c16 ^ (ra & 7);
      gl_lds16(A0 + (size_t)(m0 + ra)*K + k0 + cs*8, (char*)As + q*4096 + tid*16);
      gl_lds16(B0 + (size_t)(n0 + ra)*K + k0 + cs*8, (char*)Bs + q*4096 + tid*16);
    }
    __syncthreads();
    #pragma unroll
    for (int kk=0; kk<64; kk+=32){
      i32x4 af[4], bfr[4];
      #pragma unroll
      for (int mf=0;mf<4;mf++){
        int row = mbase + mf*16 + lr;
        af[mf] = *(const i32x4*)((const char*)As + row*128 + (((kk*2) + (lg*16)) ^ ((row&7)<<4)));
      }
      #pragma unroll
      for (int nf=0;nf<4;nf++){
        int row = nbase + nf*16 + lr;
        bfr[nf] = *(const i32x4*)((const char*)Bs + row*128 + (((kk*2) + (lg*16)) ^ ((row&7)<<4)));
      }
      #pragma unroll
      for (int mf=0;mf<4;mf++)
        #pragma unroll
        for (int nf=0;nf<4;nf++)
          acc[mf][nf] = mfma16(af[mf], bfr[nf], acc[mf][nf]);
    }
    __syncthreads();
  }

  #pragma unroll
  for (int mf=0;mf<4;mf++){
    #pragma unroll
    for (int nf=0;nf<4;nf++){
      f32x4 v = acc_fence(acc[mf][nf]);
      #pragma unroll
      for (int r=0;r<4;r++){
        int m = m0 + mbase + mf*16 + lg*4 + r;
        int n = n0 + nbase + nf*16 + lr;
        float val = v[r];
        if (MODE == 0){
          if (bias) val += bias[n];
          Cf[(size_t)m*N + n] = val;
        } else if (MODE == 1){
          val += bias[n];
          val = fmaxf(val, 0.f);
          Cb[(size_t)m*N + n] = f2bf(val);
        } else {
          int b = m >> 12, t = m & 4095, h = n >> 6, d = n & 63;
          size_t idx = ((((size_t)(b*8 + h)) << 12) + t)*64 + d;
          Cb[idx] = f2bf(val);
        }
      }
    }
  }
}

// ---------------- qk GEMM: single-pass 3-term split-bf16 + fused prep epilogue ----------------
// out: qb (bf16 hi), qlo (bf16 lo), kn (normalized * 0.125*log2e, bf16), all head-layout
__global__ __launch_bounds__(256) void k_gemmqk(
    const u16* __restrict__ Ah, const u16* __restrict__ Al,
    const u16* __restrict__ Bh, const u16* __restrict__ Bl,
    u16* __restrict__ qb, u16* __restrict__ qlo, u16* __restrict__ kn)
{
  const int K = 512;
  const int tid = threadIdx.x;
  const int l = tid & 63, w = tid >> 6;
  const int lr = l & 15, lg = l >> 4;
  int flat = blockIdx.y * gridDim.x + blockIdx.x;
  flat = xcd_swz(flat, gridDim.x * gridDim.y);
  const int m0 = (flat >> 2) * 128, n0 = (flat & 3) * 128;
  const int mbase = (w >> 1) * 64, nbase = (w & 1) * 64;

  __shared__ __align__(16) u16 AsH[128*64];
  __shared__ __align__(16) u16 AsL[128*64];
  __shared__ __align__(16) u16 BsH[128*64];
  __shared__ __align__(16) u16 BsL[128*64];

  f32x4 zero = {0.f,0.f,0.f,0.f};
  f32x4 acc[4][4];
  #pragma unroll
  for (int i=0;i<4;i++)
    #pragma unroll
    for (int j=0;j<4;j++) acc[i][j] = zero;

  const int row_s = tid >> 3;
  const int c16   = tid & 7;

  for (int k0 = 0; k0 < K; k0 += 64){
    #pragma unroll
    for (int q=0;q<4;q++){
      int ra = q*32 + row_s;
      int cs = c16 ^ (ra & 7);
      size_t ao = (size_t)(m0 + ra)*K + k0 + cs*8;
      size_t bo = (size_t)(n0 + ra)*K + k0 + cs*8;
      gl_lds16(Ah + ao, (char*)AsH + q*4096 + tid*16);
      gl_lds16(Al + ao, (char*)AsL + q*4096 + tid*16);
      gl_lds16(Bh + bo, (char*)BsH + q*4096 + tid*16);
      gl_lds16(Bl + bo, (char*)BsL + q*4096 + tid*16);
    }
    __syncthreads();
    #pragma unroll
    for (int kk=0; kk<64; kk+=32){
      i32x4 ah[4], al[4], bh2[4], bl2[4];
      #pragma unroll
      for (int mf=0;mf<4;mf++){
        int row = mbase + mf*16 + lr;
        int off = (((kk*2) + (lg*16)) ^ ((row&7)<<4));
        ah[mf] = *(const i32x4*)((const char*)AsH + row*128 + off);
        al[mf] = *(const i32x4*)((const char*)AsL + row*128 + off);
      }
      #pragma unroll
      for (int nf=0;nf<4;nf++){
        int row = nbase + nf*16 + lr;
        int off = (((kk*2) + (lg*16)) ^ ((row&7)<<4));
        bh2[nf] = *(const i32x4*)((const char*)BsH + row*128 + off);
        bl2[nf] = *(const i32x4*)((const char*)BsL + row*128 + off);
      }
      #pragma unroll
      for (int mf=0;mf<4;mf++)
        #pragma unroll
        for (int nf=0;nf<4;nf++){
          acc[mf][nf] = mfma16(ah[mf], bh2[nf], acc[mf][nf]);
          acc[mf][nf] = mfma16(al[mf], bh2[nf], acc[mf][nf]);
          acc[mf][nf] = mfma16(ah[mf], bl2[nf], acc[mf][nf]);
        }
    }
    __syncthreads();
  }

  // fused prep epilogue: this wave's 64 columns are exactly one head
  const int hh = (n0 + nbase) >> 6;
  #pragma unroll
  for (int mf=0;mf<4;mf++){
    f32x4 v[4];
    #pragma unroll
    for (int nf=0;nf<4;nf++) v[nf] = acc_fence(acc[mf][nf]);
    #pragma unroll
    for (int r=0;r<4;r++){
      float ss = 0.f;
      #pragma unroll
      for (int nf=0;nf<4;nf++) ss += v[nf][r]*v[nf][r];
      ss += __shfl_xor(ss, 1); ss += __shfl_xor(ss, 2);
      ss += __shfl_xor(ss, 4); ss += __shfl_xor(ss, 8);
      // fold dim_head^-0.5 AND log2(e) into kn so attn uses raw v_exp (2^x)
      float scale = 0.18033688f / fmaxf(sqrtf(ss), 1e-6f);
      int m = m0 + mbase + mf*16 + lg*4 + r;
      int b = m >> 12, t = m & 4095;
      size_t rowb = ((((size_t)(b*8 + hh)) << 12) + t) * 64;
      #pragma unroll
      for (int nf=0;nf<4;nf++){
        float val = v[nf][r];
        u16 hbf = f2bf(val);
        size_t idx = rowb + nf*16 + lr;
        qb [idx] = hbf;
        qlo[idx] = f2bf(val - bf2f(hbf));
        kn [idx] = f2bf(val * scale);
      }
    }
  }
}

// ---------------- LSH hash: swapped-operand MFMA, lane-local argmax ----------------
__global__ __launch_bounds__(256) void k_hash2(
    const u16* __restrict__ qh, const u16* __restrict__ ql,
    const u16* __restrict__ rh, const u16* __restrict__ rl,
    int* __restrict__ bkt)
{
  const int tid = threadIdx.x;
  const int l = tid & 63, w = tid >> 6, lr = l & 15, lg = l >> 4;
  __shared__ __align__(16) u16 Rh[128*64];
  __shared__ __align__(16) u16 Rl[128*64];
  {
    const int row_s = tid >> 3, c8 = tid & 7;
    #pragma unroll
    for (int q = 0; q < 4; q++){
      int ra = q*32 + row_s;
      int cs = c8 ^ (ra & 7);
      gl_lds16(rh + ra*64 + cs*8, (char*)Rh + q*4096 + tid*16);
      gl_lds16(rl + ra*64 + cs*8, (char*)Rl + q*4096 + tid*16);
    }
  }
  const int blk = xcd_swz(blockIdx.x, gridDim.x);
  const int qrow = blk*64 + w*16 + lr;
  const size_t qoff = (size_t)qrow*64;
  i32x4 qhf[2], qlf[2];
  qhf[0] = *(const i32x4*)(qh + qoff + lg*8);
  qhf[1] = *(const i32x4*)(qh + qoff + 32 + lg*8);
  qlf[0] = *(const i32x4*)(ql + qoff + lg*8);
  qlf[1] = *(const i32x4*)(ql + qoff + 32 + lg*8);
  __syncthreads();

  f32x4 zero = {0.f,0.f,0.f,0.f};
  f32x4 acc[8];
  #pragma unroll
  for (int i=0;i<8;i++) acc[i] = zero;
  #pragma unroll
  for (int ks = 0; ks < 2; ks++){
    #pragma unroll
    for (int nf = 0; nf < 8; nf++){
      int row = nf*16 + lr;
      int off = (ks*64 + lg*16) ^ ((row & 7) << 4);
      i32x4 rhf = *(const i32x4*)((const char*)Rh + row*128 + off);
      i32x4 rlf = *(const i32x4*)((const char*)Rl + row*128 + off);
      acc[nf] = mfma16(rhf, qhf[ks], acc[nf]);
      acc[nf] = mfma16(rlf, qhf[ks], acc[nf]);
      acc[nf] = mfma16(rhf, qlf[ks], acc[nf]);
    }
  }

  const int bh = qrow >> 12, t = qrow & 4095;
  #pragma unroll
  for (int hh = 0; hh < 4; hh++){
    f32x4 v0 = acc_fence(acc[2*hh]);
    f32x4 v1 = acc_fence(acc[2*hh+1]);
    unsigned long long kmax = 0, kmin = 0;
    #pragma unroll
    for (int r = 0; r < 4; r++){
      int j0 = lg*4 + r, j1 = 16 + lg*4 + r;
      unsigned int mu0 = f2mono(v0[r]), mu1 = f2mono(v1[r]);
      unsigned long long a = ((unsigned long long)mu0 << 32) | (unsigned int)(31 - j0);
      unsigned long long b = ((unsigned long long)mu1 << 32) | (unsigned int)(31 - j1);
      if (a > kmax) kmax = a;
      if (b > kmax) kmax = b;
      unsigned long long c = ((unsigned long long)(~mu0) << 32) | (unsigned int)(31 - j0);
      unsigned long long d = ((unsigned long long)(~mu1) << 32) | (unsigned int)(31 - j1);
      if (c > kmin) kmin = c;
      if (d > kmin) kmin = d;
    }
    #pragma unroll
    for (int msk = 16; msk < 64; msk <<= 1){
      unsigned long long o1 = shfl_xor_u64(kmax, msk); if (o1 > kmax) kmax = o1;
      unsigned long long o2 = shfl_xor_u64(kmin, msk); if (o2 > kmin) kmin = o2;
    }
    if (lg == 0){
      float vmax = mono2f((unsigned int)(kmax >> 32));
      int jmax = 31 - (int)(kmax & 0xFFFFFFFFull);
      float vmin = mono2f(~(unsigned int)(kmin >> 32));
      int jmin = 31 - (int)(kmin & 0xFFFFFFFFull);
      int bucket = (vmax >= -vmin) ? jmax : 32 + jmin;
      bkt[((size_t)(bh*4 + hh) << 12) + t] = bucket;
    }
  }
}

// ---------------- stable counting sort per (bh, round) ----------------
__global__ __launch_bounds__(64) void k_sort(const int* __restrict__ buckets, int* __restrict__ st){
  const int grp = blockIdx.x;
  const int t = threadIdx.x;
  __shared__ int bkL[4096];
  __shared__ int hist[64][65];
  __shared__ int tot[64];
  const size_t gbase = ((size_t)grp) << 12;
  for (int i=0;i<64;i++)
    bkL[i*64 + t] = buckets[gbase + i*64 + t];   // coalesced
  #pragma unroll
  for (int b=0;b<64;b++) hist[t][b] = 0;
  __syncthreads();
  for (int i=0;i<64;i++){
    int b = bkL[t*64 + i];
    hist[t][b]++;
  }
  __syncthreads();
  { int run = 0;
    for (int tt=0; tt<64; tt++){ int v = hist[tt][t]; hist[tt][t] = run; run += v; }
    tot[t] = run; }
  __syncthreads();
  { int v = tot[t]; int incl = v;
    #pragma unroll
    for (int d=1; d<64; d<<=1){ int n = __shfl_up(incl, d, 64); if (t >= d) incl += n; }
    tot[t] = incl - v; }
  __syncthreads();
  const size_t obase = (((size_t)(grp>>2)) << 14) + ((size_t)(grp&3) << 12);
  for (int i=0;i<64;i++){
    int e = t*64 + i;
    int b = bkL[e];
    int dest = tot[b] + hist[t][b];
    hist[t][b]++;
    st[obase + dest] = e;
  }
}

// ---------------- chunked LSH attention: swapped QK^T, max-free in-reg softmax ----------------
__global__ __launch_bounds__(256, 4) void k_attn(
    const u16* __restrict__ qb, const u16* __restrict__ kn, const u16* __restrict__ vB,
    const int* __restrict__ st, float* __restrict__ lgt_out, u16* __restrict__ bo)
{
  int flat = blockIdx.y * gridDim.x + blockIdx.x;
  flat = xcd_swz(flat, gridDim.x * gridDim.y);
  const int c = flat & 255, bh = flat >> 8;
  const int rnd = c >> 6;
  const int tid = threadIdx.x;
  const int l = tid & 63, w = tid >> 6, lr = l & 15, lg = l >> 4;

  __shared__ __align__(16) u16 Ks[128*64];
  __shared__ __align__(16) u16 Vt[64][136];
  __shared__ int posk[128];

  if (tid < 128){
    int cc = (tid < 64) ? c : ((c + 255) & 255);
    posk[tid] = st[(((size_t)bh) << 14) + (cc << 6) + (tid & 63)];
  }
  __syncthreads();

  const size_t kvbase = ((size_t)bh) << 12;

  {
    const int rsub = l >> 3, c8 = l & 7;
    #pragma unroll
    for (int q2 = 0; q2 < 4; q2++){
      int row = w*32 + q2*8 + rsub;
      int cs = c8 ^ (row & 7);
      gl_lds16(kn + (kvbase + posk[row])*64 + cs*8,
               (char*)Ks + (w*4 + q2)*1024 + l*16);
    }
  }

  const int pos_q16 = posk[w*16 + lr];
  i32x4 qf[2];
  #pragma unroll
  for (int ks = 0; ks < 2; ks++)
    qf[ks] = *(const i32x4*)(qb + (kvbase + pos_q16)*64 + ks*32 + lg*8);

  {
    const int pp = tid & 63, db = tid >> 6;
    const int q5 = pp & 15;
    const int K0 = (pp >> 4)*32 + 16*((q5 >> 1) & 1) + 4*(q5 >> 2) + 2*(q5 & 1);
    const u16* r0 = vB + (kvbase + posk[K0])*64 + db*16;
    const u16* r1 = vB + (kvbase + posk[K0+1])*64 + db*16;
    uint4 a0 = *(const uint4*)r0, a1 = *(const uint4*)(r0 + 8);
    uint4 b0 = *(const uint4*)r1, b1 = *(const uint4*)(r1 + 8);
    uint av[8] = {a0.x,a0.y,a0.z,a0.w,a1.x,a1.y,a1.z,a1.w};
    uint bv[8] = {b0.x,b0.y,b0.z,b0.w,b1.x,b1.y,b1.z,b1.w};
    #pragma unroll
    for (int dd = 0; dd < 16; dd++){
      uint lo = (av[dd>>1] >> ((dd&1)*16)) & 0xFFFFu;
      uint hi = (bv[dd>>1] >> ((dd&1)*16)) & 0xFFFFu;
      *(uint*)((char*)&Vt[db*16 + dd][0] + pp*4) = lo | (hi << 16);
    }
  }
  __syncthreads();

  f32x4 zero = {0.f,0.f,0.f,0.f};
  f32x4 s[8];
  #pragma unroll
  for (int i=0;i<8;i++) s[i] = zero;
  __builtin_amdgcn_s_setprio(1);
  #pragma unroll
  for (int ks = 0; ks < 2; ks++){
    #pragma unroll
    for (int nf = 0; nf < 8; nf++){
      int row = nf*16 + lr;
      i32x4 kf = *(const i32x4*)((const char*)Ks + row*128 + ((ks*64 + lg*16) ^ ((row&7)<<4)));
      s[nf] = mfma16(kf, qf[ks], s[nf]);
    }
  }
  __builtin_amdgcn_s_setprio(0);

  // max-free softmax: S already scaled by 0.125*log2e -> p = 2^S via v_exp, cannot overflow
  const bool bdry = (c & 63) == 0;   // look-back window crosses a round boundary
  float p[8][4];
  float sum = 0.f;
  #pragma unroll
  for (int nf=0;nf<8;nf++){
    f32x4 t = acc_fence(s[nf]);
    #pragma unroll
    for (int r=0;r<4;r++){
      float e = __builtin_amdgcn_exp2f(t[r]);
      if (nf == w && (lg*4 + r) == lr) e = 0.f;                         // self (same slot)
      if (nf >= 4 && bdry && posk[nf*16 + lg*4 + r] == pos_q16) e = 0.f; // cross-round same token
      p[nf][r] = e;
      sum += e;
    }
  }
  sum += __shfl_xor(sum, 16);
  sum += __shfl_xor(sum, 32);
  float lv = logf(sum);
  float inv = 1.f / sum;
  if (l < 16)
    lgt_out[(((size_t)(bh*4 + rnd)) << 12) + pos_q16] = lv;

  // unnormalized P -> bf16 via cvt_pk; scale output by per-q inv afterwards
  i32x4 pa[4];
  #pragma unroll
  for (int ks=0;ks<4;ks++){
    uint w0 = cvtpk_bf16(p[2*ks][0],   p[2*ks][1]);
    uint w1 = cvtpk_bf16(p[2*ks][2],   p[2*ks][3]);
    uint w2 = cvtpk_bf16(p[2*ks+1][0], p[2*ks+1][1]);
    uint w3 = cvtpk_bf16(p[2*ks+1][2], p[2*ks+1][3]);
    i32x4 t = {(int)w0,(int)w1,(int)w2,(int)w3};
    pa[ks] = t;
  }

  f32x4 o[4];
  #pragma unroll
  for (int i=0;i<4;i++) o[i] = zero;
  __builtin_amdgcn_s_setprio(1);
  #pragma unroll
  for (int ks=0;ks<4;ks++){
    #pragma unroll
    for (int nf=0;nf<4;nf++){
      i32x4 vf = *(const i32x4*)((const char*)&Vt[nf*16 + lr][0] + ks*64 + lg*16);
      o[nf] = mfma16(pa[ks], vf, o[nf]);
    }
  }
  __builtin_amdgcn_s_setprio(0);
  float invq[4];
  #pragma unroll
  for (int r=0;r<4;r++) invq[r] = __shfl(inv, lg*4 + r, 64);
  #pragma unroll
  for (int nf=0;nf<4;nf++){
    f32x4 ov = acc_fence(o[nf]);
    #pragma unroll
    for (int r=0;r<4;r++){
      int q = w*16 + lg*4 + r;
      bo[((((size_t)(bh*4 + rnd)) << 12) + posk[q])*64 + nf*16 + lr] = f2bf(ov[r] * invq[r]);
    }
  }
}

// ---------------- combine hash rounds ----------------
__global__ __launch_bounds__(256) void k_combine(const u16* __restrict__ bo, const float* __restrict__ lgt,
                                                 u16* __restrict__ attn){
  const int wid = blockIdx.x * 4 + (threadIdx.x >> 6);
  const int l = threadIdx.x & 63;
  const int bh = wid >> 12, t = wid & 4095;
  const size_t lbase = (((size_t)bh) << 14) + t;
  float l0 = lgt[lbase], l1 = lgt[lbase + 4096], l2 = lgt[lbase + 8192], l3 = lgt[lbase + 12288];
  float m = fmaxf(fmaxf(l0,l1), fmaxf(l2,l3));
  float w0 = __expf(l0-m), w1 = __expf(l1-m), w2 = __expf(l2-m), w3 = __expf(l3-m);
  float inv = 1.f / (w0+w1+w2+w3);
  const size_t bbase = ((((size_t)bh) << 14) + t) * 64 + l;
  float o = w0 * bf2f(bo[bbase])
          + w1 * bf2f(bo[bbase + (size_t)4096*64])
          + w2 * bf2f(bo[bbase + (size_t)8192*64])
          + w3 * bf2f(bo[bbase + (size_t)12288*64]);
  o *= inv;
  int b = bh >> 3, h = bh & 7;
  attn[((((size_t)b) << 12) + t) * 512 + h*64 + l] = f2bf(o);
}

// ---------------- residual + LayerNorm ----------------
// WB16=1: res fp32 (x), write bf16 h only. WB16=0: res bf16 (hb), write fp32 out only.
template<int WB16>
__global__ __launch_bounds__(256) void k_ln(const float* __restrict__ a,
                                            const float* __restrict__ resf, const u16* __restrict__ resb,
                                            const float* __restrict__ g, const float* __restrict__ bb,
                                            float* __restrict__ of, u16* __restrict__ ob){
  const int row = blockIdx.x*4 + (threadIdx.x >> 6);
  const int l = threadIdx.x & 63;
  const size_t base = (size_t)row*512 + l*8;
  float4 a0 = *(const float4*)(a + base);
  float4 a1 = *(const float4*)(a + base + 4);
  float rv[8];
  if (WB16){
    float4 r0 = *(const float4*)(resf + base);
    float4 r1 = *(const float4*)(resf + base + 4);
    rv[0]=r0.x; rv[1]=r0.y; rv[2]=r0.z; rv[3]=r0.w;
    rv[4]=r1.x; rv[5]=r1.y; rv[6]=r1.z; rv[7]=r1.w;
  } else {
    uint4 rr = *(const uint4*)(resb + base);
    uint rw[4] = {rr.x, rr.y, rr.z, rr.w};
    #pragma unroll
    for (int j=0;j<4;j++){
      rv[2*j]   = bf2f((u16)(rw[j] & 0xFFFF));
      rv[2*j+1] = bf2f((u16)(rw[j] >> 16));
    }
  }
  float v[8] = {a0.x+rv[0], a0.y+rv[1], a0.z+rv[2], a0.w+rv[3],
                a1.x+rv[4], a1.y+rv[5], a1.z+rv[6], a1.w+rv[7]};
  float sum = 0.f;
  #pragma unroll
  for (int j=0;j<8;j++) sum += v[j];
  #pragma unroll
  for (int msk=1; msk<64; msk<<=1) sum += __shfl_xor(sum, msk);
  float mean = sum * (1.f/512.f);
  float ss = 0.f;
  #pragma unroll
  for (int j=0;j<8;j++){ float d = v[j]-mean; ss += d*d; }
  #pragma unroll
  for (int msk=1; msk<64; msk<<=1) ss += __shfl_xor(ss, msk);
  float rstd = rsqrtf(ss * (1.f/512.f) + 1e-6f);
  float4 g0 = *(const float4*)(g + l*8),  g1 = *(const float4*)(g + l*8 + 4);
  float4 b0 = *(const float4*)(bb + l*8), b1 = *(const float4*)(bb + l*8 + 4);
  float gv[8] = {g0.x,g0.y,g0.z,g0.w,g1.x,g1.y,g1.z,g1.w};
  float bv[8] = {b0.x,b0.y,b0.z,b0.w,b1.x,b1.y,b1.z,b1.w};
  float y[8];
  #pragma unroll
  for (int j=0;j<8;j++) y[j] = (v[j]-mean)*rstd*gv[j] + bv[j];
  if (WB16){
    #pragma unroll
    for (int j=0;j<8;j++) ob[base+j] = f2bf(y[j]);
  } else {
    #pragma unroll
    for (int j=0;j<8;j++) of[base+j] = y[j];
  }
}

extern "C" void kernel_launch(void* const* d_in, const int* in_sizes, int n_in,
                              void* d_out, int out_size, void* d_ws, size_t ws_size,
                              hipStream_t stream) {
  const float* x     = (const float*)d_in[0];
  const float* rot   = (const float*)d_in[1];
  const float* w_qk  = (const float*)d_in[2];
  const float* w_v   = (const float*)d_in[3];
  const float* w_out = (const float*)d_in[4];
  const float* b_out = (const float*)d_in[5];
  const float* ln1_g = (const float*)d_in[6];
  const float* ln1_b = (const float*)d_in[7];
  const float* w1    = (const float*)d_in[8];
  const float* b1    = (const float*)d_in[9];
  const float* w2    = (const float*)d_in[10];
  const float* b2    = (const float*)d_in[11];
  const float* ln2_g = (const float*)d_in[12];
  const float* ln2_b = (const float*)d_in[13];
  float* out = (float*)d_out;

  char* p = (char*)d_ws;
  u16*   xh   = (u16*)(p);                    // x-hi   | later: hb (bf16 h)
  u16*   xl   = (u16*)(p + 16777216);         // x-lo   | later: attnc
  u16*   wqkh = (u16*)(p + 33554432);
  u16*   wqkl = (u16*)(p + 34078720);
  u16*   wvb  = (u16*)(p + 34603008);
  u16*   wob  = (u16*)(p + 35127296);
  u16*   w1b  = (u16*)(p + 35651584);
  u16*   w2b  = (u16*)(p + 37748736);
  u16*   qbuf = (u16*)(p + 39845888);         // qk bf16 hi (head layout)
  u16*   knb  = (u16*)(p + 56623104);         // kn bf16 (head layout, pre-scaled 0.125*log2e)
  u16*   vb   = (u16*)(p + 73400320);
  int*   bkt  = (int*)(p + 90177536);
  int*   stb  = (int*)(p + 92274688);
  float* lgt  = (float*)(p + 94371840);
  u16*   bo   = (u16*)(p + 96468992);         // 67 MB | early: qlo + rot buffers, later: ffn hidden
  // aliases (non-overlapping lifetimes)
  u16*   qlo   = bo;                          // bo[0..16MB): dead before k_attn writes bo
  u16*   rothi = (u16*)(p + 96468992 + 16777216);          // bo+16MB, 16KB
  u16*   rotlo = (u16*)(p + 96468992 + 16777216 + 16384);  // consumed by hash before attn
  u16*   attnc = xl;
  u16*   hb    = xh;
  u16*   hid   = bo;

  // 1) x split (hi/lo bf16)
  k_split<<<8192, 256, 0, stream>>>(x, xh, xl, 16384*512/4);
  // 2) all weight converts + rot transpose/split in one dispatch
  k_wprep<<<2848, 256, 0, stream>>>(w_qk, w_v, w_out, w1, w2, rot,
                                    wqkh, wqkl, wvb, wob, w1b, w2b, rothi, rotlo);
  // 3) qk = x @ w_qk^T (single-pass 3-term split) with fused prep epilogue
  k_gemmqk<<<dim3(4,128), 256, 0, stream>>>(xh, xl, wqkh, wqkl, qbuf, qlo, knb);
  // 4) v = x @ w_v^T, head layout bf16
  k_gemm<3><<<dim3(4,128), 256, 0, stream>>>(xh, wvb, nullptr, nullptr, vb, 16384, 512, 512);
  // 5) LSH hash: S^T = rot x qk (3-term split), lane-local argmax -> buckets
  k_hash2<<<2048, 256, 0, stream>>>(qbuf, qlo, rothi, rotlo, bkt);
  // 6) stable counting sort per (bh, round)
  k_sort<<<128, 64, 0, stream>>>(bkt, stb);
  // 7) chunked attention
  k_attn<<<dim3(256,32), 256, 0, stream>>>(qbuf, knb, vb, stb, lgt, bo);
  // 8) combine rounds -> (b,t,512) bf16
  k_combine<<<32768, 256, 0, stream>>>(bo, lgt, attnc);
  // 9) out projection (+bias) -> d_out (scratch)
  k_gemm<0><<<dim3(4,128), 256, 0, stream>>>(attnc, wob, b_out, out, nullptr, 16384, 512, 512);
  // 10) h = LN(attn + x) -> bf16 only
  k_ln<1><<<4096, 256, 0, stream>>>(out, x, nullptr, ln1_g, ln1_b, nullptr, hb);
  // 11) hidden = relu(h @ w1^T + b1) bf16
  k_gemm<1><<<dim3(16,128), 256, 0, stream>>>(hb, w1b, b1, nullptr, hid, 16384, 2048, 512);
  // 12) f = hidden @ w2^T + b2 -> d_out
  k_gemm<0><<<dim3(4,128), 256, 0, stream>>>(hid, w2b, b2, out, nullptr, 16384, 512, 2048);
  // 13) out = LN(f + h), h residual from bf16
  k_ln<0><<<4096, 256, 0, stream>>>(out, nullptr, hb, ln2_g, ln2_b, out, nullptr);
}

// Round 8
// 286.050 us; speedup vs baseline: 1.6669x; 1.0492x over previous
//
#include <hip/hip_runtime.h>
#include <stdint.h>

// Reformer layer: B=4 T=4096 D=512 H=8 DH=64 N_HASH=4 N_BUCKET=64 BUCKET=64 FFN=2048
typedef unsigned short u16;
typedef __attribute__((ext_vector_type(4))) int   i32x4;
typedef __attribute__((ext_vector_type(4))) float f32x4;

__device__ __forceinline__ u16 f2bf(float x){
  unsigned int u = __float_as_uint(x);
  u += 0x7FFFu + ((u >> 16) & 1u);
  return (u16)(u >> 16);
}
__device__ __forceinline__ float bf2f(u16 h){
  return __uint_as_float(((unsigned int)h) << 16);
}
__device__ __forceinline__ unsigned int cvtpk_bf16(float lo, float hi){
  unsigned int r;
  asm("v_cvt_pk_bf16_f32 %0, %1, %2" : "=v"(r) : "v"(lo), "v"(hi));
  return r;
}
__device__ __forceinline__ f32x4 mfma16(i32x4 a, i32x4 b, f32x4 c){
  asm("v_mfma_f32_16x16x32_bf16 %0, %1, %2, %0" : "+v"(c) : "v"(a), "v"(b));
  return c;
}
__device__ __forceinline__ f32x4 acc_fence(f32x4 c){
  asm volatile("s_nop 7\ns_nop 7" : "+v"(c));
  return c;
}
__device__ __forceinline__ void gl_lds16(const void* g, void* l){
  unsigned long long ga = (unsigned long long)g;
  unsigned int la = (unsigned int)(unsigned long long)l;
  __builtin_amdgcn_global_load_lds((const __attribute__((address_space(1))) void*)ga,
                                   (__attribute__((address_space(3))) void*)la, 16, 0, 0);
}
// XCD-chunked bijective swizzle (requires n % 8 == 0)
__device__ __forceinline__ int xcd_swz(int f, int n){
  int chunk = n >> 3;
  return (f & 7) * chunk + (f >> 3);
}
// monotonic-uint transform: order-preserving for fp32 compares
__device__ __forceinline__ unsigned int f2mono(float v){
  unsigned int u = __float_as_uint(v);
  return u ^ ((unsigned int)((int)u >> 31) | 0x80000000u);
}
__device__ __forceinline__ float mono2f(unsigned int mu){
  unsigned int u = (mu & 0x80000000u) ? (mu ^ 0x80000000u) : ~mu;
  return __uint_as_float(u);
}
__device__ __forceinline__ unsigned long long shfl_xor_u64(unsigned long long x, int m){
  int lo = __shfl_xor((int)(unsigned int)(x & 0xFFFFFFFFull), m);
  int hi = __shfl_xor((int)(unsigned int)(x >> 32), m);
  return ((unsigned long long)(unsigned int)hi << 32) | (unsigned int)lo;
}

// ---------------- x split (big) ----------------
__global__ __launch_bounds__(256) void k_split(const float* __restrict__ in, u16* __restrict__ hi, u16* __restrict__ lo, int n4){
  int i = blockIdx.x*256 + threadIdx.x;
  if (i >= n4) return;
  float4 v = ((const float4*)in)[i];
  ushort4 h, l;
  h.x=f2bf(v.x); l.x=f2bf(v.x - bf2f(h.x));
  h.y=f2bf(v.y); l.y=f2bf(v.y - bf2f(h.y));
  h.z=f2bf(v.z); l.z=f2bf(v.z - bf2f(h.z));
  h.w=f2bf(v.w); l.w=f2bf(v.w - bf2f(h.w));
  ((ushort4*)hi)[i]=h; ((ushort4*)lo)[i]=l;
}

// ---------------- fused weight prep ----------------
__global__ __launch_bounds__(256) void k_wprep(
    const float* __restrict__ w_qk, const float* __restrict__ w_v,
    const float* __restrict__ w_out, const float* __restrict__ w1,
    const float* __restrict__ w2, const float* __restrict__ rot,
    u16* __restrict__ wqkh, u16* __restrict__ wqkl,
    u16* __restrict__ wvb, u16* __restrict__ wob,
    u16* __restrict__ w1b, u16* __restrict__ w2b,
    u16* __restrict__ rothi, u16* __restrict__ rotlo)
{
  const int bid = blockIdx.x;
  if (bid >= 2816){
    int i = (bid - 2816)*256 + threadIdx.x;   // 8192 elems
    int d = i & 63, n = i >> 6;
    float v = rot[d*128 + n];
    u16 h = f2bf(v);
    rothi[i] = h; rotlo[i] = f2bf(v - bf2f(h));
    return;
  }
  const int i = bid*256 + threadIdx.x;
  if (i < 65536){
    float4 v = ((const float4*)w_qk)[i];
    ushort4 h, l;
    h.x=f2bf(v.x); l.x=f2bf(v.x - bf2f(h.x));
    h.y=f2bf(v.y); l.y=f2bf(v.y - bf2f(h.y));
    h.z=f2bf(v.z); l.z=f2bf(v.z - bf2f(h.z));
    h.w=f2bf(v.w); l.w=f2bf(v.w - bf2f(h.w));
    ((ushort4*)wqkh)[i]=h; ((ushort4*)wqkl)[i]=l;
    return;
  }
  const float* src; u16* dst; int j;
  if (i < 131072){ src = w_v;  dst = wvb; j = i - 65536; }
  else if (i < 196608){ src = w_out; dst = wob; j = i - 131072; }
  else if (i < 458752){ src = w1;   dst = w1b; j = i - 196608; }
  else { src = w2; dst = w2b; j = i - 458752; }
  float4 v = ((const float4*)src)[j];
  ushort4 o; o.x=f2bf(v.x); o.y=f2bf(v.y); o.z=f2bf(v.z); o.w=f2bf(v.w);
  ((ushort4*)dst)[j] = o;
}

// ---------------- generic bf16 MFMA GEMM: C = A * B^T ----------------
// MODE 1: bf16 rowmajor, bias+relu   MODE 3: bf16 head-layout (v)   MODE 4: bf16 rowmajor + bias
template<int MODE>
__global__ __launch_bounds__(256) void k_gemm(
    const u16* __restrict__ A0, const u16* __restrict__ B0,
    const float* __restrict__ bias,
    float* __restrict__ Cf, u16* __restrict__ Cb,
    int M, int N, int K)
{
  const int tid = threadIdx.x;
  const int l = tid & 63, w = tid >> 6;
  const int lr = l & 15, lg = l >> 4;
  int flat = blockIdx.y * gridDim.x + blockIdx.x;
  flat = xcd_swz(flat, gridDim.x * gridDim.y);
  const int m0 = (flat / gridDim.x) * 128, n0 = (flat % gridDim.x) * 128;
  const int mbase = (w >> 1) * 64, nbase = (w & 1) * 64;

  __shared__ __align__(16) u16 As[128*64];
  __shared__ __align__(16) u16 Bs[128*64];

  f32x4 zero = {0.f,0.f,0.f,0.f};
  f32x4 acc[4][4];
  #pragma unroll
  for (int i=0;i<4;i++)
    #pragma unroll
    for (int j=0;j<4;j++) acc[i][j] = zero;

  const int row_s = tid >> 3;
  const int c16   = tid & 7;

  for (int k0 = 0; k0 < K; k0 += 64){
    #pragma unroll
    for (int q=0;q<4;q++){
      int ra = q*32 + row_s;
      int cs = c16 ^ (ra & 7);
      gl_lds16(A0 + (size_t)(m0 + ra)*K + k0 + cs*8, (char*)As + q*4096 + tid*16);
      gl_lds16(B0 + (size_t)(n0 + ra)*K + k0 + cs*8, (char*)Bs + q*4096 + tid*16);
    }
    __syncthreads();
    #pragma unroll
    for (int kk=0; kk<64; kk+=32){
      i32x4 af[4], bfr[4];
      #pragma unroll
      for (int mf=0;mf<4;mf++){
        int row = mbase + mf*16 + lr;
        af[mf] = *(const i32x4*)((const char*)As + row*128 + (((kk*2) + (lg*16)) ^ ((row&7)<<4)));
      }
      #pragma unroll
      for (int nf=0;nf<4;nf++){
        int row = nbase + nf*16 + lr;
        bfr[nf] = *(const i32x4*)((const char*)Bs + row*128 + (((kk*2) + (lg*16)) ^ ((row&7)<<4)));
      }
      #pragma unroll
      for (int mf=0;mf<4;mf++)
        #pragma unroll
        for (int nf=0;nf<4;nf++)
          acc[mf][nf] = mfma16(af[mf], bfr[nf], acc[mf][nf]);
    }
    __syncthreads();
  }

  #pragma unroll
  for (int mf=0;mf<4;mf++){
    #pragma unroll
    for (int nf=0;nf<4;nf++){
      f32x4 v = acc_fence(acc[mf][nf]);
      #pragma unroll
      for (int r=0;r<4;r++){
        int m = m0 + mbase + mf*16 + lg*4 + r;
        int n = n0 + nbase + nf*16 + lr;
        float val = v[r];
        if (MODE == 1){
          val += bias[n];
          val = fmaxf(val, 0.f);
          Cb[(size_t)m*N + n] = f2bf(val);
        } else if (MODE == 4){
          val += bias[n];
          Cb[(size_t)m*N + n] = f2bf(val);
        } else {
          int b = m >> 12, t = m & 4095, h = n >> 6, d = n & 63;
          size_t idx = ((((size_t)(b*8 + h)) << 12) + t)*64 + d;
          Cb[idx] = f2bf(val);
        }
      }
    }
  }
}

// ---------------- qk GEMM: 3-term split-bf16 + fused prep + fused LSH hash ----------------
__global__ __launch_bounds__(256) void k_gemmqk(
    const u16* __restrict__ Ah, const u16* __restrict__ Al,
    const u16* __restrict__ Bh, const u16* __restrict__ Bl,
    const u16* __restrict__ rotH, const u16* __restrict__ rotL,
    u16* __restrict__ qb, u16* __restrict__ qlo, u16* __restrict__ kn,
    int* __restrict__ Bkt)
{
  const int K = 512;
  const int tid = threadIdx.x;
  const int l = tid & 63, w = tid >> 6;
  const int lr = l & 15, lg = l >> 4;
  int flat = blockIdx.y * gridDim.x + blockIdx.x;
  flat = xcd_swz(flat, gridDim.x * gridDim.y);
  const int m0 = (flat >> 2) * 128, n0 = (flat & 3) * 128;
  const int mbase = (w >> 1) * 64, nbase = (w & 1) * 64;

  __shared__ __align__(16) u16 AsH[128*64];
  __shared__ __align__(16) u16 AsL[128*64];
  __shared__ __align__(16) u16 BsH[128*64];
  __shared__ __align__(16) u16 BsL[128*64];

  f32x4 zero = {0.f,0.f,0.f,0.f};
  f32x4 acc[4][4];
  #pragma unroll
  for (int i=0;i<4;i++)
    #pragma unroll
    for (int j=0;j<4;j++) acc[i][j] = zero;

  const int row_s = tid >> 3;
  const int c16   = tid & 7;

  for (int k0 = 0; k0 < K; k0 += 64){
    #pragma unroll
    for (int q=0;q<4;q++){
      int ra = q*32 + row_s;
      int cs = c16 ^ (ra & 7);
      size_t ao = (size_t)(m0 + ra)*K + k0 + cs*8;
      size_t bo = (size_t)(n0 + ra)*K + k0 + cs*8;
      gl_lds16(Ah + ao, (char*)AsH + q*4096 + tid*16);
      gl_lds16(Al + ao, (char*)AsL + q*4096 + tid*16);
      gl_lds16(Bh + bo, (char*)BsH + q*4096 + tid*16);
      gl_lds16(Bl + bo, (char*)BsL + q*4096 + tid*16);
    }
    __syncthreads();
    #pragma unroll
    for (int kk=0; kk<64; kk+=32){
      i32x4 ah[4], al[4], bh2[4], bl2[4];
      #pragma unroll
      for (int mf=0;mf<4;mf++){
        int row = mbase + mf*16 + lr;
        int off = (((kk*2) + (lg*16)) ^ ((row&7)<<4));
        ah[mf] = *(const i32x4*)((const char*)AsH + row*128 + off);
        al[mf] = *(const i32x4*)((const char*)AsL + row*128 + off);
      }
      #pragma unroll
      for (int nf=0;nf<4;nf++){
        int row = nbase + nf*16 + lr;
        int off = (((kk*2) + (lg*16)) ^ ((row&7)<<4));
        bh2[nf] = *(const i32x4*)((const char*)BsH + row*128 + off);
        bl2[nf] = *(const i32x4*)((const char*)BsL + row*128 + off);
      }
      #pragma unroll
      for (int mf=0;mf<4;mf++)
        #pragma unroll
        for (int nf=0;nf<4;nf++){
          acc[mf][nf] = mfma16(ah[mf], bh2[nf], acc[mf][nf]);
          acc[mf][nf] = mfma16(al[mf], bh2[nf], acc[mf][nf]);
          acc[mf][nf] = mfma16(ah[mf], bl2[nf], acc[mf][nf]);
        }
    }
    __syncthreads();
  }

  // ---- fused prep epilogue: this wave's 64 columns are exactly one head ----
  const int head = (n0 + nbase) >> 6;
  const int b = m0 >> 12;
  const int t0 = (m0 & 4095) + mbase;
  #pragma unroll
  for (int mf=0;mf<4;mf++){
    f32x4 v[4];
    #pragma unroll
    for (int nf=0;nf<4;nf++) v[nf] = acc_fence(acc[mf][nf]);
    #pragma unroll
    for (int r=0;r<4;r++){
      float ss = 0.f;
      #pragma unroll
      for (int nf=0;nf<4;nf++) ss += v[nf][r]*v[nf][r];
      ss += __shfl_xor(ss, 1); ss += __shfl_xor(ss, 2);
      ss += __shfl_xor(ss, 4); ss += __shfl_xor(ss, 8);
      float scale = 0.18033688f / fmaxf(sqrtf(ss), 1e-6f);   // (1/8)*log2e folded in
      int t = t0 + mf*16 + lg*4 + r;
      size_t rowb = ((((size_t)(b*8 + head)) << 12) + t) * 64;
      #pragma unroll
      for (int nf=0;nf<4;nf++){
        float val = v[nf][r];
        u16 hbf = f2bf(val);
        size_t idx = rowb + nf*16 + lr;
        qb [idx] = hbf;
        qlo[idx] = f2bf(val - bf2f(hbf));
        kn [idx] = f2bf(val * scale);
      }
    }
  }

  // ---- fused LSH hash for this wave's 64 tokens (reads back own qb/qlo, L2-hot) ----
  asm volatile("s_waitcnt vmcnt(0)" ::: "memory");
  const size_t qrow0 = (((size_t)(b*8 + head)) << 12) + t0;
  i32x4 qhf[2][4], qlf[2][4];
  #pragma unroll
  for (int ks=0; ks<2; ks++)
    #pragma unroll
    for (int nt=0; nt<4; nt++){
      size_t off = (qrow0 + nt*16 + lr)*64 + ks*32 + lg*8;
      qhf[ks][nt] = *(const i32x4*)(qb + off);
      qlf[ks][nt] = *(const i32x4*)(qlo + off);
    }
  #pragma unroll
  for (int half=0; half<2; half++){
    f32x4 hacc[4][4];
    #pragma unroll
    for (int i=0;i<4;i++)
      #pragma unroll
      for (int j=0;j<4;j++) hacc[i][j] = zero;
    #pragma unroll
    for (int ks=0; ks<2; ks++){
      #pragma unroll
      for (int mf2=0; mf2<4; mf2++){
        int rowr = half*64 + mf2*16 + lr;
        i32x4 rh = *(const i32x4*)(rotH + rowr*64 + ks*32 + lg*8);
        i32x4 rl = *(const i32x4*)(rotL + rowr*64 + ks*32 + lg*8);
        #pragma unroll
        for (int nt=0; nt<4; nt++){
          hacc[mf2][nt] = mfma16(rh, qhf[ks][nt], hacc[mf2][nt]);
          hacc[mf2][nt] = mfma16(rl, qhf[ks][nt], hacc[mf2][nt]);
          hacc[mf2][nt] = mfma16(rh, qlf[ks][nt], hacc[mf2][nt]);
        }
      }
    }
    #pragma unroll
    for (int g=0; g<2; g++){
      int hh = half*2 + g;
      #pragma unroll
      for (int nt=0; nt<4; nt++){
        f32x4 v0 = acc_fence(hacc[2*g][nt]);
        f32x4 v1 = acc_fence(hacc[2*g+1][nt]);
        unsigned long long kmax = 0, kmin = 0;
        #pragma unroll
        for (int r = 0; r < 4; r++){
          int j0 = lg*4 + r, j1 = 16 + lg*4 + r;
          unsigned int mu0 = f2mono(v0[r]), mu1 = f2mono(v1[r]);
          unsigned long long a = ((unsigned long long)mu0 << 32) | (unsigned int)(31 - j0);
          unsigned long long b2 = ((unsigned long long)mu1 << 32) | (unsigned int)(31 - j1);
          if (a > kmax) kmax = a;
          if (b2 > kmax) kmax = b2;
          unsigned long long c2 = ((unsigned long long)(~mu0) << 32) | (unsigned int)(31 - j0);
          unsigned long long d2 = ((unsigned long long)(~mu1) << 32) | (unsigned int)(31 - j1);
          if (c2 > kmin) kmin = c2;
          if (d2 > kmin) kmin = d2;
        }
        #pragma unroll
        for (int msk = 16; msk < 64; msk <<= 1){
          unsigned long long o1 = shfl_xor_u64(kmax, msk); if (o1 > kmax) kmax = o1;
          unsigned long long o2 = shfl_xor_u64(kmin, msk); if (o2 > kmin) kmin = o2;
        }
        if (lg == 0){
          float vmax = mono2f((unsigned int)(kmax >> 32));
          int jmax = 31 - (int)(kmax & 0xFFFFFFFFull);
          float vmin = mono2f(~(unsigned int)(kmin >> 32));
          int jmin = 31 - (int)(kmin & 0xFFFFFFFFull);
          int bucket = (vmax >= -vmin) ? jmax : 32 + jmin;
          int t = t0 + nt*16 + lr;
          Bkt[((size_t)((b*8 + head)*4 + hh) << 12) + t] = bucket;
        }
      }
    }
  }
}

// ---------------- stable counting sort per (bh, round) ----------------
__global__ __launch_bounds__(64) void k_sort(const int* __restrict__ buckets, int* __restrict__ st){
  const int grp = blockIdx.x;
  const int t = threadIdx.x;
  __shared__ int bkL[4096];
  __shared__ int hist[64][65];
  __shared__ int tot[64];
  const size_t gbase = ((size_t)grp) << 12;
  for (int i=0;i<64;i++)
    bkL[i*64 + t] = buckets[gbase + i*64 + t];   // coalesced
  #pragma unroll
  for (int b=0;b<64;b++) hist[t][b] = 0;
  __syncthreads();
  for (int i=0;i<64;i++){
    int b = bkL[t*64 + i];
    hist[t][b]++;
  }
  __syncthreads();
  { int run = 0;
    for (int tt=0; tt<64; tt++){ int v = hist[tt][t]; hist[tt][t] = run; run += v; }
    tot[t] = run; }
  __syncthreads();
  { int v = tot[t]; int incl = v;
    #pragma unroll
    for (int d=1; d<64; d<<=1){ int n = __shfl_up(incl, d, 64); if (t >= d) incl += n; }
    tot[t] = incl - v; }
  __syncthreads();
  const size_t obase = (((size_t)(grp>>2)) << 14) + ((size_t)(grp&3) << 12);
  for (int i=0;i<64;i++){
    int e = t*64 + i;
    int b = bkL[e];
    int dest = tot[b] + hist[t][b];
    hist[t][b]++;
    st[obase + dest] = e;
  }
}

// ---------------- chunked LSH attention: 32KB LDS (5 blocks/CU), no posk array ----------------
__global__ __launch_bounds__(256, 5) void k_attn(
    const u16* __restrict__ qb, const u16* __restrict__ kn, const u16* __restrict__ vB,
    const int* __restrict__ st, float* __restrict__ lgt_out, u16* __restrict__ bo)
{
  int flat = blockIdx.y * gridDim.x + blockIdx.x;
  flat = xcd_swz(flat, gridDim.x * gridDim.y);
  const int c = flat & 255, bh = flat >> 8;
  const int rnd = c >> 6;
  const int cprev = (c + 255) & 255;
  const int tid = threadIdx.x;
  const int l = tid & 63, w = tid >> 6, lr = l & 15, lg = l >> 4;

  __shared__ __align__(16) u16 Ks[128*64];   // 16KB
  __shared__ __align__(16) u16 Vt[64*128];   // 16KB, XOR-swizzled rows of 256B

  const size_t stbase = ((size_t)bh) << 14;
  const size_t kvbase = ((size_t)bh) << 12;

  // K staging: direct st reads, pre-swizzled global source, linear LDS dest
  {
    const int rsub = l >> 3, c8 = l & 7;
    #pragma unroll
    for (int q2 = 0; q2 < 4; q2++){
      int row = w*32 + q2*8 + rsub;
      int cc = (row < 64) ? c : cprev;
      int pos = st[stbase + (cc << 6) + (row & 63)];
      int cs = c8 ^ (row & 7);
      gl_lds16(kn + (kvbase + pos)*64 + cs*8,
               (char*)Ks + (w*4 + q2)*1024 + l*16);
    }
  }

  // Q fragments
  const int pos_q16 = st[stbase + (c << 6) + (w*16 + lr)];
  i32x4 qf[2];
  #pragma unroll
  for (int ks = 0; ks < 2; ks++)
    qf[ks] = *(const i32x4*)(qb + (kvbase + pos_q16)*64 + ks*32 + lg*8);

  // V gather + register transpose into XOR-swizzled Vt
  {
    const int pp = tid & 63, db = tid >> 6;
    const int q5 = pp & 15;
    const int K0 = (pp >> 4)*32 + 16*((q5 >> 1) & 1) + 4*(q5 >> 2) + 2*(q5 & 1);
    int cc0 = (K0 < 64) ? c : cprev;
    int p0 = st[stbase + (cc0 << 6) + (K0 & 63)];
    int p1 = st[stbase + (cc0 << 6) + ((K0 + 1) & 63)];
    const u16* r0 = vB + (kvbase + p0)*64 + db*16;
    const u16* r1 = vB + (kvbase + p1)*64 + db*16;
    uint4 a0 = *(const uint4*)r0, a1 = *(const uint4*)(r0 + 8);
    uint4 b0 = *(const uint4*)r1, b1 = *(const uint4*)(r1 + 8);
    uint av[8] = {a0.x,a0.y,a0.z,a0.w,a1.x,a1.y,a1.z,a1.w};
    uint bv[8] = {b0.x,b0.y,b0.z,b0.w,b1.x,b1.y,b1.z,b1.w};
    #pragma unroll
    for (int dd = 0; dd < 16; dd++){
      uint lo = (av[dd>>1] >> ((dd&1)*16)) & 0xFFFFu;
      uint hi = (bv[dd>>1] >> ((dd&1)*16)) & 0xFFFFu;
      int row = db*16 + dd;
      *(uint*)((char*)Vt + row*256 + ((pp*4) ^ ((row & 7) << 5))) = lo | (hi << 16);
    }
  }
  // boundary-chunk cross-round same-token mask data (rare: 1/64 blocks)
  const bool bdry = (c & 63) == 0;
  int pkprev[4][4];
  if (bdry){
    #pragma unroll
    for (int nf2=0; nf2<4; nf2++)
      #pragma unroll
      for (int r=0;r<4;r++)
        pkprev[nf2][r] = st[stbase + (cprev << 6) + nf2*16 + lg*4 + r];
  }
  __syncthreads();

  f32x4 zero = {0.f,0.f,0.f,0.f};
  f32x4 s[8];
  #pragma unroll
  for (int i=0;i<8;i++) s[i] = zero;
  __builtin_amdgcn_s_setprio(1);
  #pragma unroll
  for (int ks = 0; ks < 2; ks++){
    #pragma unroll
    for (int nf = 0; nf < 8; nf++){
      int row = nf*16 + lr;
      i32x4 kf = *(const i32x4*)((const char*)Ks + row*128 + ((ks*64 + lg*16) ^ ((row&7)<<4)));
      s[nf] = mfma16(kf, qf[ks], s[nf]);
    }
  }
  __builtin_amdgcn_s_setprio(0);

  // max-free softmax: S pre-scaled by 0.125*log2e -> p = 2^S, cannot overflow
  float p[8][4];
  float sum = 0.f;
  #pragma unroll
  for (int nf=0;nf<8;nf++){
    f32x4 t = acc_fence(s[nf]);
    #pragma unroll
    for (int r=0;r<4;r++){
      float e = __builtin_amdgcn_exp2f(t[r]);
      if (nf == w && (lg*4 + r) == lr) e = 0.f;                          // self (same slot)
      if (nf >= 4 && bdry && pkprev[nf-4][r] == pos_q16) e = 0.f;        // cross-round same token
      p[nf][r] = e;
      sum += e;
    }
  }
  sum += __shfl_xor(sum, 16);
  sum += __shfl_xor(sum, 32);
  float lv = logf(sum);
  float inv = 1.f / sum;
  if (l < 16)
    lgt_out[((((size_t)bh) << 12) + pos_q16)*4 + rnd] = lv;

  i32x4 pa[4];
  #pragma unroll
  for (int ks=0;ks<4;ks++){
    uint w0 = cvtpk_bf16(p[2*ks][0],   p[2*ks][1]);
    uint w1 = cvtpk_bf16(p[2*ks][2],   p[2*ks][3]);
    uint w2 = cvtpk_bf16(p[2*ks+1][0], p[2*ks+1][1]);
    uint w3 = cvtpk_bf16(p[2*ks+1][2], p[2*ks+1][3]);
    i32x4 t = {(int)w0,(int)w1,(int)w2,(int)w3};
    pa[ks] = t;
  }

  f32x4 o[4];
  #pragma unroll
  for (int i=0;i<4;i++) o[i] = zero;
  __builtin_amdgcn_s_setprio(1);
  #pragma unroll
  for (int ks=0;ks<4;ks++){
    #pragma unroll
    for (int nf=0;nf<4;nf++){
      int row = nf*16 + lr;
      i32x4 vf = *(const i32x4*)((const char*)Vt + row*256 + ((ks*64 + lg*16) ^ ((row & 7) << 5)));
      o[nf] = mfma16(pa[ks], vf, o[nf]);
    }
  }
  __builtin_amdgcn_s_setprio(0);
  float invq[4]; int posq[4];
  #pragma unroll
  for (int r=0;r<4;r++){
    invq[r] = __shfl(inv, lg*4 + r, 64);
    posq[r] = __shfl(pos_q16, lg*4 + r, 64);
  }
  #pragma unroll
  for (int nf=0;nf<4;nf++){
    f32x4 ov = acc_fence(o[nf]);
    #pragma unroll
    for (int r=0;r<4;r++){
      bo[((((size_t)bh << 12) + posq[r]))*256 + rnd*64 + nf*16 + lr] = f2bf(ov[r] * invq[r]);
    }
  }
}

// ---------------- combine hash rounds (token-major bo/lgt) ----------------
__global__ __launch_bounds__(256) void k_combine(const u16* __restrict__ bo, const float* __restrict__ lgt,
                                                 u16* __restrict__ attn){
  const int wid = blockIdx.x * 4 + (threadIdx.x >> 6);
  const int l = threadIdx.x & 63;
  const int bh = wid >> 12, t = wid & 4095;
  const size_t tb = (((size_t)bh) << 12) + t;
  float4 lg4 = *(const float4*)(lgt + tb*4);
  float m = fmaxf(fmaxf(lg4.x,lg4.y), fmaxf(lg4.z,lg4.w));
  float w0 = __expf(lg4.x-m), w1 = __expf(lg4.y-m), w2 = __expf(lg4.z-m), w3 = __expf(lg4.w-m);
  float inv = 1.f / (w0+w1+w2+w3);
  const u16* bp = bo + tb*256;
  float o = w0 * bf2f(bp[l]) + w1 * bf2f(bp[64+l]) + w2 * bf2f(bp[128+l]) + w3 * bf2f(bp[192+l]);
  o *= inv;
  int b = bh >> 3, h = bh & 7;
  attn[((((size_t)b) << 12) + t) * 512 + h*64 + l] = f2bf(o);
}

// ---------------- residual + LayerNorm: a always bf16 ----------------
// RESF=1: res fp32 (x), write bf16 ob. RESF=0: res bf16 (hb), write fp32 of.
template<int RESF>
__global__ __launch_bounds__(256) void k_ln(const u16* __restrict__ a,
                                            const float* __restrict__ resf, const u16* __restrict__ resb,
                                            const float* __restrict__ g, const float* __restrict__ bb,
                                            float* __restrict__ of, u16* __restrict__ ob){
  const int row = blockIdx.x*4 + (threadIdx.x >> 6);
  const int l = threadIdx.x & 63;
  const size_t base = (size_t)row*512 + l*8;
  uint4 aa = *(const uint4*)(a + base);
  uint aw[4] = {aa.x, aa.y, aa.z, aa.w};
  float av[8];
  #pragma unroll
  for (int j=0;j<4;j++){
    av[2*j]   = bf2f((u16)(aw[j] & 0xFFFF));
    av[2*j+1] = bf2f((u16)(aw[j] >> 16));
  }
  float rv[8];
  if (RESF){
    float4 r0 = *(const float4*)(resf + base);
    float4 r1 = *(const float4*)(resf + base + 4);
    rv[0]=r0.x; rv[1]=r0.y; rv[2]=r0.z; rv[3]=r0.w;
    rv[4]=r1.x; rv[5]=r1.y; rv[6]=r1.z; rv[7]=r1.w;
  } else {
    uint4 rr = *(const uint4*)(resb + base);
    uint rw[4] = {rr.x, rr.y, rr.z, rr.w};
    #pragma unroll
    for (int j=0;j<4;j++){
      rv[2*j]   = bf2f((u16)(rw[j] & 0xFFFF));
      rv[2*j+1] = bf2f((u16)(rw[j] >> 16));
    }
  }
  float v[8];
  #pragma unroll
  for (int j=0;j<8;j++) v[j] = av[j] + rv[j];
  float sum = 0.f;
  #pragma unroll
  for (int j=0;j<8;j++) sum += v[j];
  #pragma unroll
  for (int msk=1; msk<64; msk<<=1) sum += __shfl_xor(sum, msk);
  float mean = sum * (1.f/512.f);
  float ss = 0.f;
  #pragma unroll
  for (int j=0;j<8;j++){ float d = v[j]-mean; ss += d*d; }
  #pragma unroll
  for (int msk=1; msk<64; msk<<=1) ss += __shfl_xor(ss, msk);
  float rstd = rsqrtf(ss * (1.f/512.f) + 1e-6f);
  float4 g0 = *(const float4*)(g + l*8),  g1 = *(const float4*)(g + l*8 + 4);
  float4 b0 = *(const float4*)(bb + l*8), b1 = *(const float4*)(bb + l*8 + 4);
  float gv[8] = {g0.x,g0.y,g0.z,g0.w,g1.x,g1.y,g1.z,g1.w};
  float bv[8] = {b0.x,b0.y,b0.z,b0.w,b1.x,b1.y,b1.z,b1.w};
  float y[8];
  #pragma unroll
  for (int j=0;j<8;j++) y[j] = (v[j]-mean)*rstd*gv[j] + bv[j];
  if (RESF){
    #pragma unroll
    for (int j=0;j<8;j++) ob[base+j] = f2bf(y[j]);
  } else {
    #pragma unroll
    for (int j=0;j<8;j++) of[base+j] = y[j];
  }
}

extern "C" void kernel_launch(void* const* d_in, const int* in_sizes, int n_in,
                              void* d_out, int out_size, void* d_ws, size_t ws_size,
                              hipStream_t stream) {
  const float* x     = (const float*)d_in[0];
  const float* rot   = (const float*)d_in[1];
  const float* w_qk  = (const float*)d_in[2];
  const float* w_v   = (const float*)d_in[3];
  const float* w_out = (const float*)d_in[4];
  const float* b_out = (const float*)d_in[5];
  const float* ln1_g = (const float*)d_in[6];
  const float* ln1_b = (const float*)d_in[7];
  const float* w1    = (const float*)d_in[8];
  const float* b1    = (const float*)d_in[9];
  const float* w2    = (const float*)d_in[10];
  const float* b2    = (const float*)d_in[11];
  const float* ln2_g = (const float*)d_in[12];
  const float* ln2_b = (const float*)d_in[13];
  float* out = (float*)d_out;

  char* p = (char*)d_ws;
  u16*   xh   = (u16*)(p);                    // x-hi   | later: hb (bf16 h)
  u16*   xl   = (u16*)(p + 16777216);         // x-lo   | later: attnc, then f bf16
  u16*   wqkh = (u16*)(p + 33554432);
  u16*   wqkl = (u16*)(p + 34078720);
  u16*   wvb  = (u16*)(p + 34603008);
  u16*   wob  = (u16*)(p + 35127296);
  u16*   w1b  = (u16*)(p + 35651584);
  u16*   w2b  = (u16*)(p + 37748736);
  u16*   qbuf = (u16*)(p + 39845888);         // qk bf16 hi (head layout) | later: proj bf16
  u16*   knb  = (u16*)(p + 56623104);         // kn bf16 (head layout, pre-scaled 0.125*log2e)
  u16*   vb   = (u16*)(p + 73400320);
  int*   bkt  = (int*)(p + 90177536);
  int*   stb  = (int*)(p + 92274688);
  float* lgt  = (float*)(p + 94371840);
  u16*   bo   = (u16*)(p + 96468992);         // 67 MB | early: qlo + rot buffers, later: ffn hidden
  // aliases (non-overlapping lifetimes)
  u16*   qlo   = bo;                          // bo[0..16MB): dead before k_attn writes bo
  u16*   rothi = (u16*)(p + 96468992 + 16777216);          // bo+16MB, 16KB
  u16*   rotlo = (u16*)(p + 96468992 + 16777216 + 16384);  // consumed by gemmqk hash
  u16*   attnc = xl;
  u16*   projb = qbuf;                        // out-proj bf16 (qbuf dead after attn)
  u16*   fb    = xl;                          // FFN2 bf16 (xl dead after out-proj)
  u16*   hb    = xh;
  u16*   hid   = bo;

  // 1) x split (hi/lo bf16)
  k_split<<<8192, 256, 0, stream>>>(x, xh, xl, 16384*512/4);
  // 2) all weight converts + rot transpose/split in one dispatch
  k_wprep<<<2848, 256, 0, stream>>>(w_qk, w_v, w_out, w1, w2, rot,
                                    wqkh, wqkl, wvb, wob, w1b, w2b, rothi, rotlo);
  // 3) qk GEMM (3-term split) + fused prep + fused LSH hash -> qb/qlo/kn + buckets
  k_gemmqk<<<dim3(4,128), 256, 0, stream>>>(xh, xl, wqkh, wqkl, rothi, rotlo,
                                            qbuf, qlo, knb, bkt);
  // 4) v = x @ w_v^T, head layout bf16
  k_gemm<3><<<dim3(4,128), 256, 0, stream>>>(xh, wvb, nullptr, nullptr, vb, 16384, 512, 512);
  // 5) stable counting sort per (bh, round)
  k_sort<<<128, 64, 0, stream>>>(bkt, stb);
  // 6) chunked attention (5 blocks/CU)
  k_attn<<<dim3(256,32), 256, 0, stream>>>(qbuf, knb, vb, stb, lgt, bo);
  // 7) combine rounds -> (b,t,512) bf16
  k_combine<<<32768, 256, 0, stream>>>(bo, lgt, attnc);
  // 8) out projection (+bias) -> bf16 projb
  k_gemm<4><<<dim3(4,128), 256, 0, stream>>>(attnc, wob, b_out, nullptr, projb, 16384, 512, 512);
  // 9) h = LN(proj + x) -> bf16 hb
  k_ln<1><<<4096, 256, 0, stream>>>(projb, x, nullptr, ln1_g, ln1_b, nullptr, hb);
  // 10) hidden = relu(h @ w1^T + b1) bf16
  k_gemm<1><<<dim3(16,128), 256, 0, stream>>>(hb, w1b, b1, nullptr, hid, 16384, 2048, 512);
  // 11) f = hidden @ w2^T + b2 -> bf16 fb
  k_gemm<4><<<dim3(4,128), 256, 0, stream>>>(hid, w2b, b2, nullptr, fb, 16384, 512, 2048);
  // 12) out = LN(f + h) -> fp32 d_out
  k_ln<0><<<4096, 256, 0, stream>>>(fb, nullptr, hb, ln2_g, ln2_b, out, nullptr);
}

// Round 9
// 282.441 us; speedup vs baseline: 1.6882x; 1.0128x over previous
//
#include <hip/hip_runtime.h>
#include <stdint.h>

// Reformer layer: B=4 T=4096 D=512 H=8 DH=64 N_HASH=4 N_BUCKET=64 BUCKET=64 FFN=2048
typedef unsigned short u16;
typedef __attribute__((ext_vector_type(4))) int   i32x4;
typedef __attribute__((ext_vector_type(4))) float f32x4;

__device__ __forceinline__ u16 f2bf(float x){
  unsigned int u = __float_as_uint(x);
  u += 0x7FFFu + ((u >> 16) & 1u);
  return (u16)(u >> 16);
}
__device__ __forceinline__ float bf2f(u16 h){
  return __uint_as_float(((unsigned int)h) << 16);
}
__device__ __forceinline__ unsigned int cvtpk_bf16(float lo, float hi){
  unsigned int r;
  asm("v_cvt_pk_bf16_f32 %0, %1, %2" : "=v"(r) : "v"(lo), "v"(hi));
  return r;
}
__device__ __forceinline__ f32x4 mfma16(i32x4 a, i32x4 b, f32x4 c){
  asm("v_mfma_f32_16x16x32_bf16 %0, %1, %2, %0" : "+v"(c) : "v"(a), "v"(b));
  return c;
}
__device__ __forceinline__ f32x4 acc_fence(f32x4 c){
  asm volatile("s_nop 7\ns_nop 7" : "+v"(c));
  return c;
}
__device__ __forceinline__ void gl_lds16(const void* g, void* l){
  unsigned long long ga = (unsigned long long)g;
  unsigned int la = (unsigned int)(unsigned long long)l;
  __builtin_amdgcn_global_load_lds((const __attribute__((address_space(1))) void*)ga,
                                   (__attribute__((address_space(3))) void*)la, 16, 0, 0);
}
// XCD-chunked bijective swizzle (requires n % 8 == 0)
__device__ __forceinline__ int xcd_swz(int f, int n){
  int chunk = n >> 3;
  return (f & 7) * chunk + (f >> 3);
}
// monotonic-uint transform: order-preserving for fp32 compares
__device__ __forceinline__ unsigned int f2mono(float v){
  unsigned int u = __float_as_uint(v);
  return u ^ ((unsigned int)((int)u >> 31) | 0x80000000u);
}
__device__ __forceinline__ float mono2f(unsigned int mu){
  unsigned int u = (mu & 0x80000000u) ? (mu ^ 0x80000000u) : ~mu;
  return __uint_as_float(u);
}
__device__ __forceinline__ unsigned long long shfl_xor_u64(unsigned long long x, int m){
  int lo = __shfl_xor((int)(unsigned int)(x & 0xFFFFFFFFull), m);
  int hi = __shfl_xor((int)(unsigned int)(x >> 32), m);
  return ((unsigned long long)(unsigned int)hi << 32) | (unsigned int)lo;
}

// ---------------- x split (big) ----------------
__global__ __launch_bounds__(256) void k_split(const float* __restrict__ in, u16* __restrict__ hi, u16* __restrict__ lo, int n4){
  int i = blockIdx.x*256 + threadIdx.x;
  if (i >= n4) return;
  float4 v = ((const float4*)in)[i];
  ushort4 h, l;
  h.x=f2bf(v.x); l.x=f2bf(v.x - bf2f(h.x));
  h.y=f2bf(v.y); l.y=f2bf(v.y - bf2f(h.y));
  h.z=f2bf(v.z); l.z=f2bf(v.z - bf2f(h.z));
  h.w=f2bf(v.w); l.w=f2bf(v.w - bf2f(h.w));
  ((ushort4*)hi)[i]=h; ((ushort4*)lo)[i]=l;
}

// ---------------- fused weight prep ----------------
__global__ __launch_bounds__(256) void k_wprep(
    const float* __restrict__ w_qk, const float* __restrict__ w_v,
    const float* __restrict__ w_out, const float* __restrict__ w1,
    const float* __restrict__ w2, const float* __restrict__ rot,
    u16* __restrict__ wqkh, u16* __restrict__ wqkl,
    u16* __restrict__ wvb, u16* __restrict__ wob,
    u16* __restrict__ w1b, u16* __restrict__ w2b,
    u16* __restrict__ rothi, u16* __restrict__ rotlo)
{
  const int bid = blockIdx.x;
  if (bid >= 2816){
    int i = (bid - 2816)*256 + threadIdx.x;   // 8192 elems
    int d = i & 63, n = i >> 6;
    float v = rot[d*128 + n];
    u16 h = f2bf(v);
    rothi[i] = h; rotlo[i] = f2bf(v - bf2f(h));
    return;
  }
  const int i = bid*256 + threadIdx.x;
  if (i < 65536){
    float4 v = ((const float4*)w_qk)[i];
    ushort4 h, l;
    h.x=f2bf(v.x); l.x=f2bf(v.x - bf2f(h.x));
    h.y=f2bf(v.y); l.y=f2bf(v.y - bf2f(h.y));
    h.z=f2bf(v.z); l.z=f2bf(v.z - bf2f(h.z));
    h.w=f2bf(v.w); l.w=f2bf(v.w - bf2f(h.w));
    ((ushort4*)wqkh)[i]=h; ((ushort4*)wqkl)[i]=l;
    return;
  }
  const float* src; u16* dst; int j;
  if (i < 131072){ src = w_v;  dst = wvb; j = i - 65536; }
  else if (i < 196608){ src = w_out; dst = wob; j = i - 131072; }
  else if (i < 458752){ src = w1;   dst = w1b; j = i - 196608; }
  else { src = w2; dst = w2b; j = i - 458752; }
  float4 v = ((const float4*)src)[j];
  ushort4 o; o.x=f2bf(v.x); o.y=f2bf(v.y); o.z=f2bf(v.z); o.w=f2bf(v.w);
  ((ushort4*)dst)[j] = o;
}

// ---------------- generic bf16 MFMA GEMM: C = A * B^T ----------------
// MODE 1: bf16 rowmajor, bias+relu   MODE 3: bf16 head-layout (v)   MODE 4: bf16 rowmajor + bias
template<int MODE>
__global__ __launch_bounds__(256) void k_gemm(
    const u16* __restrict__ A0, const u16* __restrict__ B0,
    const float* __restrict__ bias,
    float* __restrict__ Cf, u16* __restrict__ Cb,
    int M, int N, int K)
{
  const int tid = threadIdx.x;
  const int l = tid & 63, w = tid >> 6;
  const int lr = l & 15, lg = l >> 4;
  int flat = blockIdx.y * gridDim.x + blockIdx.x;
  flat = xcd_swz(flat, gridDim.x * gridDim.y);
  const int m0 = (flat / gridDim.x) * 128, n0 = (flat % gridDim.x) * 128;
  const int mbase = (w >> 1) * 64, nbase = (w & 1) * 64;

  __shared__ __align__(16) u16 As[128*64];
  __shared__ __align__(16) u16 Bs[128*64];

  f32x4 zero = {0.f,0.f,0.f,0.f};
  f32x4 acc[4][4];
  #pragma unroll
  for (int i=0;i<4;i++)
    #pragma unroll
    for (int j=0;j<4;j++) acc[i][j] = zero;

  const int row_s = tid >> 3;
  const int c16   = tid & 7;

  for (int k0 = 0; k0 < K; k0 += 64){
    #pragma unroll
    for (int q=0;q<4;q++){
      int ra = q*32 + row_s;
      int cs = c16 ^ (ra & 7);
      gl_lds16(A0 + (size_t)(m0 + ra)*K + k0 + cs*8, (char*)As + q*4096 + tid*16);
      gl_lds16(B0 + (size_t)(n0 + ra)*K + k0 + cs*8, (char*)Bs + q*4096 + tid*16);
    }
    __syncthreads();
    #pragma unroll
    for (int kk=0; kk<64; kk+=32){
      i32x4 af[4], bfr[4];
      #pragma unroll
      for (int mf=0;mf<4;mf++){
        int row = mbase + mf*16 + lr;
        af[mf] = *(const i32x4*)((const char*)As + row*128 + (((kk*2) + (lg*16)) ^ ((row&7)<<4)));
      }
      #pragma unroll
      for (int nf=0;nf<4;nf++){
        int row = nbase + nf*16 + lr;
        bfr[nf] = *(const i32x4*)((const char*)Bs + row*128 + (((kk*2) + (lg*16)) ^ ((row&7)<<4)));
      }
      #pragma unroll
      for (int mf=0;mf<4;mf++)
        #pragma unroll
        for (int nf=0;nf<4;nf++)
          acc[mf][nf] = mfma16(af[mf], bfr[nf], acc[mf][nf]);
    }
    __syncthreads();
  }

  #pragma unroll
  for (int mf=0;mf<4;mf++){
    #pragma unroll
    for (int nf=0;nf<4;nf++){
      f32x4 v = acc_fence(acc[mf][nf]);
      #pragma unroll
      for (int r=0;r<4;r++){
        int m = m0 + mbase + mf*16 + lg*4 + r;
        int n = n0 + nbase + nf*16 + lr;
        float val = v[r];
        if (MODE == 1){
          val += bias[n];
          val = fmaxf(val, 0.f);
          Cb[(size_t)m*N + n] = f2bf(val);
        } else if (MODE == 4){
          val += bias[n];
          Cb[(size_t)m*N + n] = f2bf(val);
        } else {
          int b = m >> 12, t = m & 4095, h = n >> 6, d = n & 63;
          size_t idx = ((((size_t)(b*8 + h)) << 12) + t)*64 + d;
          Cb[idx] = f2bf(val);
        }
      }
    }
  }
}

// ---------------- qk GEMM: single-pass 3-term split-bf16 + fused prep epilogue ----------------
// out: qb (bf16 hi), qlo (bf16 lo), kn (normalized * 0.125*log2e, bf16), all head-layout
__global__ __launch_bounds__(256) void k_gemmqk(
    const u16* __restrict__ Ah, const u16* __restrict__ Al,
    const u16* __restrict__ Bh, const u16* __restrict__ Bl,
    u16* __restrict__ qb, u16* __restrict__ qlo, u16* __restrict__ kn)
{
  const int K = 512;
  const int tid = threadIdx.x;
  const int l = tid & 63, w = tid >> 6;
  const int lr = l & 15, lg = l >> 4;
  int flat = blockIdx.y * gridDim.x + blockIdx.x;
  flat = xcd_swz(flat, gridDim.x * gridDim.y);
  const int m0 = (flat >> 2) * 128, n0 = (flat & 3) * 128;
  const int mbase = (w >> 1) * 64, nbase = (w & 1) * 64;

  __shared__ __align__(16) u16 AsH[128*64];
  __shared__ __align__(16) u16 AsL[128*64];
  __shared__ __align__(16) u16 BsH[128*64];
  __shared__ __align__(16) u16 BsL[128*64];

  f32x4 zero = {0.f,0.f,0.f,0.f};
  f32x4 acc[4][4];
  #pragma unroll
  for (int i=0;i<4;i++)
    #pragma unroll
    for (int j=0;j<4;j++) acc[i][j] = zero;

  const int row_s = tid >> 3;
  const int c16   = tid & 7;

  for (int k0 = 0; k0 < K; k0 += 64){
    #pragma unroll
    for (int q=0;q<4;q++){
      int ra = q*32 + row_s;
      int cs = c16 ^ (ra & 7);
      size_t ao = (size_t)(m0 + ra)*K + k0 + cs*8;
      size_t bo = (size_t)(n0 + ra)*K + k0 + cs*8;
      gl_lds16(Ah + ao, (char*)AsH + q*4096 + tid*16);
      gl_lds16(Al + ao, (char*)AsL + q*4096 + tid*16);
      gl_lds16(Bh + bo, (char*)BsH + q*4096 + tid*16);
      gl_lds16(Bl + bo, (char*)BsL + q*4096 + tid*16);
    }
    __syncthreads();
    #pragma unroll
    for (int kk=0; kk<64; kk+=32){
      i32x4 ah[4], al[4], bh2[4], bl2[4];
      #pragma unroll
      for (int mf=0;mf<4;mf++){
        int row = mbase + mf*16 + lr;
        int off = (((kk*2) + (lg*16)) ^ ((row&7)<<4));
        ah[mf] = *(const i32x4*)((const char*)AsH + row*128 + off);
        al[mf] = *(const i32x4*)((const char*)AsL + row*128 + off);
      }
      #pragma unroll
      for (int nf=0;nf<4;nf++){
        int row = nbase + nf*16 + lr;
        int off = (((kk*2) + (lg*16)) ^ ((row&7)<<4));
        bh2[nf] = *(const i32x4*)((const char*)BsH + row*128 + off);
        bl2[nf] = *(const i32x4*)((const char*)BsL + row*128 + off);
      }
      #pragma unroll
      for (int mf=0;mf<4;mf++)
        #pragma unroll
        for (int nf=0;nf<4;nf++){
          acc[mf][nf] = mfma16(ah[mf], bh2[nf], acc[mf][nf]);
          acc[mf][nf] = mfma16(al[mf], bh2[nf], acc[mf][nf]);
          acc[mf][nf] = mfma16(ah[mf], bl2[nf], acc[mf][nf]);
        }
    }
    __syncthreads();
  }

  // fused prep epilogue: this wave's 64 columns are exactly one head
  const int hh = (n0 + nbase) >> 6;
  #pragma unroll
  for (int mf=0;mf<4;mf++){
    f32x4 v[4];
    #pragma unroll
    for (int nf=0;nf<4;nf++) v[nf] = acc_fence(acc[mf][nf]);
    #pragma unroll
    for (int r=0;r<4;r++){
      float ss = 0.f;
      #pragma unroll
      for (int nf=0;nf<4;nf++) ss += v[nf][r]*v[nf][r];
      ss += __shfl_xor(ss, 1); ss += __shfl_xor(ss, 2);
      ss += __shfl_xor(ss, 4); ss += __shfl_xor(ss, 8);
      // fold dim_head^-0.5 AND log2(e) into kn so attn uses raw v_exp (2^x)
      float scale = 0.18033688f / fmaxf(sqrtf(ss), 1e-6f);
      int m = m0 + mbase + mf*16 + lg*4 + r;
      int b = m >> 12, t = m & 4095;
      size_t rowb = ((((size_t)(b*8 + hh)) << 12) + t) * 64;
      #pragma unroll
      for (int nf=0;nf<4;nf++){
        float val = v[nf][r];
        u16 hbf = f2bf(val);
        size_t idx = rowb + nf*16 + lr;
        qb [idx] = hbf;
        qlo[idx] = f2bf(val - bf2f(hbf));
        kn [idx] = f2bf(val * scale);
      }
    }
  }
}

// ---------------- LSH hash: swapped-operand MFMA, lane-local argmax ----------------
__global__ __launch_bounds__(256) void k_hash2(
    const u16* __restrict__ qh, const u16* __restrict__ ql,
    const u16* __restrict__ rh, const u16* __restrict__ rl,
    int* __restrict__ bkt)
{
  const int tid = threadIdx.x;
  const int l = tid & 63, w = tid >> 6, lr = l & 15, lg = l >> 4;
  __shared__ __align__(16) u16 Rh[128*64];
  __shared__ __align__(16) u16 Rl[128*64];
  {
    const int row_s = tid >> 3, c8 = tid & 7;
    #pragma unroll
    for (int q = 0; q < 4; q++){
      int ra = q*32 + row_s;
      int cs = c8 ^ (ra & 7);
      gl_lds16(rh + ra*64 + cs*8, (char*)Rh + q*4096 + tid*16);
      gl_lds16(rl + ra*64 + cs*8, (char*)Rl + q*4096 + tid*16);
    }
  }
  const int blk = xcd_swz(blockIdx.x, gridDim.x);
  const int qrow = blk*64 + w*16 + lr;
  const size_t qoff = (size_t)qrow*64;
  i32x4 qhf[2], qlf[2];
  qhf[0] = *(const i32x4*)(qh + qoff + lg*8);
  qhf[1] = *(const i32x4*)(qh + qoff + 32 + lg*8);
  qlf[0] = *(const i32x4*)(ql + qoff + lg*8);
  qlf[1] = *(const i32x4*)(ql + qoff + 32 + lg*8);
  __syncthreads();

  f32x4 zero = {0.f,0.f,0.f,0.f};
  f32x4 acc[8];
  #pragma unroll
  for (int i=0;i<8;i++) acc[i] = zero;
  #pragma unroll
  for (int ks = 0; ks < 2; ks++){
    #pragma unroll
    for (int nf = 0; nf < 8; nf++){
      int row = nf*16 + lr;
      int off = (ks*64 + lg*16) ^ ((row & 7) << 4);
      i32x4 rhf = *(const i32x4*)((const char*)Rh + row*128 + off);
      i32x4 rlf = *(const i32x4*)((const char*)Rl + row*128 + off);
      acc[nf] = mfma16(rhf, qhf[ks], acc[nf]);
      acc[nf] = mfma16(rlf, qhf[ks], acc[nf]);
      acc[nf] = mfma16(rhf, qlf[ks], acc[nf]);
    }
  }

  const int bh = qrow >> 12, t = qrow & 4095;
  #pragma unroll
  for (int hh = 0; hh < 4; hh++){
    f32x4 v0 = acc_fence(acc[2*hh]);
    f32x4 v1 = acc_fence(acc[2*hh+1]);
    unsigned long long kmax = 0, kmin = 0;
    #pragma unroll
    for (int r = 0; r < 4; r++){
      int j0 = lg*4 + r, j1 = 16 + lg*4 + r;
      unsigned int mu0 = f2mono(v0[r]), mu1 = f2mono(v1[r]);
      unsigned long long a = ((unsigned long long)mu0 << 32) | (unsigned int)(31 - j0);
      unsigned long long b = ((unsigned long long)mu1 << 32) | (unsigned int)(31 - j1);
      if (a > kmax) kmax = a;
      if (b > kmax) kmax = b;
      unsigned long long c = ((unsigned long long)(~mu0) << 32) | (unsigned int)(31 - j0);
      unsigned long long d = ((unsigned long long)(~mu1) << 32) | (unsigned int)(31 - j1);
      if (c > kmin) kmin = c;
      if (d > kmin) kmin = d;
    }
    #pragma unroll
    for (int msk = 16; msk < 64; msk <<= 1){
      unsigned long long o1 = shfl_xor_u64(kmax, msk); if (o1 > kmax) kmax = o1;
      unsigned long long o2 = shfl_xor_u64(kmin, msk); if (o2 > kmin) kmin = o2;
    }
    if (lg == 0){
      float vmax = mono2f((unsigned int)(kmax >> 32));
      int jmax = 31 - (int)(kmax & 0xFFFFFFFFull);
      float vmin = mono2f(~(unsigned int)(kmin >> 32));
      int jmin = 31 - (int)(kmin & 0xFFFFFFFFull);
      int bucket = (vmax >= -vmin) ? jmax : 32 + jmin;
      bkt[((size_t)(bh*4 + hh) << 12) + t] = bucket;
    }
  }
}

// ---------------- stable counting sort per (bh, round) ----------------
__global__ __launch_bounds__(64) void k_sort(const int* __restrict__ buckets, int* __restrict__ st){
  const int grp = blockIdx.x;
  const int t = threadIdx.x;
  __shared__ int bkL[4096];
  __shared__ int hist[64][65];
  __shared__ int tot[64];
  const size_t gbase = ((size_t)grp) << 12;
  for (int i=0;i<64;i++)
    bkL[i*64 + t] = buckets[gbase + i*64 + t];   // coalesced
  #pragma unroll
  for (int b=0;b<64;b++) hist[t][b] = 0;
  __syncthreads();
  for (int i=0;i<64;i++){
    int b = bkL[t*64 + i];
    hist[t][b]++;
  }
  __syncthreads();
  { int run = 0;
    for (int tt=0; tt<64; tt++){ int v = hist[tt][t]; hist[tt][t] = run; run += v; }
    tot[t] = run; }
  __syncthreads();
  { int v = tot[t]; int incl = v;
    #pragma unroll
    for (int d=1; d<64; d<<=1){ int n = __shfl_up(incl, d, 64); if (t >= d) incl += n; }
    tot[t] = incl - v; }
  __syncthreads();
  const size_t obase = (((size_t)(grp>>2)) << 14) + ((size_t)(grp&3) << 12);
  for (int i=0;i<64;i++){
    int e = t*64 + i;
    int b = bkL[e];
    int dest = tot[b] + hist[t][b];
    hist[t][b]++;
    st[obase + dest] = e;
  }
}

// ---------------- chunked LSH attention: 32KB LDS (5 blocks/CU), no posk array ----------------
__global__ __launch_bounds__(256, 5) void k_attn(
    const u16* __restrict__ qb, const u16* __restrict__ kn, const u16* __restrict__ vB,
    const int* __restrict__ st, float* __restrict__ lgt_out, u16* __restrict__ bo)
{
  int flat = blockIdx.y * gridDim.x + blockIdx.x;
  flat = xcd_swz(flat, gridDim.x * gridDim.y);
  const int c = flat & 255, bh = flat >> 8;
  const int rnd = c >> 6;
  const int cprev = (c + 255) & 255;
  const int tid = threadIdx.x;
  const int l = tid & 63, w = tid >> 6, lr = l & 15, lg = l >> 4;

  __shared__ __align__(16) u16 Ks[128*64];   // 16KB
  __shared__ __align__(16) u16 Vt[64*128];   // 16KB, XOR-swizzled rows of 256B

  const size_t stbase = ((size_t)bh) << 14;
  const size_t kvbase = ((size_t)bh) << 12;

  // K staging: direct st reads, pre-swizzled global source, linear LDS dest
  {
    const int rsub = l >> 3, c8 = l & 7;
    #pragma unroll
    for (int q2 = 0; q2 < 4; q2++){
      int row = w*32 + q2*8 + rsub;
      int cc = (row < 64) ? c : cprev;
      int pos = st[stbase + (cc << 6) + (row & 63)];
      int cs = c8 ^ (row & 7);
      gl_lds16(kn + (kvbase + pos)*64 + cs*8,
               (char*)Ks + (w*4 + q2)*1024 + l*16);
    }
  }

  // Q fragments
  const int pos_q16 = st[stbase + (c << 6) + (w*16 + lr)];
  i32x4 qf[2];
  #pragma unroll
  for (int ks = 0; ks < 2; ks++)
    qf[ks] = *(const i32x4*)(qb + (kvbase + pos_q16)*64 + ks*32 + lg*8);

  // V gather + register transpose into XOR-swizzled Vt
  {
    const int pp = tid & 63, db = tid >> 6;
    const int q5 = pp & 15;
    const int K0 = (pp >> 4)*32 + 16*((q5 >> 1) & 1) + 4*(q5 >> 2) + 2*(q5 & 1);
    int cc0 = (K0 < 64) ? c : cprev;
    int p0 = st[stbase + (cc0 << 6) + (K0 & 63)];
    int p1 = st[stbase + (cc0 << 6) + ((K0 + 1) & 63)];
    const u16* r0 = vB + (kvbase + p0)*64 + db*16;
    const u16* r1 = vB + (kvbase + p1)*64 + db*16;
    uint4 a0 = *(const uint4*)r0, a1 = *(const uint4*)(r0 + 8);
    uint4 b0 = *(const uint4*)r1, b1 = *(const uint4*)(r1 + 8);
    uint av[8] = {a0.x,a0.y,a0.z,a0.w,a1.x,a1.y,a1.z,a1.w};
    uint bv[8] = {b0.x,b0.y,b0.z,b0.w,b1.x,b1.y,b1.z,b1.w};
    #pragma unroll
    for (int dd = 0; dd < 16; dd++){
      uint lo = (av[dd>>1] >> ((dd&1)*16)) & 0xFFFFu;
      uint hi = (bv[dd>>1] >> ((dd&1)*16)) & 0xFFFFu;
      int row = db*16 + dd;
      *(uint*)((char*)Vt + row*256 + ((pp*4) ^ ((row & 7) << 5))) = lo | (hi << 16);
    }
  }
  // boundary-chunk cross-round same-token mask data (rare: 1/64 blocks)
  const bool bdry = (c & 63) == 0;
  int pkprev[4][4];
  if (bdry){
    #pragma unroll
    for (int nf2=0; nf2<4; nf2++)
      #pragma unroll
      for (int r=0;r<4;r++)
        pkprev[nf2][r] = st[stbase + (cprev << 6) + nf2*16 + lg*4 + r];
  }
  __syncthreads();

  f32x4 zero = {0.f,0.f,0.f,0.f};
  f32x4 s[8];
  #pragma unroll
  for (int i=0;i<8;i++) s[i] = zero;
  __builtin_amdgcn_s_setprio(1);
  #pragma unroll
  for (int ks = 0; ks < 2; ks++){
    #pragma unroll
    for (int nf = 0; nf < 8; nf++){
      int row = nf*16 + lr;
      i32x4 kf = *(const i32x4*)((const char*)Ks + row*128 + ((ks*64 + lg*16) ^ ((row&7)<<4)));
      s[nf] = mfma16(kf, qf[ks], s[nf]);
    }
  }
  __builtin_amdgcn_s_setprio(0);

  // max-free softmax: S pre-scaled by 0.125*log2e -> p = 2^S, cannot overflow
  float p[8][4];
  float sum = 0.f;
  #pragma unroll
  for (int nf=0;nf<8;nf++){
    f32x4 t = acc_fence(s[nf]);
    #pragma unroll
    for (int r=0;r<4;r++){
      float e = __builtin_amdgcn_exp2f(t[r]);
      if (nf == w && (lg*4 + r) == lr) e = 0.f;                          // self (same slot)
      if (nf >= 4 && bdry && pkprev[nf-4][r] == pos_q16) e = 0.f;        // cross-round same token
      p[nf][r] = e;
      sum += e;
    }
  }
  sum += __shfl_xor(sum, 16);
  sum += __shfl_xor(sum, 32);
  float lv = logf(sum);
  float inv = 1.f / sum;
  if (l < 16)
    lgt_out[((((size_t)bh) << 12) + pos_q16)*4 + rnd] = lv;

  i32x4 pa[4];
  #pragma unroll
  for (int ks=0;ks<4;ks++){
    uint w0 = cvtpk_bf16(p[2*ks][0],   p[2*ks][1]);
    uint w1 = cvtpk_bf16(p[2*ks][2],   p[2*ks][3]);
    uint w2 = cvtpk_bf16(p[2*ks+1][0], p[2*ks+1][1]);
    uint w3 = cvtpk_bf16(p[2*ks+1][2], p[2*ks+1][3]);
    i32x4 t = {(int)w0,(int)w1,(int)w2,(int)w3};
    pa[ks] = t;
  }

  f32x4 o[4];
  #pragma unroll
  for (int i=0;i<4;i++) o[i] = zero;
  __builtin_amdgcn_s_setprio(1);
  #pragma unroll
  for (int ks=0;ks<4;ks++){
    #pragma unroll
    for (int nf=0;nf<4;nf++){
      int row = nf*16 + lr;
      i32x4 vf = *(const i32x4*)((const char*)Vt + row*256 + ((ks*64 + lg*16) ^ ((row & 7) << 5)));
      o[nf] = mfma16(pa[ks], vf, o[nf]);
    }
  }
  __builtin_amdgcn_s_setprio(0);
  float invq[4]; int posq[4];
  #pragma unroll
  for (int r=0;r<4;r++){
    invq[r] = __shfl(inv, lg*4 + r, 64);
    posq[r] = __shfl(pos_q16, lg*4 + r, 64);
  }
  #pragma unroll
  for (int nf=0;nf<4;nf++){
    f32x4 ov = acc_fence(o[nf]);
    #pragma unroll
    for (int r=0;r<4;r++){
      bo[((((size_t)bh << 12) + posq[r]))*256 + rnd*64 + nf*16 + lr] = f2bf(ov[r] * invq[r]);
    }
  }
}

// ---------------- combine hash rounds (token-major bo/lgt) ----------------
__global__ __launch_bounds__(256) void k_combine(const u16* __restrict__ bo, const float* __restrict__ lgt,
                                                 u16* __restrict__ attn){
  const int wid = blockIdx.x * 4 + (threadIdx.x >> 6);
  const int l = threadIdx.x & 63;
  const int bh = wid >> 12, t = wid & 4095;
  const size_t tb = (((size_t)bh) << 12) + t;
  float4 lg4 = *(const float4*)(lgt + tb*4);
  float m = fmaxf(fmaxf(lg4.x,lg4.y), fmaxf(lg4.z,lg4.w));
  float w0 = __expf(lg4.x-m), w1 = __expf(lg4.y-m), w2 = __expf(lg4.z-m), w3 = __expf(lg4.w-m);
  float inv = 1.f / (w0+w1+w2+w3);
  const u16* bp = bo + tb*256;
  float o = w0 * bf2f(bp[l]) + w1 * bf2f(bp[64+l]) + w2 * bf2f(bp[128+l]) + w3 * bf2f(bp[192+l]);
  o *= inv;
  int b = bh >> 3, h = bh & 7;
  attn[((((size_t)b) << 12) + t) * 512 + h*64 + l] = f2bf(o);
}

// ---------------- residual + LayerNorm: a always bf16 ----------------
// RESF=1: res fp32 (x), write bf16 ob. RESF=0: res bf16 (hb), write fp32 of.
template<int RESF>
__global__ __launch_bounds__(256) void k_ln(const u16* __restrict__ a,
                                            const float* __restrict__ resf, const u16* __restrict__ resb,
                                            const float* __restrict__ g, const float* __restrict__ bb,
                                            float* __restrict__ of, u16* __restrict__ ob){
  const int row = blockIdx.x*4 + (threadIdx.x >> 6);
  const int l = threadIdx.x & 63;
  const size_t base = (size_t)row*512 + l*8;
  uint4 aa = *(const uint4*)(a + base);
  uint aw[4] = {aa.x, aa.y, aa.z, aa.w};
  float av[8];
  #pragma unroll
  for (int j=0;j<4;j++){
    av[2*j]   = bf2f((u16)(aw[j] & 0xFFFF));
    av[2*j+1] = bf2f((u16)(aw[j] >> 16));
  }
  float rv[8];
  if (RESF){
    float4 r0 = *(const float4*)(resf + base);
    float4 r1 = *(const float4*)(resf + base + 4);
    rv[0]=r0.x; rv[1]=r0.y; rv[2]=r0.z; rv[3]=r0.w;
    rv[4]=r1.x; rv[5]=r1.y; rv[6]=r1.z; rv[7]=r1.w;
  } else {
    uint4 rr = *(const uint4*)(resb + base);
    uint rw[4] = {rr.x, rr.y, rr.z, rr.w};
    #pragma unroll
    for (int j=0;j<4;j++){
      rv[2*j]   = bf2f((u16)(rw[j] & 0xFFFF));
      rv[2*j+1] = bf2f((u16)(rw[j] >> 16));
    }
  }
  float v[8];
  #pragma unroll
  for (int j=0;j<8;j++) v[j] = av[j] + rv[j];
  float sum = 0.f;
  #pragma unroll
  for (int j=0;j<8;j++) sum += v[j];
  #pragma unroll
  for (int msk=1; msk<64; msk<<=1) sum += __shfl_xor(sum, msk);
  float mean = sum * (1.f/512.f);
  float ss = 0.f;
  #pragma unroll
  for (int j=0;j<8;j++){ float d = v[j]-mean; ss += d*d; }
  #pragma unroll
  for (int msk=1; msk<64; msk<<=1) ss += __shfl_xor(ss, msk);
  float rstd = rsqrtf(ss * (1.f/512.f) + 1e-6f);
  float4 g0 = *(const float4*)(g + l*8),  g1 = *(const float4*)(g + l*8 + 4);
  float4 b0 = *(const float4*)(bb + l*8), b1 = *(const float4*)(bb + l*8 + 4);
  float gv[8] = {g0.x,g0.y,g0.z,g0.w,g1.x,g1.y,g1.z,g1.w};
  float bv[8] = {b0.x,b0.y,b0.z,b0.w,b1.x,b1.y,b1.z,b1.w};
  float y[8];
  #pragma unroll
  for (int j=0;j<8;j++) y[j] = (v[j]-mean)*rstd*gv[j] + bv[j];
  if (RESF){
    #pragma unroll
    for (int j=0;j<8;j++) ob[base+j] = f2bf(y[j]);
  } else {
    #pragma unroll
    for (int j=0;j<8;j++) of[base+j] = y[j];
  }
}

extern "C" void kernel_launch(void* const* d_in, const int* in_sizes, int n_in,
                              void* d_out, int out_size, void* d_ws, size_t ws_size,
                              hipStream_t stream) {
  const float* x     = (const float*)d_in[0];
  const float* rot   = (const float*)d_in[1];
  const float* w_qk  = (const float*)d_in[2];
  const float* w_v   = (const float*)d_in[3];
  const float* w_out = (const float*)d_in[4];
  const float* b_out = (const float*)d_in[5];
  const float* ln1_g = (const float*)d_in[6];
  const float* ln1_b = (const float*)d_in[7];
  const float* w1    = (const float*)d_in[8];
  const float* b1    = (const float*)d_in[9];
  const float* w2    = (const float*)d_in[10];
  const float* b2    = (const float*)d_in[11];
  const float* ln2_g = (const float*)d_in[12];
  const float* ln2_b = (const float*)d_in[13];
  float* out = (float*)d_out;

  char* p = (char*)d_ws;
  u16*   xh   = (u16*)(p);                    // x-hi   | later: hb (bf16 h)
  u16*   xl   = (u16*)(p + 16777216);         // x-lo   | later: attnc, then f bf16
  u16*   wqkh = (u16*)(p + 33554432);
  u16*   wqkl = (u16*)(p + 34078720);
  u16*   wvb  = (u16*)(p + 34603008);
  u16*   wob  = (u16*)(p + 35127296);
  u16*   w1b  = (u16*)(p + 35651584);
  u16*   w2b  = (u16*)(p + 37748736);
  u16*   qbuf = (u16*)(p + 39845888);         // qk bf16 hi (head layout) | later: proj bf16
  u16*   knb  = (u16*)(p + 56623104);         // kn bf16 (head layout, pre-scaled 0.125*log2e)
  u16*   vb   = (u16*)(p + 73400320);
  int*   bkt  = (int*)(p + 90177536);
  int*   stb  = (int*)(p + 92274688);
  float* lgt  = (float*)(p + 94371840);
  u16*   bo   = (u16*)(p + 96468992);         // 67 MB | early: qlo + rot buffers, later: ffn hidden
  // aliases (non-overlapping lifetimes)
  u16*   qlo   = bo;                          // bo[0..16MB): dead before k_attn writes bo
  u16*   rothi = (u16*)(p + 96468992 + 16777216);          // bo+16MB, 16KB
  u16*   rotlo = (u16*)(p + 96468992 + 16777216 + 16384);  // consumed by hash before attn
  u16*   attnc = xl;
  u16*   projb = qbuf;                        // out-proj bf16 (qbuf dead after attn)
  u16*   fb    = xl;                          // FFN2 bf16 (xl dead after out-proj)
  u16*   hb    = xh;
  u16*   hid   = bo;

  // 1) x split (hi/lo bf16)
  k_split<<<8192, 256, 0, stream>>>(x, xh, xl, 16384*512/4);
  // 2) all weight converts + rot transpose/split in one dispatch
  k_wprep<<<2848, 256, 0, stream>>>(w_qk, w_v, w_out, w1, w2, rot,
                                    wqkh, wqkl, wvb, wob, w1b, w2b, rothi, rotlo);
  // 3) qk GEMM (single-pass 3-term split) + fused prep epilogue
  k_gemmqk<<<dim3(4,128), 256, 0, stream>>>(xh, xl, wqkh, wqkl, qbuf, qlo, knb);
  // 4) v = x @ w_v^T, head layout bf16
  k_gemm<3><<<dim3(4,128), 256, 0, stream>>>(xh, wvb, nullptr, nullptr, vb, 16384, 512, 512);
  // 5) LSH hash: S^T = rot x qk (3-term split), lane-local argmax -> buckets
  k_hash2<<<2048, 256, 0, stream>>>(qbuf, qlo, rothi, rotlo, bkt);
  // 6) stable counting sort per (bh, round)
  k_sort<<<128, 64, 0, stream>>>(bkt, stb);
  // 7) chunked attention (5 blocks/CU)
  k_attn<<<dim3(256,32), 256, 0, stream>>>(qbuf, knb, vb, stb, lgt, bo);
  // 8) combine rounds -> (b,t,512) bf16
  k_combine<<<32768, 256, 0, stream>>>(bo, lgt, attnc);
  // 9) out projection (+bias) -> bf16 projb
  k_gemm<4><<<dim3(4,128), 256, 0, stream>>>(attnc, wob, b_out, nullptr, projb, 16384, 512, 512);
  // 10) h = LN(proj + x) -> bf16 hb
  k_ln<1><<<4096, 256, 0, stream>>>(projb, x, nullptr, ln1_g, ln1_b, nullptr, hb);
  // 11) hidden = relu(h @ w1^T + b1) bf16
  k_gemm<1><<<dim3(16,128), 256, 0, stream>>>(hb, w1b, b1, nullptr, hid, 16384, 2048, 512);
  // 12) f = hidden @ w2^T + b2 -> bf16 fb
  k_gemm<4><<<dim3(4,128), 256, 0, stream>>>(hid, w2b, b2, nullptr, fb, 16384, 512, 2048);
  // 13) out = LN(f + h) -> fp32 d_out
  k_ln<0><<<4096, 256, 0, stream>>>(fb, nullptr, hb, ln2_g, ln2_b, out, nullptr);
}